// Round 15
// baseline (382.584 us; speedup 1.0000x reference)
//
#include <hip/hip_runtime.h>
#include <hip/hip_fp16.h>

// NequIP-style layer, f32.
// Tier 1 (~234MB ws): CSR sort -> pack_weights/pack_node_B -> node_prep ->
//   w_kernel (dot2 MLP + MFMA w-GEMM, D = Wm3T x h2 so stores pack 8B/lane;
//   global-B, 32KB LDS, 4 blocks/CU) -> gather_tp -> node_gemm -> gate_kernel.
// Tier 2 (~62.8MB ws): r7 fused gather + VALU node_post.
// Tier 3 (~61.4MB ws): atomic kernel + VALU node_post.

#define NN 20000
#define NE 320000

typedef _Float16 h2v __attribute__((ext_vector_type(2)));
typedef _Float16 f16x8 __attribute__((ext_vector_type(8)));
typedef float f32x4 __attribute__((ext_vector_type(4)));

__device__ __forceinline__ float swishf(float x) {
  float t = __expf(-fabsf(x));
  float r = 1.0f / (1.0f + t);
  float sig = (x >= 0.0f) ? r : t * r;
  return x * sig;
}

__device__ __forceinline__ unsigned pack2h(float a, float b) {
  __half2 h = __floats2half2_rn(a, b);
  return *reinterpret_cast<unsigned*>(&h);
}

__device__ __forceinline__ h2v u32h2(unsigned u) {
  union { unsigned u; h2v h; } x; x.u = u; return x.h;
}

__device__ __forceinline__ h2v packh2v(float a, float b) {
  h2v h; h.x = (_Float16)a; h.y = (_Float16)b; return h;
}

__device__ __forceinline__ f16x8 u4f16(uint4 u) {
  union { uint4 u; f16x8 h; } x; x.u = u; return x.h;
}

__device__ __forceinline__ void ld8(float d[8], const float* p) {
  float4 a0 = *(const float4*)p;
  float4 a1 = *(const float4*)(p + 4);
  d[0]=a0.x; d[1]=a0.y; d[2]=a0.z; d[3]=a0.w;
  d[4]=a1.x; d[5]=a1.y; d[6]=a1.z; d[7]=a1.w;
}

__device__ __forceinline__ void fma8v(float (&acc)[8], const float* p, float w) {
  float4 a0 = *(const float4*)p;
  float4 a1 = *(const float4*)(p + 4);
  acc[0] = fmaf(a0.x, w, acc[0]); acc[1] = fmaf(a0.y, w, acc[1]);
  acc[2] = fmaf(a0.z, w, acc[2]); acc[3] = fmaf(a0.w, w, acc[3]);
  acc[4] = fmaf(a1.x, w, acc[4]); acc[5] = fmaf(a1.y, w, acc[5]);
  acc[6] = fmaf(a1.z, w, acc[6]); acc[7] = fmaf(a1.w, w, acc[7]);
}

// ---------------- CSR build ----------------
__global__ __launch_bounds__(256) void hist_kernel(const int* __restrict__ rcv,
                                                   int* __restrict__ counts) {
  int e = blockIdx.x * 256 + threadIdx.x;
  atomicAdd(&counts[rcv[e]], 1);
}

__global__ __launch_bounds__(1024) void scan_kernel(const int* __restrict__ counts,
                                                    int* __restrict__ offsets,
                                                    int* __restrict__ cursor) {
  __shared__ int part[1024];
  const int t = threadIdx.x;
  const int base = t * 20;
  int loc[20];
  int s = 0;
  #pragma unroll
  for (int j = 0; j < 20; ++j) {
    int idx = base + j;
    int c = (idx < NN) ? counts[idx] : 0;
    loc[j] = s;
    s += c;
  }
  part[t] = s;
  __syncthreads();
  for (int d = 1; d < 1024; d <<= 1) {
    int v = (t >= d) ? part[t - d] : 0;
    __syncthreads();
    part[t] += v;
    __syncthreads();
  }
  int excl = (t > 0) ? part[t - 1] : 0;
  #pragma unroll
  for (int j = 0; j < 20; ++j) {
    int idx = base + j;
    if (idx < NN) {
      int o = excl + loc[j];
      offsets[idx] = o;
      cursor[idx] = o;
    }
  }
  if (t == 1023) offsets[NN] = part[1023];
}

__global__ __launch_bounds__(256) void scatter_full(
    const int* __restrict__ rcv, const int* __restrict__ snd,
    const float* __restrict__ esh, int* __restrict__ cursor,
    int* __restrict__ csr_edge, int* __restrict__ snd_sorted,
    float* __restrict__ sh_sorted) {
  int e = blockIdx.x * 256 + threadIdx.x;
  int r = rcv[e];
  int pos = atomicAdd(&cursor[r], 1);
  csr_edge[pos] = e;
  snd_sorted[pos] = snd[e];
  float4 sh = *(const float4*)(esh + (size_t)e * 4);
  *(float4*)(sh_sorted + (size_t)pos * 4) = sh;
}

__global__ __launch_bounds__(256) void scatter_kernel(
    const int* __restrict__ rcv, int* __restrict__ cursor,
    int* __restrict__ csr_edge) {
  int e = blockIdx.x * 256 + threadIdx.x;
  int r = rcv[e];
  int pos = atomicAdd(&cursor[r], 1);
  csr_edge[pos] = e;
}

// ---------------- pack Wm2/Wm3 into f16 k-pair tables ----------------
__global__ __launch_bounds__(256) void pack_weights(
    const float* __restrict__ Wm2, const float* __restrict__ Wm3,
    unsigned* __restrict__ Wm2P, unsigned* __restrict__ Wm3P,
    unsigned* __restrict__ Wm3T) {
  int idx = blockIdx.x * 256 + threadIdx.x;
  if (idx < 2048) {
    int k2 = idx >> 6, v = idx & 63;
    Wm2P[idx] = pack2h(Wm2[(2 * k2) * 64 + v], Wm2[(2 * k2 + 1) * 64 + v]);
  } else if (idx < 10240) {
    int r = idx - 2048;
    int k2 = r >> 8, c = r & 255;
    Wm3P[r] = pack2h(Wm3[(2 * k2) * 256 + c], Wm3[(2 * k2 + 1) * 256 + c]);
  } else if (idx < 18432) {
    int r = idx - 10240;
    int c = r >> 5, j = r & 31;
    Wm3T[r] = pack2h(Wm3[(2 * j) * 256 + c], Wm3[(2 * j + 1) * 256 + c]);
  }
}

// ---------------- pack node-side B^T tables (scales folded) ----------------
__global__ __launch_bounds__(256) void pack_node_B(
    const float* __restrict__ Wr_s, const float* __restrict__ W2s,
    const float* __restrict__ Wr_v, const float* __restrict__ W2v,
    unsigned* __restrict__ BsT, unsigned* __restrict__ BvT) {
  const float nr = 0.05590169943749474f;   // 1/sqrt(320)
  const float n2 = 0.08838834764831845f;   // 1/sqrt(128)
  int idx = blockIdx.x * 256 + threadIdx.x;
  if (idx < 28672) {
    int v = idx / 224, j = idx % 224;
    float a, b;
    if (j < 160) {
      int s = j >> 5, u0 = (j & 31) << 1;
      a = Wr_s[(u0 * 5 + s) * 128 + v] * nr;
      b = Wr_s[((u0 + 1) * 5 + s) * 128 + v] * nr;
    } else {
      int c0 = (j - 160) << 1;
      a = W2s[c0 * 128 + v] * n2;
      b = W2s[(c0 + 1) * 128 + v] * n2;
    }
    BsT[idx] = pack2h(a, b);
  } else if (idx < 43008) {
    int r = idx - 28672;
    int v = r / 224, j = r % 224;
    float a, b;
    if (j < 160) {
      int s = j >> 5, u0 = (j & 31) << 1;
      a = Wr_v[(u0 * 5 + s) * 64 + v] * nr;
      b = Wr_v[((u0 + 1) * 5 + s) * 64 + v] * nr;
    } else {
      int c0 = (j - 160) << 1;
      a = W2v[c0 * 64 + v] * n2;
      b = W2v[(c0 + 1) * 64 + v] * n2;
    }
    BvT[r] = pack2h(a, b);
  }
}

// ---------------- node_prep: y = [x0@Wl0, x1@Wl1] * nl ----------------
__global__ __launch_bounds__(256) void node_prep(
    const float* __restrict__ feats, const float* __restrict__ Wl0,
    const float* __restrict__ Wl1, float* __restrict__ y)
{
  __shared__ __align__(16) float sX[4 * 256];
  const int t = threadIdx.x;
  const int n0 = blockIdx.x * 4;
  #pragma unroll
  for (int nb = 0; nb < 4; ++nb)
    sX[nb * 256 + t] = feats[(size_t)(n0 + nb) * 256 + t];
  __syncthreads();

  float acc[4] = {0.f, 0.f, 0.f, 0.f};
  if (t < 64) {
    const int v = t;
    for (int u = 0; u < 64; ++u) {
      float w = Wl0[u * 64 + v];
      acc[0] = fmaf(sX[0 * 256 + u], w, acc[0]);
      acc[1] = fmaf(sX[1 * 256 + u], w, acc[1]);
      acc[2] = fmaf(sX[2 * 256 + u], w, acc[2]);
      acc[3] = fmaf(sX[3 * 256 + u], w, acc[3]);
    }
  } else {
    const int i = t - 64;
    const int v = i / 3;
    const int m = i - v * 3;
    for (int u = 0; u < 64; ++u) {
      float w = Wl1[u * 64 + v];
      int xi = 64 + u * 3 + m;
      acc[0] = fmaf(sX[0 * 256 + xi], w, acc[0]);
      acc[1] = fmaf(sX[1 * 256 + xi], w, acc[1]);
      acc[2] = fmaf(sX[2 * 256 + xi], w, acc[2]);
      acc[3] = fmaf(sX[3 * 256 + xi], w, acc[3]);
    }
  }
  #pragma unroll
  for (int nb = 0; nb < 4; ++nb)
    y[(size_t)(n0 + nb) * 256 + t] = acc[nb] * 0.125f;   // nl = 1/sqrt(64)
}

// GEMV helper (fallback paths, f32)
__device__ __forceinline__ void wgemv(float (&wa)[64], const float* __restrict__ Wm3,
                                      const float* h2col, int p)
{
  #pragma unroll
  for (int v = 0; v < 64; ++v) wa[v] = 0.f;
  #pragma unroll 2
  for (int k = 0; k < 64; ++k) {
    float h2k = h2col[k * 256];
    const float* wrow = Wm3 + k * 256 + p * 64;
    #pragma unroll
    for (int v = 0; v < 64; ++v) wa[v] = fmaf(h2k, wrow[v], wa[v]);
  }
}

// ---------------- tier-1 phase A: MLP h2 (dot2) + MFMA w-GEMM ----------------
// D = Wm3T(A, M=cols) x h2(B, N=edges): lane holds 4 consecutive w-cols of one
// edge -> packed 8B stores. B-frags (h2) cached from LDS; A-frags from global
// Wm3T (L2-hit). 32KB LDS -> 4 blocks/CU.
__global__ __launch_bounds__(256, 4) void w_kernel(
    const int* __restrict__ csr_edge, const float* __restrict__ emb,
    const float* __restrict__ Wm1, const unsigned* __restrict__ Wm2P,
    const unsigned* __restrict__ Wm3T, __half* __restrict__ w_sorted)
{
  __shared__ unsigned sA[256 * 32];   // h2 f16 [edge][k2], swizzled, 32KB
  const int tid = threadIdx.x;
  const int i = blockIdx.x * 256 + tid;
  const int e = csr_edge[i];

  float e8[8];
  ld8(e8, emb + (size_t)e * 8);
  float h2a[64];
  #pragma unroll
  for (int v = 0; v < 64; ++v) h2a[v] = 0.f;
  #pragma unroll 1
  for (int k2 = 0; k2 < 32; ++k2) {
    float a0 = 0.f, a1 = 0.f;
    #pragma unroll
    for (int j = 0; j < 8; ++j) {
      a0 = fmaf(e8[j], Wm1[j * 64 + 2 * k2], a0);
      a1 = fmaf(e8[j], Wm1[j * 64 + 2 * k2 + 1], a1);
    }
    h2v ph = packh2v(swishf(a0 * 0.35355339059327373f),
                     swishf(a1 * 0.35355339059327373f));
    const unsigned* wrow = Wm2P + k2 * 64;
    #pragma unroll
    for (int v = 0; v < 64; ++v)
      h2a[v] = __builtin_amdgcn_fdot2(ph, u32h2(wrow[v]), h2a[v], false);
  }
  {
    const int r = tid;
    #pragma unroll
    for (int c = 0; c < 8; ++c) {
      uint4 v;
      v.x = pack2h(swishf(h2a[8 * c + 0] * 0.125f), swishf(h2a[8 * c + 1] * 0.125f));
      v.y = pack2h(swishf(h2a[8 * c + 2] * 0.125f), swishf(h2a[8 * c + 3] * 0.125f));
      v.z = pack2h(swishf(h2a[8 * c + 4] * 0.125f), swishf(h2a[8 * c + 5] * 0.125f));
      v.w = pack2h(swishf(h2a[8 * c + 6] * 0.125f), swishf(h2a[8 * c + 7] * 0.125f));
      *(uint4*)&sA[r * 32 + ((c ^ (r & 7)) << 2)] = v;
    }
  }
  __syncthreads();

  const int l = tid & 63;
  const int wv = tid >> 6;
  const int lg = l >> 4;
  const int lm = l & 15;

  // B-frags: the wave's 64 edges (4 n-tiles), k-contiguous per edge (validated
  // fragment pattern, same as before -- only the operand role changes).
  f16x8 bfr[4][2];
  #pragma unroll
  for (int nt = 0; nt < 4; ++nt) {
    int row = wv * 64 + nt * 16 + lm;
    #pragma unroll
    for (int kh = 0; kh < 2; ++kh) {
      uint4 u = *(const uint4*)&sA[row * 32 + ((((kh << 2) + lg) ^ (row & 7)) << 2)];
      bfr[nt][kh] = u4f16(u);
    }
  }

  const size_t ebase = ((size_t)blockIdx.x * 256 + (size_t)wv * 64) * 256;
  #pragma unroll 1
  for (int mt = 0; mt < 16; ++mt) {
    int arow = mt * 16 + lm;            // w-col row in Wm3T
    uint4 u0 = *(const uint4*)&Wm3T[arow * 32 + (lg << 2)];
    uint4 u1 = *(const uint4*)&Wm3T[arow * 32 + 16 + (lg << 2)];
    f16x8 a0 = u4f16(u0), a1 = u4f16(u1);
    #pragma unroll
    for (int nt = 0; nt < 4; ++nt) {
      f32x4 acc = {0.f, 0.f, 0.f, 0.f};
      acc = __builtin_amdgcn_mfma_f32_16x16x32_f16(a0, bfr[nt][0], acc, 0, 0, 0);
      acc = __builtin_amdgcn_mfma_f32_16x16x32_f16(a1, bfr[nt][1], acc, 0, 0, 0);
      // D: row = w-col (mt*16 + lg*4 + rr), col = edge (nt*16 + lm)
      uint2 pk;
      pk.x = pack2h(acc[0], acc[1]);
      pk.y = pack2h(acc[2], acc[3]);
      *(uint2*)(w_sorted + ebase + (size_t)(nt * 16 + lm) * 256 + mt * 16 + lg * 4) = pk;
    }
  }
}

// ---------------- tier-1 phase B: per-node gather + tensor product ----------
__global__ __launch_bounds__(256) void gather_tp(
    const float* __restrict__ y, const __half* __restrict__ w_sorted,
    const float* __restrict__ sh_sorted, const int* __restrict__ snd_sorted,
    const int* __restrict__ offsets, float* __restrict__ agg)
{
  const int l = threadIdx.x & 63;
  const int wv = threadIdx.x >> 6;
  const int n = blockIdx.x * 4 + wv;
  const int row0 = offsets[n];
  const int row1 = offsets[n + 1];

  float s0 = 0.f, s1 = 0.f;
  float v0x = 0.f, v0y = 0.f, v0z = 0.f;
  float v1x = 0.f, v1y = 0.f, v1z = 0.f;

  for (int i = row0; i < row1; ++i) {
    const int s = snd_sorted[i];
    const float4 sh = *(const float4*)(sh_sorted + (size_t)i * 4);
    const __half* wr = w_sorted + (size_t)i * 256;
    float w1 = __half2float(wr[l]);
    float w2 = __half2float(wr[64 + l]);
    float w3 = __half2float(wr[128 + l]);
    float w4 = __half2float(wr[192 + l]);
    const float* yr = y + (size_t)s * 256;
    float e0 = yr[l];
    float ex = yr[64 + 3 * l], ey = yr[65 + 3 * l], ez = yr[66 + 3 * l];

    s0 = fmaf(w1 * e0, sh.x, s0);
    s1 = fmaf(w4, fmaf(ex, sh.y, fmaf(ey, sh.z, ez * sh.w)), s1);
    float t2 = w2 * e0;
    v0x = fmaf(t2, sh.y, v0x); v0y = fmaf(t2, sh.z, v0y); v0z = fmaf(t2, sh.w, v0z);
    float t3 = w3 * sh.x;
    v1x = fmaf(t3, ex, v1x); v1y = fmaf(t3, ey, v1y); v1z = fmaf(t3, ez, v1z);
  }

  const float SCL = 0.0078125f;                          // (1/8 w-scale) / 16
  const float C4  = 0.125f / (16.0f * 1.7320508075688772f);
  float* ar = agg + (size_t)n * 512;
  ar[l]       = s0 * SCL;
  ar[64 + l]  = s1 * C4;
  ar[128 + 3 * l]     = v0x * SCL;
  ar[128 + 3 * l + 1] = v0y * SCL;
  ar[128 + 3 * l + 2] = v0z * SCL;
  ar[320 + 3 * l]     = v1x * SCL;
  ar[320 + 3 * l + 1] = v1y * SCL;
  ar[320 + 3 * l + 2] = v1z * SCL;
}

// ---------------- tier-1: node-side MFMA GEMM ----------------
__global__ __launch_bounds__(256) void node_gemm(
    const float* __restrict__ feats, const float* __restrict__ attrs,
    const float* __restrict__ agg, const unsigned* __restrict__ BsT,
    const unsigned* __restrict__ BvT, float* __restrict__ zs,
    float* __restrict__ zv)
{
  __shared__ unsigned sAK[64 * 224];   // 57344B
  __shared__ float sX[16 * 257];       // padded
  __shared__ float sAt[16 * 5];
  const int t = threadIdx.x;
  const int n0 = blockIdx.x * 16;

  #pragma unroll
  for (int nb = 0; nb < 16; ++nb)
    sX[nb * 257 + t] = feats[(size_t)(n0 + nb) * 256 + t];
  if (t < 80) sAt[t] = attrs[(size_t)n0 * 5 + t];
  __syncthreads();

  {
    const int row = t >> 2;
    const int part = t & 3;
    const bool is_s = row < 16;
    int node, m = 0;
    if (is_s) node = row;
    else { int vi = row - 16; node = vi / 3; m = vi - node * 3; }
    const float* xrow = &sX[node * 257];
    const float* atr = &sAt[node * 5];
    const float* aggr = agg + (size_t)(n0 + node) * 512;
    unsigned* arow = &sAK[row * 224];
    #pragma unroll 8
    for (int jj = 0; jj < 56; ++jj) {
      const int j = part + 4 * jj;
      float v0, v1;
      if (jj < 40) {
        int s = j >> 5;
        int u0 = (j & 31) << 1;
        float a = atr[s];
        float x0 = is_s ? xrow[u0]     : xrow[64 + 3 * u0 + m];
        float x1 = is_s ? xrow[u0 + 1] : xrow[64 + 3 * u0 + 3 + m];
        v0 = x0 * a;
        v1 = x1 * a;
      } else {
        int c0 = (j - 160) << 1;
        if (is_s) { v0 = aggr[c0]; v1 = aggr[c0 + 1]; }
        else {
          v0 = aggr[128 + 3 * c0 + m];
          v1 = aggr[128 + 3 * c0 + 3 + m];
        }
      }
      int chs = (jj & ~7) | ((jj ^ row) & 7);
      arow[(chs << 2) + part] = pack2h(v0, v1);
    }
  }
  __syncthreads();

  const int l = t & 63;
  const int wv = t >> 6;
  const int lm = l & 15;
  const int lg = l >> 4;

  #pragma unroll 1
  for (int jj = 0; jj < 5; ++jj) {
    const int jd = wv + 4 * jj;
    int mtile, ntile;
    const unsigned* Bt;
    if (jd < 8) { mtile = 0; ntile = jd; Bt = BsT; }
    else { int q = jd - 8; mtile = 1 + (q >> 2); ntile = q & 3; Bt = BvT; }

    const int arow0 = mtile * 16 + lm;
    const unsigned* brow = Bt + (ntile * 16 + lm) * 224;
    f32x4 acc = {0.f, 0.f, 0.f, 0.f};
    #pragma unroll 2
    for (int ks = 0; ks < 14; ++ks) {
      int ch = ks * 4 + lg;
      int chs = (ch & ~7) | ((ch ^ arow0) & 7);
      uint4 ua = *(const uint4*)&sAK[arow0 * 224 + (chs << 2)];
      uint4 ub = *(const uint4*)&brow[ch << 2];
      acc = __builtin_amdgcn_mfma_f32_16x16x32_f16(u4f16(ua), u4f16(ub), acc, 0, 0, 0);
    }
    const int drow = mtile * 16 + lg * 4;
    if (jd < 8) {
      #pragma unroll
      for (int rr = 0; rr < 4; ++rr)
        zs[(size_t)(n0 + drow + rr) * 128 + ntile * 16 + lm] = acc[rr];
    } else {
      const int vi0 = drow - 16;
      #pragma unroll
      for (int rr = 0; rr < 4; ++rr)
        zv[((size_t)blockIdx.x * 48 + vi0 + rr) * 64 + ntile * 16 + lm] = acc[rr];
    }
  }
}

// ---------------- tier-1: gating epilogue ----------------
__global__ __launch_bounds__(256) void gate_kernel(
    const float* __restrict__ zs, const float* __restrict__ zv,
    float* __restrict__ out)
{
  const int n = blockIdx.x;
  const int t = threadIdx.x;
  float val;
  if (t < 64) {
    val = swishf(zs[(size_t)n * 128 + t]);
  } else {
    int i = t - 64;
    int u = i / 3;
    int m = i - u * 3;
    float gate = swishf(zs[(size_t)n * 128 + 64 + u]);
    val = gate * zv[((size_t)n * 3 + m) * 64 + u];
  }
  out[(size_t)n * 256 + t] = val;
}

// ---------------- tier-2: r7 fused gather ----------------
__global__ __launch_bounds__(512, 2) void gather_fused(
    const float* __restrict__ y, const int* __restrict__ csr_edge,
    const int* __restrict__ snd, const float* __restrict__ esh,
    const float* __restrict__ emb, const float* __restrict__ Wm1,
    const float* __restrict__ Wm2, const float* __restrict__ Wm3,
    const int* __restrict__ offsets, float* __restrict__ agg)
{
  __shared__ __align__(16) float sW3[64 * 256];
  __shared__ __align__(16) float sH[8 * 4 * 64];
  const int t = threadIdx.x;

  #pragma unroll 4
  for (int i = 0; i < 32; ++i) {
    int idx = i * 512 + t;
    int k = idx >> 8;
    int c = idx & 255;
    float v = Wm3[idx];
    int kg = k >> 2, kk = k & 3;
    sW3[c * 64 + (((kg ^ (c & 15)) & 15) << 2) + kk] = v;
  }
  __syncthreads();

  const int l = t & 63;
  const int wv = t >> 6;
  const int n = blockIdx.x * 8 + wv;
  const int row0 = offsets[n];
  const int row1 = offsets[n + 1];

  float* sHw = &sH[wv * 256];

  float wm1r[8];
  #pragma unroll
  for (int j = 0; j < 8; ++j) wm1r[j] = Wm1[j * 64 + l];

  float s0 = 0.f, s1 = 0.f;
  float v0x = 0.f, v0y = 0.f, v0z = 0.f;
  float v1x = 0.f, v1y = 0.f, v1z = 0.f;

  const int swz = ((l & 15) << 2);

  for (int i = row0; i < row1; i += 4) {
    const int nb = row1 - i;

    int   sn[4];
    float4 sh[4];
    #pragma unroll
    for (int b = 0; b < 4; ++b) {
      int idx = (b < nb) ? (i + b) : i;
      int e = csr_edge[idx];
      sn[b] = snd[e];
      float4 s = *(const float4*)(esh + (size_t)e * 4);
      if (b >= nb) s = make_float4(0.f, 0.f, 0.f, 0.f);
      sh[b] = s;
      float em8[8];
      ld8(em8, emb + (size_t)e * 8);
      float a = 0.f;
      #pragma unroll
      for (int j = 0; j < 8; ++j) a = fmaf(em8[j], wm1r[j], a);
      sHw[b * 64 + l] = swishf(a * 0.35355339059327373f);
    }

    float h2[4] = {0.f, 0.f, 0.f, 0.f};
    #pragma unroll 4
    for (int q = 0; q < 16; ++q) {
      float wq0 = Wm2[(4 * q + 0) * 64 + l];
      float wq1 = Wm2[(4 * q + 1) * 64 + l];
      float wq2 = Wm2[(4 * q + 2) * 64 + l];
      float wq3 = Wm2[(4 * q + 3) * 64 + l];
      #pragma unroll
      for (int b = 0; b < 4; ++b) {
        float4 h = *(const float4*)&sHw[b * 64 + 4 * q];
        h2[b] = fmaf(h.x, wq0, h2[b]);
        h2[b] = fmaf(h.y, wq1, h2[b]);
        h2[b] = fmaf(h.z, wq2, h2[b]);
        h2[b] = fmaf(h.w, wq3, h2[b]);
      }
    }
    #pragma unroll
    for (int b = 0; b < 4; ++b)
      h2[b] = swishf(h2[b] * 0.125f);
    #pragma unroll
    for (int b = 0; b < 4; ++b)
      sHw[b * 64 + l] = h2[b];

    float w0[4]  = {0,0,0,0}, w1a[4] = {0,0,0,0};
    float w2a[4] = {0,0,0,0}, w3a[4] = {0,0,0,0};
    #pragma unroll 1
    for (int g = 0; g < 16; ++g) {
      int sbase = l * 64 + (((g << 2) ^ swz) & 63);
      float4 m0 = *(const float4*)&sW3[sbase];
      float4 m1 = *(const float4*)&sW3[sbase + 4096];
      float4 m2 = *(const float4*)&sW3[sbase + 8192];
      float4 m3 = *(const float4*)&sW3[sbase + 12288];
      #pragma unroll
      for (int b = 0; b < 4; ++b) {
        float4 hb = *(const float4*)&sHw[b * 64 + 4 * g];
        #pragma unroll
        for (int kk = 0; kk < 4; ++kk) {
          float bc = (&hb.x)[kk];
          w0[b]  = fmaf(bc, (&m0.x)[kk], w0[b]);
          w1a[b] = fmaf(bc, (&m1.x)[kk], w1a[b]);
          w2a[b] = fmaf(bc, (&m2.x)[kk], w2a[b]);
          w3a[b] = fmaf(bc, (&m3.x)[kk], w3a[b]);
        }
      }
    }

    #pragma unroll
    for (int b = 0; b < 4; ++b) {
      const float* yr = y + (size_t)sn[b] * 256;
      float e0 = yr[l];
      float ex = yr[64 + 3 * l], ey = yr[65 + 3 * l], ez = yr[66 + 3 * l];
      float4 s = sh[b];
      s0 = fmaf(w0[b] * e0, s.x, s0);
      s1 = fmaf(w3a[b], fmaf(ex, s.y, fmaf(ey, s.z, ez * s.w)), s1);
      float t2 = w1a[b] * e0;
      v0x = fmaf(t2, s.y, v0x); v0y = fmaf(t2, s.z, v0y); v0z = fmaf(t2, s.w, v0z);
      float t3 = w2a[b] * s.x;
      v1x = fmaf(t3, ex, v1x); v1y = fmaf(t3, ey, v1y); v1z = fmaf(t3, ez, v1z);
    }
  }

  const float SCL = 0.0078125f;
  const float C4  = 0.125f / (16.0f * 1.7320508075688772f);
  float* ar = agg + (size_t)n * 512;
  ar[l]       = s0 * SCL;
  ar[64 + l]  = s1 * C4;
  ar[128 + 3 * l]     = v0x * SCL;
  ar[128 + 3 * l + 1] = v0y * SCL;
  ar[128 + 3 * l + 2] = v0z * SCL;
  ar[320 + 3 * l]     = v1x * SCL;
  ar[320 + 3 * l + 1] = v1y * SCL;
  ar[320 + 3 * l + 2] = v1z * SCL;
}

// ---------------- tier-3: atomic edge kernel ----------------
__global__ __launch_bounds__(256) void edge_kernel(
    const float* __restrict__ y, const float* __restrict__ edge_sh,
    const int* __restrict__ senders, const int* __restrict__ receivers,
    const float* __restrict__ emb, const float* __restrict__ Wm1,
    const float* __restrict__ Wm2, const float* __restrict__ Wm3,
    float* __restrict__ agg)
{
  __shared__ float h2s[64 * 256];
  const int tid = threadIdx.x;
  const int e = blockIdx.x * 256 + tid;
  const int s = senders[e];
  const int r = receivers[e];
  const float4 shv = *(const float4*)(edge_sh + (size_t)e * 4);
  float e8[8];
  ld8(e8, emb + (size_t)e * 8);

  float h2a[64];
  #pragma unroll
  for (int v = 0; v < 64; ++v) h2a[v] = 0.f;
  #pragma unroll 2
  for (int k = 0; k < 64; ++k) {
    float a = 0.f;
    #pragma unroll
    for (int j = 0; j < 8; ++j) a = fmaf(e8[j], Wm1[j * 64 + k], a);
    float h1k = swishf(a * 0.35355339059327373f);
    const float* wrow = Wm2 + k * 64;
    #pragma unroll
    for (int v = 0; v < 64; ++v) h2a[v] = fmaf(h1k, wrow[v], h2a[v]);
  }
  #pragma unroll
  for (int v = 0; v < 64; ++v)
    h2s[v * 256 + tid] = swishf(h2a[v] * 0.125f);

  const float* yrow = y + (size_t)s * 256;
  float* aggr = agg + (size_t)r * 512;
  const float SCL = 0.0078125f;
  const float c0  = shv.x * SCL;
  const float c1x = shv.y * SCL, c1y = shv.z * SCL, c1z = shv.w * SCL;
  const float c4  = 0.125f / (16.0f * 1.7320508075688772f);

  float wa[64];

  wgemv(wa, Wm3, h2s + tid, 0);
  #pragma unroll
  for (int uc = 0; uc < 8; ++uc) {
    float ev[8];
    ld8(ev, yrow + uc * 8);
    #pragma unroll
    for (int j = 0; j < 8; ++j) {
      int u = uc * 8 + j;
      atomicAdd(&aggr[u], wa[u] * ev[j] * c0);
    }
  }
  wgemv(wa, Wm3, h2s + tid, 1);
  #pragma unroll
  for (int uc = 0; uc < 8; ++uc) {
    float ev[8];
    ld8(ev, yrow + uc * 8);
    #pragma unroll
    for (int j = 0; j < 8; ++j) {
      int u = uc * 8 + j;
      float tt = wa[u] * ev[j];
      atomicAdd(&aggr[128 + 3 * u    ], tt * c1x);
      atomicAdd(&aggr[128 + 3 * u + 1], tt * c1y);
      atomicAdd(&aggr[128 + 3 * u + 2], tt * c1z);
    }
  }
  wgemv(wa, Wm3, h2s + tid, 2);
  #pragma unroll
  for (int uc = 0; uc < 8; ++uc) {
    float ev[24];
    ld8(ev,      yrow + 64 + uc * 24);
    ld8(ev + 8,  yrow + 64 + uc * 24 + 8);
    ld8(ev + 16, yrow + 64 + uc * 24 + 16);
    #pragma unroll
    for (int j = 0; j < 8; ++j) {
      int u = uc * 8 + j;
      float tt = wa[u] * c0;
      atomicAdd(&aggr[320 + 3 * u    ], tt * ev[3 * j    ]);
      atomicAdd(&aggr[320 + 3 * u + 1], tt * ev[3 * j + 1]);
      atomicAdd(&aggr[320 + 3 * u + 2], tt * ev[3 * j + 2]);
    }
  }
  wgemv(wa, Wm3, h2s + tid, 3);
  #pragma unroll
  for (int uc = 0; uc < 8; ++uc) {
    float ev[24];
    ld8(ev,      yrow + 64 + uc * 24);
    ld8(ev + 8,  yrow + 64 + uc * 24 + 8);
    ld8(ev + 16, yrow + 64 + uc * 24 + 16);
    #pragma unroll
    for (int j = 0; j < 8; ++j) {
      int u = uc * 8 + j;
      float d = ev[3*j]*shv.y + ev[3*j+1]*shv.z + ev[3*j+2]*shv.w;
      atomicAdd(&aggr[64 + u], wa[u] * d * c4);
    }
  }
}

// ---------------- VALU node_post (tier-2/3 fallback) ----------------
__global__ __launch_bounds__(256) void node_post(
    const float* __restrict__ feats, const float* __restrict__ attrs,
    const float* __restrict__ agg, const float* __restrict__ W2s,
    const float* __restrict__ W2v, const float* __restrict__ Wr_s,
    const float* __restrict__ Wr_v, float* __restrict__ out)
{
  __shared__ __align__(16) float sA[320 * 8];
  __shared__ __align__(16) float sX0[64 * 8];
  __shared__ __align__(16) float sX1[192 * 8];
  __shared__ __align__(16) float sAt[5 * 8];
  __shared__ __align__(16) float sAggS[128 * 8];
  __shared__ __align__(16) float sAggV[384 * 8];
  __shared__ __align__(16) float sZs[8 * 128];
  __shared__ __align__(16) float sZv[8 * 192];

  const int t = threadIdx.x;
  const int n0 = blockIdx.x * 8;
  const float nr = 0.05590169943749474f;
  const float n2 = 0.08838834764831845f;

  #pragma unroll
  for (int nb = 0; nb < 8; ++nb) {
    float v = feats[(size_t)(n0 + nb) * 256 + t];
    if (t < 64) sX0[t * 8 + nb] = v;
    else        sX1[(t - 64) * 8 + nb] = v;
  }
  if (t < 40) {
    int nb = t & 7, s = t >> 3;
    sAt[s * 8 + nb] = attrs[(size_t)(n0 + nb) * 5 + s] * nr;
  }
  #pragma unroll
  for (int i = 0; i < 16; ++i) {
    int idx = i * 256 + t;
    int nb = idx >> 9;
    int c = idx & 511;
    float v = agg[(size_t)(n0 + nb) * 512 + c] * n2;
    if (c < 128) sAggS[c * 8 + nb] = v;
    else         sAggV[(c - 128) * 8 + nb] = v;
  }
  __syncthreads();

  #pragma unroll
  for (int i = 0; i < 10; ++i) {
    int idx = i * 256 + t;
    int nb = idx & 7;
    int us = idx >> 3;
    int u = us / 5;
    int s = us - u * 5;
    sA[us * 8 + nb] = sX0[u * 8 + nb] * sAt[s * 8 + nb];
  }
  __syncthreads();

  float av[8][3];

  if (t < 128) {
    const int v = t;
    float acc[8];
    #pragma unroll
    for (int nb = 0; nb < 8; ++nb) acc[nb] = 0.f;
    for (int us = 0; us < 320; ++us)
      fma8v(acc, &sA[us * 8], Wr_s[us * 128 + v]);
    for (int c = 0; c < 128; ++c)
      fma8v(acc, &sAggS[c * 8], W2s[c * 128 + v]);
    #pragma unroll
    for (int nb = 0; nb < 8; ++nb) sZs[nb * 128 + v] = acc[nb];
  } else {
    const int tv = t - 128;
    const int v = tv & 63;
    const int half = tv >> 6;
    #pragma unroll
    for (int nb = 0; nb < 8; ++nb)
      #pragma unroll
      for (int m = 0; m < 3; ++m) av[nb][m] = 0.f;

    const int u0 = half * 32;
    for (int u = u0; u < u0 + 32; ++u) {
      float xr0[8], xr1[8], xr2[8];
      ld8(xr0, &sX1[(u * 3 + 0) * 8]);
      ld8(xr1, &sX1[(u * 3 + 1) * 8]);
      ld8(xr2, &sX1[(u * 3 + 2) * 8]);
      #pragma unroll
      for (int s = 0; s < 5; ++s) {
        float w = Wr_v[(u * 5 + s) * 64 + v];
        float at[8];
        ld8(at, &sAt[s * 8]);
        #pragma unroll
        for (int nb = 0; nb < 8; ++nb) {
          float tt = at[nb] * w;
          av[nb][0] = fmaf(xr0[nb], tt, av[nb][0]);
          av[nb][1] = fmaf(xr1[nb], tt, av[nb][1]);
          av[nb][2] = fmaf(xr2[nb], tt, av[nb][2]);
        }
      }
    }
    const int c0 = half * 64;
    for (int c = c0; c < c0 + 64; ++c) {
      float w = W2v[c * 64 + v];
      float g0[8], g1[8], g2[8];
      ld8(g0, &sAggV[(c * 3 + 0) * 8]);
      ld8(g1, &sAggV[(c * 3 + 1) * 8]);
      ld8(g2, &sAggV[(c * 3 + 2) * 8]);
      #pragma unroll
      for (int nb = 0; nb < 8; ++nb) {
        av[nb][0] = fmaf(g0[nb], w, av[nb][0]);
        av[nb][1] = fmaf(g1[nb], w, av[nb][1]);
        av[nb][2] = fmaf(g2[nb], w, av[nb][2]);
      }
    }
    if (half == 0) {
      #pragma unroll
      for (int nb = 0; nb < 8; ++nb)
        #pragma unroll
        for (int m = 0; m < 3; ++m)
          sZv[nb * 192 + v * 3 + m] = av[nb][m];
    }
  }
  __syncthreads();
  if (t >= 192) {
    const int v = (t - 128) & 63;
    #pragma unroll
    for (int nb = 0; nb < 8; ++nb)
      #pragma unroll
      for (int m = 0; m < 3; ++m)
        sZv[nb * 192 + v * 3 + m] += av[nb][m];
  }
  __syncthreads();

  const int i = t - 64;
  const int ug = (t >= 64) ? (i / 3) : 0;
  #pragma unroll
  for (int nb = 0; nb < 8; ++nb) {
    float val;
    if (t < 64) {
      val = swishf(sZs[nb * 128 + t]);
    } else {
      float gate = swishf(sZs[nb * 128 + 64 + ug]);
      val = gate * sZv[nb * 192 + i];
    }
    out[(size_t)(n0 + nb) * 256 + t] = val;
  }
}

extern "C" void kernel_launch(void* const* d_in, const int* in_sizes, int n_in,
                              void* d_out, int out_size, void* d_ws, size_t ws_size,
                              hipStream_t stream)
{
  const float* feats = (const float*)d_in[0];
  const float* attrs = (const float*)d_in[1];
  const float* esh   = (const float*)d_in[2];
  const int*   snd   = (const int*)d_in[3];
  const int*   rcv   = (const int*)d_in[4];
  const float* emb   = (const float*)d_in[5];
  const float* Wl0   = (const float*)d_in[6];
  const float* Wl1   = (const float*)d_in[7];
  const float* Wm1   = (const float*)d_in[8];
  const float* Wm2   = (const float*)d_in[9];
  const float* Wm3   = (const float*)d_in[10];
  const float* W2s   = (const float*)d_in[11];
  const float* W2v   = (const float*)d_in[12];
  const float* Wr_s  = (const float*)d_in[13];
  const float* Wr_v  = (const float*)d_in[14];
  float* out = (float*)d_out;

  float* y   = (float*)d_ws;                     // NN*256 f32
  float* agg = y + (size_t)NN * 256;             // NN*512 f32
  int* counts = (int*)agg;                       // aliased transients
  int* cursor = counts + NN;
  int* csr_edge = (int*)(agg + (size_t)NN * 512);   // NE ints
  int* offsets  = csr_edge + NE;                    // NN+1 ints
  int* snd_sorted = offsets + NN + 1;               // NE ints
  float* sh_sorted = (float*)(snd_sorted + NE);     // NE*4 f32
  __half* w_sorted = (__half*)(sh_sorted + (size_t)NE * 4);  // NE*256 f16
  unsigned* Wm2P = (unsigned*)(w_sorted + (size_t)NE * 256); // 2048 u32
  unsigned* Wm3P = Wm2P + 2048;                              // 8192 u32
  unsigned* Wm3T = Wm3P + 8192;                              // 8192 u32
  unsigned* BsT  = Wm3T + 8192;                              // 28672 u32
  unsigned* BvT  = BsT + 28672;                              // 14336 u32
  float* zs = y;                                  // NN*128 f32 (y dead)
  float* zv = (float*)w_sorted;                   // 60000*64 f32 (w dead)
  size_t need1 = (size_t)((char*)(BvT + 14336) - (char*)d_ws);
  size_t need2 = (size_t)((char*)(offsets + NN + 1) - (char*)d_ws);

  if (ws_size >= need1) {
    hipMemsetAsync(counts, 0, (size_t)NN * sizeof(int), stream);
    hist_kernel<<<NE / 256, 256, 0, stream>>>(rcv, counts);
    scan_kernel<<<1, 1024, 0, stream>>>(counts, offsets, cursor);
    scatter_full<<<NE / 256, 256, 0, stream>>>(rcv, snd, esh, cursor,
                                               csr_edge, snd_sorted, sh_sorted);
    pack_weights<<<72, 256, 0, stream>>>(Wm2, Wm3, Wm2P, Wm3P, Wm3T);
    pack_node_B<<<168, 256, 0, stream>>>(Wr_s, W2s, Wr_v, W2v, BsT, BvT);
    node_prep<<<NN / 4, 256, 0, stream>>>(feats, Wl0, Wl1, y);
    w_kernel<<<NE / 256, 256, 0, stream>>>(csr_edge, emb, Wm1, Wm2P, Wm3T, w_sorted);
    gather_tp<<<NN / 4, 256, 0, stream>>>(y, w_sorted, sh_sorted, snd_sorted,
                                          offsets, agg);
    node_gemm<<<NN / 16, 256, 0, stream>>>(feats, attrs, agg, BsT, BvT, zs, zv);
    gate_kernel<<<NN, 256, 0, stream>>>(zs, zv, out);
  } else if (ws_size >= need2) {
    hipMemsetAsync(counts, 0, (size_t)NN * sizeof(int), stream);
    hist_kernel<<<NE / 256, 256, 0, stream>>>(rcv, counts);
    scan_kernel<<<1, 1024, 0, stream>>>(counts, offsets, cursor);
    scatter_kernel<<<NE / 256, 256, 0, stream>>>(rcv, cursor, csr_edge);
    node_prep<<<NN / 4, 256, 0, stream>>>(feats, Wl0, Wl1, y);
    gather_fused<<<NN / 8, 512, 0, stream>>>(y, csr_edge, snd, esh, emb,
                                             Wm1, Wm2, Wm3, offsets, agg);
    node_post<<<NN / 8, 256, 0, stream>>>(feats, attrs, agg, W2s, W2v, Wr_s, Wr_v, out);
  } else {
    hipMemsetAsync(agg, 0, (size_t)NN * 512 * sizeof(float), stream);
    node_prep<<<NN / 4, 256, 0, stream>>>(feats, Wl0, Wl1, y);
    edge_kernel<<<NE / 256, 256, 0, stream>>>(y, esh, snd, rcv, emb, Wm1, Wm2, Wm3, agg);
    node_post<<<NN / 8, 256, 0, stream>>>(feats, attrs, agg, W2s, W2v, Wr_s, Wr_v, out);
  }
}

// Round 16
// 352.353 us; speedup vs baseline: 1.0858x; 1.0858x over previous
//
#include <hip/hip_runtime.h>
#include <hip/hip_fp16.h>

// NequIP-style layer, f32.
// Tier 1 (~234MB ws): CSR sort -> pack_weights/pack_node_B -> node_prep ->
//   w_kernel (dot2 MLP + MFMA w-GEMM; wave-private LDS store-staging ->
//   full-sector 128B-per-row global stores) -> gather_tp -> node_gemm ->
//   gate_kernel.
// Tier 2 (~62.8MB ws): r7 fused gather + VALU node_post.
// Tier 3 (~61.4MB ws): atomic kernel + VALU node_post.

#define NN 20000
#define NE 320000

typedef _Float16 h2v __attribute__((ext_vector_type(2)));
typedef _Float16 f16x8 __attribute__((ext_vector_type(8)));
typedef float f32x4 __attribute__((ext_vector_type(4)));

__device__ __forceinline__ float swishf(float x) {
  float t = __expf(-fabsf(x));
  float r = 1.0f / (1.0f + t);
  float sig = (x >= 0.0f) ? r : t * r;
  return x * sig;
}

__device__ __forceinline__ unsigned pack2h(float a, float b) {
  __half2 h = __floats2half2_rn(a, b);
  return *reinterpret_cast<unsigned*>(&h);
}

__device__ __forceinline__ h2v u32h2(unsigned u) {
  union { unsigned u; h2v h; } x; x.u = u; return x.h;
}

__device__ __forceinline__ h2v packh2v(float a, float b) {
  h2v h; h.x = (_Float16)a; h.y = (_Float16)b; return h;
}

__device__ __forceinline__ f16x8 u4f16(uint4 u) {
  union { uint4 u; f16x8 h; } x; x.u = u; return x.h;
}

__device__ __forceinline__ void ld8(float d[8], const float* p) {
  float4 a0 = *(const float4*)p;
  float4 a1 = *(const float4*)(p + 4);
  d[0]=a0.x; d[1]=a0.y; d[2]=a0.z; d[3]=a0.w;
  d[4]=a1.x; d[5]=a1.y; d[6]=a1.z; d[7]=a1.w;
}

__device__ __forceinline__ void fma8v(float (&acc)[8], const float* p, float w) {
  float4 a0 = *(const float4*)p;
  float4 a1 = *(const float4*)(p + 4);
  acc[0] = fmaf(a0.x, w, acc[0]); acc[1] = fmaf(a0.y, w, acc[1]);
  acc[2] = fmaf(a0.z, w, acc[2]); acc[3] = fmaf(a0.w, w, acc[3]);
  acc[4] = fmaf(a1.x, w, acc[4]); acc[5] = fmaf(a1.y, w, acc[5]);
  acc[6] = fmaf(a1.z, w, acc[6]); acc[7] = fmaf(a1.w, w, acc[7]);
}

// ---------------- CSR build ----------------
__global__ __launch_bounds__(256) void hist_kernel(const int* __restrict__ rcv,
                                                   int* __restrict__ counts) {
  int e = blockIdx.x * 256 + threadIdx.x;
  atomicAdd(&counts[rcv[e]], 1);
}

__global__ __launch_bounds__(1024) void scan_kernel(const int* __restrict__ counts,
                                                    int* __restrict__ offsets,
                                                    int* __restrict__ cursor) {
  __shared__ int part[1024];
  const int t = threadIdx.x;
  const int base = t * 20;
  int loc[20];
  int s = 0;
  #pragma unroll
  for (int j = 0; j < 20; ++j) {
    int idx = base + j;
    int c = (idx < NN) ? counts[idx] : 0;
    loc[j] = s;
    s += c;
  }
  part[t] = s;
  __syncthreads();
  for (int d = 1; d < 1024; d <<= 1) {
    int v = (t >= d) ? part[t - d] : 0;
    __syncthreads();
    part[t] += v;
    __syncthreads();
  }
  int excl = (t > 0) ? part[t - 1] : 0;
  #pragma unroll
  for (int j = 0; j < 20; ++j) {
    int idx = base + j;
    if (idx < NN) {
      int o = excl + loc[j];
      offsets[idx] = o;
      cursor[idx] = o;
    }
  }
  if (t == 1023) offsets[NN] = part[1023];
}

__global__ __launch_bounds__(256) void scatter_full(
    const int* __restrict__ rcv, const int* __restrict__ snd,
    const float* __restrict__ esh, int* __restrict__ cursor,
    int* __restrict__ csr_edge, int* __restrict__ snd_sorted,
    float* __restrict__ sh_sorted) {
  int e = blockIdx.x * 256 + threadIdx.x;
  int r = rcv[e];
  int pos = atomicAdd(&cursor[r], 1);
  csr_edge[pos] = e;
  snd_sorted[pos] = snd[e];
  float4 sh = *(const float4*)(esh + (size_t)e * 4);
  *(float4*)(sh_sorted + (size_t)pos * 4) = sh;
}

__global__ __launch_bounds__(256) void scatter_kernel(
    const int* __restrict__ rcv, int* __restrict__ cursor,
    int* __restrict__ csr_edge) {
  int e = blockIdx.x * 256 + threadIdx.x;
  int r = rcv[e];
  int pos = atomicAdd(&cursor[r], 1);
  csr_edge[pos] = e;
}

// ---------------- pack Wm2/Wm3 into f16 k-pair tables ----------------
__global__ __launch_bounds__(256) void pack_weights(
    const float* __restrict__ Wm2, const float* __restrict__ Wm3,
    unsigned* __restrict__ Wm2P, unsigned* __restrict__ Wm3P,
    unsigned* __restrict__ Wm3T) {
  int idx = blockIdx.x * 256 + threadIdx.x;
  if (idx < 2048) {
    int k2 = idx >> 6, v = idx & 63;
    Wm2P[idx] = pack2h(Wm2[(2 * k2) * 64 + v], Wm2[(2 * k2 + 1) * 64 + v]);
  } else if (idx < 10240) {
    int r = idx - 2048;
    int k2 = r >> 8, c = r & 255;
    Wm3P[r] = pack2h(Wm3[(2 * k2) * 256 + c], Wm3[(2 * k2 + 1) * 256 + c]);
  } else if (idx < 18432) {
    int r = idx - 10240;
    int c = r >> 5, j = r & 31;
    Wm3T[r] = pack2h(Wm3[(2 * j) * 256 + c], Wm3[(2 * j + 1) * 256 + c]);
  }
}

// ---------------- pack node-side B^T tables (scales folded) ----------------
__global__ __launch_bounds__(256) void pack_node_B(
    const float* __restrict__ Wr_s, const float* __restrict__ W2s,
    const float* __restrict__ Wr_v, const float* __restrict__ W2v,
    unsigned* __restrict__ BsT, unsigned* __restrict__ BvT) {
  const float nr = 0.05590169943749474f;   // 1/sqrt(320)
  const float n2 = 0.08838834764831845f;   // 1/sqrt(128)
  int idx = blockIdx.x * 256 + threadIdx.x;
  if (idx < 28672) {
    int v = idx / 224, j = idx % 224;
    float a, b;
    if (j < 160) {
      int s = j >> 5, u0 = (j & 31) << 1;
      a = Wr_s[(u0 * 5 + s) * 128 + v] * nr;
      b = Wr_s[((u0 + 1) * 5 + s) * 128 + v] * nr;
    } else {
      int c0 = (j - 160) << 1;
      a = W2s[c0 * 128 + v] * n2;
      b = W2s[(c0 + 1) * 128 + v] * n2;
    }
    BsT[idx] = pack2h(a, b);
  } else if (idx < 43008) {
    int r = idx - 28672;
    int v = r / 224, j = r % 224;
    float a, b;
    if (j < 160) {
      int s = j >> 5, u0 = (j & 31) << 1;
      a = Wr_v[(u0 * 5 + s) * 64 + v] * nr;
      b = Wr_v[((u0 + 1) * 5 + s) * 64 + v] * nr;
    } else {
      int c0 = (j - 160) << 1;
      a = W2v[c0 * 64 + v] * n2;
      b = W2v[(c0 + 1) * 64 + v] * n2;
    }
    BvT[r] = pack2h(a, b);
  }
}

// ---------------- node_prep: y = [x0@Wl0, x1@Wl1] * nl ----------------
__global__ __launch_bounds__(256) void node_prep(
    const float* __restrict__ feats, const float* __restrict__ Wl0,
    const float* __restrict__ Wl1, float* __restrict__ y)
{
  __shared__ __align__(16) float sX[4 * 256];
  const int t = threadIdx.x;
  const int n0 = blockIdx.x * 4;
  #pragma unroll
  for (int nb = 0; nb < 4; ++nb)
    sX[nb * 256 + t] = feats[(size_t)(n0 + nb) * 256 + t];
  __syncthreads();

  float acc[4] = {0.f, 0.f, 0.f, 0.f};
  if (t < 64) {
    const int v = t;
    for (int u = 0; u < 64; ++u) {
      float w = Wl0[u * 64 + v];
      acc[0] = fmaf(sX[0 * 256 + u], w, acc[0]);
      acc[1] = fmaf(sX[1 * 256 + u], w, acc[1]);
      acc[2] = fmaf(sX[2 * 256 + u], w, acc[2]);
      acc[3] = fmaf(sX[3 * 256 + u], w, acc[3]);
    }
  } else {
    const int i = t - 64;
    const int v = i / 3;
    const int m = i - v * 3;
    for (int u = 0; u < 64; ++u) {
      float w = Wl1[u * 64 + v];
      int xi = 64 + u * 3 + m;
      acc[0] = fmaf(sX[0 * 256 + xi], w, acc[0]);
      acc[1] = fmaf(sX[1 * 256 + xi], w, acc[1]);
      acc[2] = fmaf(sX[2 * 256 + xi], w, acc[2]);
      acc[3] = fmaf(sX[3 * 256 + xi], w, acc[3]);
    }
  }
  #pragma unroll
  for (int nb = 0; nb < 4; ++nb)
    y[(size_t)(n0 + nb) * 256 + t] = acc[nb] * 0.125f;   // nl = 1/sqrt(64)
}

// GEMV helper (fallback paths, f32)
__device__ __forceinline__ void wgemv(float (&wa)[64], const float* __restrict__ Wm3,
                                      const float* h2col, int p)
{
  #pragma unroll
  for (int v = 0; v < 64; ++v) wa[v] = 0.f;
  #pragma unroll 2
  for (int k = 0; k < 64; ++k) {
    float h2k = h2col[k * 256];
    const float* wrow = Wm3 + k * 256 + p * 64;
    #pragma unroll
    for (int v = 0; v < 64; ++v) wa[v] = fmaf(h2k, wrow[v], wa[v]);
  }
}

// ---------------- tier-1 phase A: MLP h2 (dot2) + MFMA w-GEMM ----------------
// D = Wm3T x h2 (lane: 4 consecutive w-cols of one edge). Results staged in a
// wave-private 8KB LDS slab (reuses sA after h2-frags are in regs), drained as
// 128B-per-edge-row global stores (8 lanes cover one row -> full sectors).
__global__ __launch_bounds__(256, 4) void w_kernel(
    const int* __restrict__ csr_edge, const float* __restrict__ emb,
    const float* __restrict__ Wm1, const unsigned* __restrict__ Wm2P,
    const unsigned* __restrict__ Wm3T, __half* __restrict__ w_sorted)
{
  __shared__ unsigned sA[256 * 32];   // h2 f16 [edge][k2] swizzled; then slabs
  const int tid = threadIdx.x;
  const int i = blockIdx.x * 256 + tid;
  const int e = csr_edge[i];

  float e8[8];
  ld8(e8, emb + (size_t)e * 8);
  float h2a[64];
  #pragma unroll
  for (int v = 0; v < 64; ++v) h2a[v] = 0.f;
  #pragma unroll 1
  for (int k2 = 0; k2 < 32; ++k2) {
    float a0 = 0.f, a1 = 0.f;
    #pragma unroll
    for (int j = 0; j < 8; ++j) {
      a0 = fmaf(e8[j], Wm1[j * 64 + 2 * k2], a0);
      a1 = fmaf(e8[j], Wm1[j * 64 + 2 * k2 + 1], a1);
    }
    h2v ph = packh2v(swishf(a0 * 0.35355339059327373f),
                     swishf(a1 * 0.35355339059327373f));
    const unsigned* wrow = Wm2P + k2 * 64;
    #pragma unroll
    for (int v = 0; v < 64; ++v)
      h2a[v] = __builtin_amdgcn_fdot2(ph, u32h2(wrow[v]), h2a[v], false);
  }
  {
    const int r = tid;
    #pragma unroll
    for (int c = 0; c < 8; ++c) {
      uint4 v;
      v.x = pack2h(swishf(h2a[8 * c + 0] * 0.125f), swishf(h2a[8 * c + 1] * 0.125f));
      v.y = pack2h(swishf(h2a[8 * c + 2] * 0.125f), swishf(h2a[8 * c + 3] * 0.125f));
      v.z = pack2h(swishf(h2a[8 * c + 4] * 0.125f), swishf(h2a[8 * c + 5] * 0.125f));
      v.w = pack2h(swishf(h2a[8 * c + 6] * 0.125f), swishf(h2a[8 * c + 7] * 0.125f));
      *(uint4*)&sA[r * 32 + ((c ^ (r & 7)) << 2)] = v;
    }
  }
  __syncthreads();

  const int l = tid & 63;
  const int wv = tid >> 6;
  const int lg = l >> 4;
  const int lm = l & 15;

  // B-frags: this wave's 64 edges (validated fragment pattern)
  f16x8 bfr[4][2];
  #pragma unroll
  for (int nt = 0; nt < 4; ++nt) {
    int row = wv * 64 + nt * 16 + lm;
    #pragma unroll
    for (int kh = 0; kh < 2; ++kh) {
      uint4 u = *(const uint4*)&sA[row * 32 + ((((kh << 2) + lg) ^ (row & 7)) << 2)];
      bfr[nt][kh] = u4f16(u);
    }
  }
  // sA now dead for this wave's rows -> wave-private slab (64 rows x 32 u32)
  unsigned* sTw = sA + wv * 2048;
  const int eb = blockIdx.x * 256 + wv * 64;

  #pragma unroll 1
  for (int p = 0; p < 4; ++p) {
    #pragma unroll
    for (int mtl = 0; mtl < 4; ++mtl) {
      const int mt = p * 4 + mtl;
      int arow = mt * 16 + lm;            // w-col row in Wm3T
      uint4 u0 = *(const uint4*)&Wm3T[arow * 32 + (lg << 2)];
      uint4 u1 = *(const uint4*)&Wm3T[arow * 32 + 16 + (lg << 2)];
      f16x8 a0 = u4f16(u0), a1 = u4f16(u1);
      #pragma unroll
      for (int nt = 0; nt < 4; ++nt) {
        f32x4 acc = {0.f, 0.f, 0.f, 0.f};
        acc = __builtin_amdgcn_mfma_f32_16x16x32_f16(a0, bfr[nt][0], acc, 0, 0, 0);
        acc = __builtin_amdgcn_mfma_f32_16x16x32_f16(a1, bfr[nt][1], acc, 0, 0, 0);
        // D: cols p*64 + u*4 + {0..3} (u = mtl*4+lg) of edge r = nt*16+lm
        const int r = nt * 16 + lm;
        const int u = mtl * 4 + lg;
        const int pos8 = ((((u >> 1) ^ (r & 7)) << 1) | (u & 1));
        uint2 pk;
        pk.x = pack2h(acc[0], acc[1]);
        pk.y = pack2h(acc[2], acc[3]);
        *(uint2*)&sTw[r * 32 + pos8 * 2] = pk;
      }
    }
    // drain group p: pass g, lane handles edge er = g*8 + (l>>3), chunk c8 = l&7
    #pragma unroll
    for (int g = 0; g < 8; ++g) {
      const int er = g * 8 + (l >> 3);
      const int c8 = l & 7;
      uint4 v = *(const uint4*)&sTw[er * 32 + ((c8 ^ (er & 7)) << 2)];
      *(uint4*)(w_sorted + (size_t)(eb + er) * 256 + p * 64 + c8 * 8) = v;
    }
  }
}

// ---------------- tier-1 phase B: per-node gather + tensor product ----------
__global__ __launch_bounds__(256) void gather_tp(
    const float* __restrict__ y, const __half* __restrict__ w_sorted,
    const float* __restrict__ sh_sorted, const int* __restrict__ snd_sorted,
    const int* __restrict__ offsets, float* __restrict__ agg)
{
  const int l = threadIdx.x & 63;
  const int wv = threadIdx.x >> 6;
  const int n = blockIdx.x * 4 + wv;
  const int row0 = offsets[n];
  const int row1 = offsets[n + 1];

  float s0 = 0.f, s1 = 0.f;
  float v0x = 0.f, v0y = 0.f, v0z = 0.f;
  float v1x = 0.f, v1y = 0.f, v1z = 0.f;

  for (int i = row0; i < row1; ++i) {
    const int s = snd_sorted[i];
    const float4 sh = *(const float4*)(sh_sorted + (size_t)i * 4);
    const __half* wr = w_sorted + (size_t)i * 256;
    float w1 = __half2float(wr[l]);
    float w2 = __half2float(wr[64 + l]);
    float w3 = __half2float(wr[128 + l]);
    float w4 = __half2float(wr[192 + l]);
    const float* yr = y + (size_t)s * 256;
    float e0 = yr[l];
    float ex = yr[64 + 3 * l], ey = yr[65 + 3 * l], ez = yr[66 + 3 * l];

    s0 = fmaf(w1 * e0, sh.x, s0);
    s1 = fmaf(w4, fmaf(ex, sh.y, fmaf(ey, sh.z, ez * sh.w)), s1);
    float t2 = w2 * e0;
    v0x = fmaf(t2, sh.y, v0x); v0y = fmaf(t2, sh.z, v0y); v0z = fmaf(t2, sh.w, v0z);
    float t3 = w3 * sh.x;
    v1x = fmaf(t3, ex, v1x); v1y = fmaf(t3, ey, v1y); v1z = fmaf(t3, ez, v1z);
  }

  const float SCL = 0.0078125f;                          // (1/8 w-scale) / 16
  const float C4  = 0.125f / (16.0f * 1.7320508075688772f);
  float* ar = agg + (size_t)n * 512;
  ar[l]       = s0 * SCL;
  ar[64 + l]  = s1 * C4;
  ar[128 + 3 * l]     = v0x * SCL;
  ar[128 + 3 * l + 1] = v0y * SCL;
  ar[128 + 3 * l + 2] = v0z * SCL;
  ar[320 + 3 * l]     = v1x * SCL;
  ar[320 + 3 * l + 1] = v1y * SCL;
  ar[320 + 3 * l + 2] = v1z * SCL;
}

// ---------------- tier-1: node-side MFMA GEMM ----------------
__global__ __launch_bounds__(256) void node_gemm(
    const float* __restrict__ feats, const float* __restrict__ attrs,
    const float* __restrict__ agg, const unsigned* __restrict__ BsT,
    const unsigned* __restrict__ BvT, float* __restrict__ zs,
    float* __restrict__ zv)
{
  __shared__ unsigned sAK[64 * 224];   // 57344B
  __shared__ float sX[16 * 257];       // padded
  __shared__ float sAt[16 * 5];
  const int t = threadIdx.x;
  const int n0 = blockIdx.x * 16;

  #pragma unroll
  for (int nb = 0; nb < 16; ++nb)
    sX[nb * 257 + t] = feats[(size_t)(n0 + nb) * 256 + t];
  if (t < 80) sAt[t] = attrs[(size_t)n0 * 5 + t];
  __syncthreads();

  {
    const int row = t >> 2;
    const int part = t & 3;
    const bool is_s = row < 16;
    int node, m = 0;
    if (is_s) node = row;
    else { int vi = row - 16; node = vi / 3; m = vi - node * 3; }
    const float* xrow = &sX[node * 257];
    const float* atr = &sAt[node * 5];
    const float* aggr = agg + (size_t)(n0 + node) * 512;
    unsigned* arow = &sAK[row * 224];
    #pragma unroll 8
    for (int jj = 0; jj < 56; ++jj) {
      const int j = part + 4 * jj;
      float v0, v1;
      if (jj < 40) {
        int s = j >> 5;
        int u0 = (j & 31) << 1;
        float a = atr[s];
        float x0 = is_s ? xrow[u0]     : xrow[64 + 3 * u0 + m];
        float x1 = is_s ? xrow[u0 + 1] : xrow[64 + 3 * u0 + 3 + m];
        v0 = x0 * a;
        v1 = x1 * a;
      } else {
        int c0 = (j - 160) << 1;
        if (is_s) { v0 = aggr[c0]; v1 = aggr[c0 + 1]; }
        else {
          v0 = aggr[128 + 3 * c0 + m];
          v1 = aggr[128 + 3 * c0 + 3 + m];
        }
      }
      int chs = (jj & ~7) | ((jj ^ row) & 7);
      arow[(chs << 2) + part] = pack2h(v0, v1);
    }
  }
  __syncthreads();

  const int l = t & 63;
  const int wv = t >> 6;
  const int lm = l & 15;
  const int lg = l >> 4;

  #pragma unroll 1
  for (int jj = 0; jj < 5; ++jj) {
    const int jd = wv + 4 * jj;
    int mtile, ntile;
    const unsigned* Bt;
    if (jd < 8) { mtile = 0; ntile = jd; Bt = BsT; }
    else { int q = jd - 8; mtile = 1 + (q >> 2); ntile = q & 3; Bt = BvT; }

    const int arow0 = mtile * 16 + lm;
    const unsigned* brow = Bt + (ntile * 16 + lm) * 224;
    f32x4 acc = {0.f, 0.f, 0.f, 0.f};
    #pragma unroll 2
    for (int ks = 0; ks < 14; ++ks) {
      int ch = ks * 4 + lg;
      int chs = (ch & ~7) | ((ch ^ arow0) & 7);
      uint4 ua = *(const uint4*)&sAK[arow0 * 224 + (chs << 2)];
      uint4 ub = *(const uint4*)&brow[ch << 2];
      acc = __builtin_amdgcn_mfma_f32_16x16x32_f16(u4f16(ua), u4f16(ub), acc, 0, 0, 0);
    }
    const int drow = mtile * 16 + lg * 4;
    if (jd < 8) {
      #pragma unroll
      for (int rr = 0; rr < 4; ++rr)
        zs[(size_t)(n0 + drow + rr) * 128 + ntile * 16 + lm] = acc[rr];
    } else {
      const int vi0 = drow - 16;
      #pragma unroll
      for (int rr = 0; rr < 4; ++rr)
        zv[((size_t)blockIdx.x * 48 + vi0 + rr) * 64 + ntile * 16 + lm] = acc[rr];
    }
  }
}

// ---------------- tier-1: gating epilogue ----------------
__global__ __launch_bounds__(256) void gate_kernel(
    const float* __restrict__ zs, const float* __restrict__ zv,
    float* __restrict__ out)
{
  const int n = blockIdx.x;
  const int t = threadIdx.x;
  float val;
  if (t < 64) {
    val = swishf(zs[(size_t)n * 128 + t]);
  } else {
    int i = t - 64;
    int u = i / 3;
    int m = i - u * 3;
    float gate = swishf(zs[(size_t)n * 128 + 64 + u]);
    val = gate * zv[((size_t)n * 3 + m) * 64 + u];
  }
  out[(size_t)n * 256 + t] = val;
}

// ---------------- tier-2: r7 fused gather ----------------
__global__ __launch_bounds__(512, 2) void gather_fused(
    const float* __restrict__ y, const int* __restrict__ csr_edge,
    const int* __restrict__ snd, const float* __restrict__ esh,
    const float* __restrict__ emb, const float* __restrict__ Wm1,
    const float* __restrict__ Wm2, const float* __restrict__ Wm3,
    const int* __restrict__ offsets, float* __restrict__ agg)
{
  __shared__ __align__(16) float sW3[64 * 256];
  __shared__ __align__(16) float sH[8 * 4 * 64];
  const int t = threadIdx.x;

  #pragma unroll 4
  for (int i = 0; i < 32; ++i) {
    int idx = i * 512 + t;
    int k = idx >> 8;
    int c = idx & 255;
    float v = Wm3[idx];
    int kg = k >> 2, kk = k & 3;
    sW3[c * 64 + (((kg ^ (c & 15)) & 15) << 2) + kk] = v;
  }
  __syncthreads();

  const int l = t & 63;
  const int wv = t >> 6;
  const int n = blockIdx.x * 8 + wv;
  const int row0 = offsets[n];
  const int row1 = offsets[n + 1];

  float* sHw = &sH[wv * 256];

  float wm1r[8];
  #pragma unroll
  for (int j = 0; j < 8; ++j) wm1r[j] = Wm1[j * 64 + l];

  float s0 = 0.f, s1 = 0.f;
  float v0x = 0.f, v0y = 0.f, v0z = 0.f;
  float v1x = 0.f, v1y = 0.f, v1z = 0.f;

  const int swz = ((l & 15) << 2);

  for (int i = row0; i < row1; i += 4) {
    const int nb = row1 - i;

    int   sn[4];
    float4 sh[4];
    #pragma unroll
    for (int b = 0; b < 4; ++b) {
      int idx = (b < nb) ? (i + b) : i;
      int e = csr_edge[idx];
      sn[b] = snd[e];
      float4 s = *(const float4*)(esh + (size_t)e * 4);
      if (b >= nb) s = make_float4(0.f, 0.f, 0.f, 0.f);
      sh[b] = s;
      float em8[8];
      ld8(em8, emb + (size_t)e * 8);
      float a = 0.f;
      #pragma unroll
      for (int j = 0; j < 8; ++j) a = fmaf(em8[j], wm1r[j], a);
      sHw[b * 64 + l] = swishf(a * 0.35355339059327373f);
    }

    float h2[4] = {0.f, 0.f, 0.f, 0.f};
    #pragma unroll 4
    for (int q = 0; q < 16; ++q) {
      float wq0 = Wm2[(4 * q + 0) * 64 + l];
      float wq1 = Wm2[(4 * q + 1) * 64 + l];
      float wq2 = Wm2[(4 * q + 2) * 64 + l];
      float wq3 = Wm2[(4 * q + 3) * 64 + l];
      #pragma unroll
      for (int b = 0; b < 4; ++b) {
        float4 h = *(const float4*)&sHw[b * 64 + 4 * q];
        h2[b] = fmaf(h.x, wq0, h2[b]);
        h2[b] = fmaf(h.y, wq1, h2[b]);
        h2[b] = fmaf(h.z, wq2, h2[b]);
        h2[b] = fmaf(h.w, wq3, h2[b]);
      }
    }
    #pragma unroll
    for (int b = 0; b < 4; ++b)
      h2[b] = swishf(h2[b] * 0.125f);
    #pragma unroll
    for (int b = 0; b < 4; ++b)
      sHw[b * 64 + l] = h2[b];

    float w0[4]  = {0,0,0,0}, w1a[4] = {0,0,0,0};
    float w2a[4] = {0,0,0,0}, w3a[4] = {0,0,0,0};
    #pragma unroll 1
    for (int g = 0; g < 16; ++g) {
      int sbase = l * 64 + (((g << 2) ^ swz) & 63);
      float4 m0 = *(const float4*)&sW3[sbase];
      float4 m1 = *(const float4*)&sW3[sbase + 4096];
      float4 m2 = *(const float4*)&sW3[sbase + 8192];
      float4 m3 = *(const float4*)&sW3[sbase + 12288];
      #pragma unroll
      for (int b = 0; b < 4; ++b) {
        float4 hb = *(const float4*)&sHw[b * 64 + 4 * g];
        #pragma unroll
        for (int kk = 0; kk < 4; ++kk) {
          float bc = (&hb.x)[kk];
          w0[b]  = fmaf(bc, (&m0.x)[kk], w0[b]);
          w1a[b] = fmaf(bc, (&m1.x)[kk], w1a[b]);
          w2a[b] = fmaf(bc, (&m2.x)[kk], w2a[b]);
          w3a[b] = fmaf(bc, (&m3.x)[kk], w3a[b]);
        }
      }
    }

    #pragma unroll
    for (int b = 0; b < 4; ++b) {
      const float* yr = y + (size_t)sn[b] * 256;
      float e0 = yr[l];
      float ex = yr[64 + 3 * l], ey = yr[65 + 3 * l], ez = yr[66 + 3 * l];
      float4 s = sh[b];
      s0 = fmaf(w0[b] * e0, s.x, s0);
      s1 = fmaf(w3a[b], fmaf(ex, s.y, fmaf(ey, s.z, ez * s.w)), s1);
      float t2 = w1a[b] * e0;
      v0x = fmaf(t2, s.y, v0x); v0y = fmaf(t2, s.z, v0y); v0z = fmaf(t2, s.w, v0z);
      float t3 = w2a[b] * s.x;
      v1x = fmaf(t3, ex, v1x); v1y = fmaf(t3, ey, v1y); v1z = fmaf(t3, ez, v1z);
    }
  }

  const float SCL = 0.0078125f;
  const float C4  = 0.125f / (16.0f * 1.7320508075688772f);
  float* ar = agg + (size_t)n * 512;
  ar[l]       = s0 * SCL;
  ar[64 + l]  = s1 * C4;
  ar[128 + 3 * l]     = v0x * SCL;
  ar[128 + 3 * l + 1] = v0y * SCL;
  ar[128 + 3 * l + 2] = v0z * SCL;
  ar[320 + 3 * l]     = v1x * SCL;
  ar[320 + 3 * l + 1] = v1y * SCL;
  ar[320 + 3 * l + 2] = v1z * SCL;
}

// ---------------- tier-3: atomic edge kernel ----------------
__global__ __launch_bounds__(256) void edge_kernel(
    const float* __restrict__ y, const float* __restrict__ edge_sh,
    const int* __restrict__ senders, const int* __restrict__ receivers,
    const float* __restrict__ emb, const float* __restrict__ Wm1,
    const float* __restrict__ Wm2, const float* __restrict__ Wm3,
    float* __restrict__ agg)
{
  __shared__ float h2s[64 * 256];
  const int tid = threadIdx.x;
  const int e = blockIdx.x * 256 + tid;
  const int s = senders[e];
  const int r = receivers[e];
  const float4 shv = *(const float4*)(edge_sh + (size_t)e * 4);
  float e8[8];
  ld8(e8, emb + (size_t)e * 8);

  float h2a[64];
  #pragma unroll
  for (int v = 0; v < 64; ++v) h2a[v] = 0.f;
  #pragma unroll 2
  for (int k = 0; k < 64; ++k) {
    float a = 0.f;
    #pragma unroll
    for (int j = 0; j < 8; ++j) a = fmaf(e8[j], Wm1[j * 64 + k], a);
    float h1k = swishf(a * 0.35355339059327373f);
    const float* wrow = Wm2 + k * 64;
    #pragma unroll
    for (int v = 0; v < 64; ++v) h2a[v] = fmaf(h1k, wrow[v], h2a[v]);
  }
  #pragma unroll
  for (int v = 0; v < 64; ++v)
    h2s[v * 256 + tid] = swishf(h2a[v] * 0.125f);

  const float* yrow = y + (size_t)s * 256;
  float* aggr = agg + (size_t)r * 512;
  const float SCL = 0.0078125f;
  const float c0  = shv.x * SCL;
  const float c1x = shv.y * SCL, c1y = shv.z * SCL, c1z = shv.w * SCL;
  const float c4  = 0.125f / (16.0f * 1.7320508075688772f);

  float wa[64];

  wgemv(wa, Wm3, h2s + tid, 0);
  #pragma unroll
  for (int uc = 0; uc < 8; ++uc) {
    float ev[8];
    ld8(ev, yrow + uc * 8);
    #pragma unroll
    for (int j = 0; j < 8; ++j) {
      int u = uc * 8 + j;
      atomicAdd(&aggr[u], wa[u] * ev[j] * c0);
    }
  }
  wgemv(wa, Wm3, h2s + tid, 1);
  #pragma unroll
  for (int uc = 0; uc < 8; ++uc) {
    float ev[8];
    ld8(ev, yrow + uc * 8);
    #pragma unroll
    for (int j = 0; j < 8; ++j) {
      int u = uc * 8 + j;
      float tt = wa[u] * ev[j];
      atomicAdd(&aggr[128 + 3 * u    ], tt * c1x);
      atomicAdd(&aggr[128 + 3 * u + 1], tt * c1y);
      atomicAdd(&aggr[128 + 3 * u + 2], tt * c1z);
    }
  }
  wgemv(wa, Wm3, h2s + tid, 2);
  #pragma unroll
  for (int uc = 0; uc < 8; ++uc) {
    float ev[24];
    ld8(ev,      yrow + 64 + uc * 24);
    ld8(ev + 8,  yrow + 64 + uc * 24 + 8);
    ld8(ev + 16, yrow + 64 + uc * 24 + 16);
    #pragma unroll
    for (int j = 0; j < 8; ++j) {
      int u = uc * 8 + j;
      float tt = wa[u] * c0;
      atomicAdd(&aggr[320 + 3 * u    ], tt * ev[3 * j    ]);
      atomicAdd(&aggr[320 + 3 * u + 1], tt * ev[3 * j + 1]);
      atomicAdd(&aggr[320 + 3 * u + 2], tt * ev[3 * j + 2]);
    }
  }
  wgemv(wa, Wm3, h2s + tid, 3);
  #pragma unroll
  for (int uc = 0; uc < 8; ++uc) {
    float ev[24];
    ld8(ev,      yrow + 64 + uc * 24);
    ld8(ev + 8,  yrow + 64 + uc * 24 + 8);
    ld8(ev + 16, yrow + 64 + uc * 24 + 16);
    #pragma unroll
    for (int j = 0; j < 8; ++j) {
      int u = uc * 8 + j;
      float d = ev[3*j]*shv.y + ev[3*j+1]*shv.z + ev[3*j+2]*shv.w;
      atomicAdd(&aggr[64 + u], wa[u] * d * c4);
    }
  }
}

// ---------------- VALU node_post (tier-2/3 fallback) ----------------
__global__ __launch_bounds__(256) void node_post(
    const float* __restrict__ feats, const float* __restrict__ attrs,
    const float* __restrict__ agg, const float* __restrict__ W2s,
    const float* __restrict__ W2v, const float* __restrict__ Wr_s,
    const float* __restrict__ Wr_v, float* __restrict__ out)
{
  __shared__ __align__(16) float sA[320 * 8];
  __shared__ __align__(16) float sX0[64 * 8];
  __shared__ __align__(16) float sX1[192 * 8];
  __shared__ __align__(16) float sAt[5 * 8];
  __shared__ __align__(16) float sAggS[128 * 8];
  __shared__ __align__(16) float sAggV[384 * 8];
  __shared__ __align__(16) float sZs[8 * 128];
  __shared__ __align__(16) float sZv[8 * 192];

  const int t = threadIdx.x;
  const int n0 = blockIdx.x * 8;
  const float nr = 0.05590169943749474f;
  const float n2 = 0.08838834764831845f;

  #pragma unroll
  for (int nb = 0; nb < 8; ++nb) {
    float v = feats[(size_t)(n0 + nb) * 256 + t];
    if (t < 64) sX0[t * 8 + nb] = v;
    else        sX1[(t - 64) * 8 + nb] = v;
  }
  if (t < 40) {
    int nb = t & 7, s = t >> 3;
    sAt[s * 8 + nb] = attrs[(size_t)(n0 + nb) * 5 + s] * nr;
  }
  #pragma unroll
  for (int i = 0; i < 16; ++i) {
    int idx = i * 256 + t;
    int nb = idx >> 9;
    int c = idx & 511;
    float v = agg[(size_t)(n0 + nb) * 512 + c] * n2;
    if (c < 128) sAggS[c * 8 + nb] = v;
    else         sAggV[(c - 128) * 8 + nb] = v;
  }
  __syncthreads();

  #pragma unroll
  for (int i = 0; i < 10; ++i) {
    int idx = i * 256 + t;
    int nb = idx & 7;
    int us = idx >> 3;
    int u = us / 5;
    int s = us - u * 5;
    sA[us * 8 + nb] = sX0[u * 8 + nb] * sAt[s * 8 + nb];
  }
  __syncthreads();

  float av[8][3];

  if (t < 128) {
    const int v = t;
    float acc[8];
    #pragma unroll
    for (int nb = 0; nb < 8; ++nb) acc[nb] = 0.f;
    for (int us = 0; us < 320; ++us)
      fma8v(acc, &sA[us * 8], Wr_s[us * 128 + v]);
    for (int c = 0; c < 128; ++c)
      fma8v(acc, &sAggS[c * 8], W2s[c * 128 + v]);
    #pragma unroll
    for (int nb = 0; nb < 8; ++nb) sZs[nb * 128 + v] = acc[nb];
  } else {
    const int tv = t - 128;
    const int v = tv & 63;
    const int half = tv >> 6;
    #pragma unroll
    for (int nb = 0; nb < 8; ++nb)
      #pragma unroll
      for (int m = 0; m < 3; ++m) av[nb][m] = 0.f;

    const int u0 = half * 32;
    for (int u = u0; u < u0 + 32; ++u) {
      float xr0[8], xr1[8], xr2[8];
      ld8(xr0, &sX1[(u * 3 + 0) * 8]);
      ld8(xr1, &sX1[(u * 3 + 1) * 8]);
      ld8(xr2, &sX1[(u * 3 + 2) * 8]);
      #pragma unroll
      for (int s = 0; s < 5; ++s) {
        float w = Wr_v[(u * 5 + s) * 64 + v];
        float at[8];
        ld8(at, &sAt[s * 8]);
        #pragma unroll
        for (int nb = 0; nb < 8; ++nb) {
          float tt = at[nb] * w;
          av[nb][0] = fmaf(xr0[nb], tt, av[nb][0]);
          av[nb][1] = fmaf(xr1[nb], tt, av[nb][1]);
          av[nb][2] = fmaf(xr2[nb], tt, av[nb][2]);
        }
      }
    }
    const int c0 = half * 64;
    for (int c = c0; c < c0 + 64; ++c) {
      float w = W2v[c * 64 + v];
      float g0[8], g1[8], g2[8];
      ld8(g0, &sAggV[(c * 3 + 0) * 8]);
      ld8(g1, &sAggV[(c * 3 + 1) * 8]);
      ld8(g2, &sAggV[(c * 3 + 2) * 8]);
      #pragma unroll
      for (int nb = 0; nb < 8; ++nb) {
        av[nb][0] = fmaf(g0[nb], w, av[nb][0]);
        av[nb][1] = fmaf(g1[nb], w, av[nb][1]);
        av[nb][2] = fmaf(g2[nb], w, av[nb][2]);
      }
    }
    if (half == 0) {
      #pragma unroll
      for (int nb = 0; nb < 8; ++nb)
        #pragma unroll
        for (int m = 0; m < 3; ++m)
          sZv[nb * 192 + v * 3 + m] = av[nb][m];
    }
  }
  __syncthreads();
  if (t >= 192) {
    const int v = (t - 128) & 63;
    #pragma unroll
    for (int nb = 0; nb < 8; ++nb)
      #pragma unroll
      for (int m = 0; m < 3; ++m)
        sZv[nb * 192 + v * 3 + m] += av[nb][m];
  }
  __syncthreads();

  const int i = t - 64;
  const int ug = (t >= 64) ? (i / 3) : 0;
  #pragma unroll
  for (int nb = 0; nb < 8; ++nb) {
    float val;
    if (t < 64) {
      val = swishf(sZs[nb * 128 + t]);
    } else {
      float gate = swishf(sZs[nb * 128 + 64 + ug]);
      val = gate * sZv[nb * 192 + i];
    }
    out[(size_t)(n0 + nb) * 256 + t] = val;
  }
}

extern "C" void kernel_launch(void* const* d_in, const int* in_sizes, int n_in,
                              void* d_out, int out_size, void* d_ws, size_t ws_size,
                              hipStream_t stream)
{
  const float* feats = (const float*)d_in[0];
  const float* attrs = (const float*)d_in[1];
  const float* esh   = (const float*)d_in[2];
  const int*   snd   = (const int*)d_in[3];
  const int*   rcv   = (const int*)d_in[4];
  const float* emb   = (const float*)d_in[5];
  const float* Wl0   = (const float*)d_in[6];
  const float* Wl1   = (const float*)d_in[7];
  const float* Wm1   = (const float*)d_in[8];
  const float* Wm2   = (const float*)d_in[9];
  const float* Wm3   = (const float*)d_in[10];
  const float* W2s   = (const float*)d_in[11];
  const float* W2v   = (const float*)d_in[12];
  const float* Wr_s  = (const float*)d_in[13];
  const float* Wr_v  = (const float*)d_in[14];
  float* out = (float*)d_out;

  float* y   = (float*)d_ws;                     // NN*256 f32
  float* agg = y + (size_t)NN * 256;             // NN*512 f32
  int* counts = (int*)agg;                       // aliased transients
  int* cursor = counts + NN;
  int* csr_edge = (int*)(agg + (size_t)NN * 512);   // NE ints
  int* offsets  = csr_edge + NE;                    // NN+1 ints
  int* snd_sorted = offsets + NN + 1;               // NE ints
  float* sh_sorted = (float*)(snd_sorted + NE);     // NE*4 f32
  __half* w_sorted = (__half*)(sh_sorted + (size_t)NE * 4);  // NE*256 f16
  unsigned* Wm2P = (unsigned*)(w_sorted + (size_t)NE * 256); // 2048 u32
  unsigned* Wm3P = Wm2P + 2048;                              // 8192 u32
  unsigned* Wm3T = Wm3P + 8192;                              // 8192 u32
  unsigned* BsT  = Wm3T + 8192;                              // 28672 u32
  unsigned* BvT  = BsT + 28672;                              // 14336 u32
  float* zs = y;                                  // NN*128 f32 (y dead)
  float* zv = (float*)w_sorted;                   // 60000*64 f32 (w dead)
  size_t need1 = (size_t)((char*)(BvT + 14336) - (char*)d_ws);
  size_t need2 = (size_t)((char*)(offsets + NN + 1) - (char*)d_ws);

  if (ws_size >= need1) {
    hipMemsetAsync(counts, 0, (size_t)NN * sizeof(int), stream);
    hist_kernel<<<NE / 256, 256, 0, stream>>>(rcv, counts);
    scan_kernel<<<1, 1024, 0, stream>>>(counts, offsets, cursor);
    scatter_full<<<NE / 256, 256, 0, stream>>>(rcv, snd, esh, cursor,
                                               csr_edge, snd_sorted, sh_sorted);
    pack_weights<<<72, 256, 0, stream>>>(Wm2, Wm3, Wm2P, Wm3P, Wm3T);
    pack_node_B<<<168, 256, 0, stream>>>(Wr_s, W2s, Wr_v, W2v, BsT, BvT);
    node_prep<<<NN / 4, 256, 0, stream>>>(feats, Wl0, Wl1, y);
    w_kernel<<<NE / 256, 256, 0, stream>>>(csr_edge, emb, Wm1, Wm2P, Wm3T, w_sorted);
    gather_tp<<<NN / 4, 256, 0, stream>>>(y, w_sorted, sh_sorted, snd_sorted,
                                          offsets, agg);
    node_gemm<<<NN / 16, 256, 0, stream>>>(feats, attrs, agg, BsT, BvT, zs, zv);
    gate_kernel<<<NN, 256, 0, stream>>>(zs, zv, out);
  } else if (ws_size >= need2) {
    hipMemsetAsync(counts, 0, (size_t)NN * sizeof(int), stream);
    hist_kernel<<<NE / 256, 256, 0, stream>>>(rcv, counts);
    scan_kernel<<<1, 1024, 0, stream>>>(counts, offsets, cursor);
    scatter_kernel<<<NE / 256, 256, 0, stream>>>(rcv, cursor, csr_edge);
    node_prep<<<NN / 4, 256, 0, stream>>>(feats, Wl0, Wl1, y);
    gather_fused<<<NN / 8, 512, 0, stream>>>(y, csr_edge, snd, esh, emb,
                                             Wm1, Wm2, Wm3, offsets, agg);
    node_post<<<NN / 8, 256, 0, stream>>>(feats, attrs, agg, W2s, W2v, Wr_s, Wr_v, out);
  } else {
    hipMemsetAsync(agg, 0, (size_t)NN * 512 * sizeof(float), stream);
    node_prep<<<NN / 4, 256, 0, stream>>>(feats, Wl0, Wl1, y);
    edge_kernel<<<NE / 256, 256, 0, stream>>>(y, esh, snd, rcv, emb, Wm1, Wm2, Wm3, agg);
    node_post<<<NN / 8, 256, 0, stream>>>(feats, attrs, agg, W2s, W2v, Wr_s, Wr_v, out);
  }
}

// Round 17
// 342.280 us; speedup vs baseline: 1.1178x; 1.0294x over previous
//
#include <hip/hip_runtime.h>
#include <hip/hip_fp16.h>

// NequIP-style layer, f32.
// Tier 1 (~234MB ws): CSR sort -> pack_weights/pack_node_B -> node_prep ->
//   w_kernel (dot2 MLP + MFMA w-GEMM, LDS store-staging) -> gather_tp ->
//   node_gemm (MFMA, reg-preloaded B, fused gate epilogue -> out).
// Tier 2 (~62.8MB ws): r7 fused gather + VALU node_post.
// Tier 3 (~61.4MB ws): atomic kernel + VALU node_post.

#define NN 20000
#define NE 320000

typedef _Float16 h2v __attribute__((ext_vector_type(2)));
typedef _Float16 f16x8 __attribute__((ext_vector_type(8)));
typedef float f32x4 __attribute__((ext_vector_type(4)));

__device__ __forceinline__ float swishf(float x) {
  float t = __expf(-fabsf(x));
  float r = 1.0f / (1.0f + t);
  float sig = (x >= 0.0f) ? r : t * r;
  return x * sig;
}

__device__ __forceinline__ unsigned pack2h(float a, float b) {
  __half2 h = __floats2half2_rn(a, b);
  return *reinterpret_cast<unsigned*>(&h);
}

__device__ __forceinline__ h2v u32h2(unsigned u) {
  union { unsigned u; h2v h; } x; x.u = u; return x.h;
}

__device__ __forceinline__ h2v packh2v(float a, float b) {
  h2v h; h.x = (_Float16)a; h.y = (_Float16)b; return h;
}

__device__ __forceinline__ f16x8 u4f16(uint4 u) {
  union { uint4 u; f16x8 h; } x; x.u = u; return x.h;
}

__device__ __forceinline__ void ld8(float d[8], const float* p) {
  float4 a0 = *(const float4*)p;
  float4 a1 = *(const float4*)(p + 4);
  d[0]=a0.x; d[1]=a0.y; d[2]=a0.z; d[3]=a0.w;
  d[4]=a1.x; d[5]=a1.y; d[6]=a1.z; d[7]=a1.w;
}

__device__ __forceinline__ void fma8v(float (&acc)[8], const float* p, float w) {
  float4 a0 = *(const float4*)p;
  float4 a1 = *(const float4*)(p + 4);
  acc[0] = fmaf(a0.x, w, acc[0]); acc[1] = fmaf(a0.y, w, acc[1]);
  acc[2] = fmaf(a0.z, w, acc[2]); acc[3] = fmaf(a0.w, w, acc[3]);
  acc[4] = fmaf(a1.x, w, acc[4]); acc[5] = fmaf(a1.y, w, acc[5]);
  acc[6] = fmaf(a1.z, w, acc[6]); acc[7] = fmaf(a1.w, w, acc[7]);
}

// ---------------- CSR build ----------------
__global__ __launch_bounds__(256) void hist_kernel(const int* __restrict__ rcv,
                                                   int* __restrict__ counts) {
  int e = blockIdx.x * 256 + threadIdx.x;
  atomicAdd(&counts[rcv[e]], 1);
}

__global__ __launch_bounds__(1024) void scan_kernel(const int* __restrict__ counts,
                                                    int* __restrict__ offsets,
                                                    int* __restrict__ cursor) {
  __shared__ int part[1024];
  const int t = threadIdx.x;
  const int base = t * 20;
  int loc[20];
  int s = 0;
  #pragma unroll
  for (int j = 0; j < 20; ++j) {
    int idx = base + j;
    int c = (idx < NN) ? counts[idx] : 0;
    loc[j] = s;
    s += c;
  }
  part[t] = s;
  __syncthreads();
  for (int d = 1; d < 1024; d <<= 1) {
    int v = (t >= d) ? part[t - d] : 0;
    __syncthreads();
    part[t] += v;
    __syncthreads();
  }
  int excl = (t > 0) ? part[t - 1] : 0;
  #pragma unroll
  for (int j = 0; j < 20; ++j) {
    int idx = base + j;
    if (idx < NN) {
      int o = excl + loc[j];
      offsets[idx] = o;
      cursor[idx] = o;
    }
  }
  if (t == 1023) offsets[NN] = part[1023];
}

__global__ __launch_bounds__(256) void scatter_full(
    const int* __restrict__ rcv, const int* __restrict__ snd,
    const float* __restrict__ esh, int* __restrict__ cursor,
    int* __restrict__ csr_edge, int* __restrict__ snd_sorted,
    float* __restrict__ sh_sorted) {
  int e = blockIdx.x * 256 + threadIdx.x;
  int r = rcv[e];
  int pos = atomicAdd(&cursor[r], 1);
  csr_edge[pos] = e;
  snd_sorted[pos] = snd[e];
  float4 sh = *(const float4*)(esh + (size_t)e * 4);
  *(float4*)(sh_sorted + (size_t)pos * 4) = sh;
}

__global__ __launch_bounds__(256) void scatter_kernel(
    const int* __restrict__ rcv, int* __restrict__ cursor,
    int* __restrict__ csr_edge) {
  int e = blockIdx.x * 256 + threadIdx.x;
  int r = rcv[e];
  int pos = atomicAdd(&cursor[r], 1);
  csr_edge[pos] = e;
}

// ---------------- pack Wm2/Wm3 into f16 k-pair tables ----------------
__global__ __launch_bounds__(256) void pack_weights(
    const float* __restrict__ Wm2, const float* __restrict__ Wm3,
    unsigned* __restrict__ Wm2P, unsigned* __restrict__ Wm3P,
    unsigned* __restrict__ Wm3T) {
  int idx = blockIdx.x * 256 + threadIdx.x;
  if (idx < 2048) {
    int k2 = idx >> 6, v = idx & 63;
    Wm2P[idx] = pack2h(Wm2[(2 * k2) * 64 + v], Wm2[(2 * k2 + 1) * 64 + v]);
  } else if (idx < 10240) {
    int r = idx - 2048;
    int k2 = r >> 8, c = r & 255;
    Wm3P[r] = pack2h(Wm3[(2 * k2) * 256 + c], Wm3[(2 * k2 + 1) * 256 + c]);
  } else if (idx < 18432) {
    int r = idx - 10240;
    int c = r >> 5, j = r & 31;
    Wm3T[r] = pack2h(Wm3[(2 * j) * 256 + c], Wm3[(2 * j + 1) * 256 + c]);
  }
}

// ---------------- pack node-side B^T tables (scales folded) ----------------
__global__ __launch_bounds__(256) void pack_node_B(
    const float* __restrict__ Wr_s, const float* __restrict__ W2s,
    const float* __restrict__ Wr_v, const float* __restrict__ W2v,
    unsigned* __restrict__ BsT, unsigned* __restrict__ BvT) {
  const float nr = 0.05590169943749474f;   // 1/sqrt(320)
  const float n2 = 0.08838834764831845f;   // 1/sqrt(128)
  int idx = blockIdx.x * 256 + threadIdx.x;
  if (idx < 28672) {
    int v = idx / 224, j = idx % 224;
    float a, b;
    if (j < 160) {
      int s = j >> 5, u0 = (j & 31) << 1;
      a = Wr_s[(u0 * 5 + s) * 128 + v] * nr;
      b = Wr_s[((u0 + 1) * 5 + s) * 128 + v] * nr;
    } else {
      int c0 = (j - 160) << 1;
      a = W2s[c0 * 128 + v] * n2;
      b = W2s[(c0 + 1) * 128 + v] * n2;
    }
    BsT[idx] = pack2h(a, b);
  } else if (idx < 43008) {
    int r = idx - 28672;
    int v = r / 224, j = r % 224;
    float a, b;
    if (j < 160) {
      int s = j >> 5, u0 = (j & 31) << 1;
      a = Wr_v[(u0 * 5 + s) * 64 + v] * nr;
      b = Wr_v[((u0 + 1) * 5 + s) * 64 + v] * nr;
    } else {
      int c0 = (j - 160) << 1;
      a = W2v[c0 * 64 + v] * n2;
      b = W2v[(c0 + 1) * 64 + v] * n2;
    }
    BvT[r] = pack2h(a, b);
  }
}

// ---------------- node_prep: y = [x0@Wl0, x1@Wl1] * nl ----------------
__global__ __launch_bounds__(256) void node_prep(
    const float* __restrict__ feats, const float* __restrict__ Wl0,
    const float* __restrict__ Wl1, float* __restrict__ y)
{
  __shared__ __align__(16) float sX[4 * 256];
  const int t = threadIdx.x;
  const int n0 = blockIdx.x * 4;
  #pragma unroll
  for (int nb = 0; nb < 4; ++nb)
    sX[nb * 256 + t] = feats[(size_t)(n0 + nb) * 256 + t];
  __syncthreads();

  float acc[4] = {0.f, 0.f, 0.f, 0.f};
  if (t < 64) {
    const int v = t;
    for (int u = 0; u < 64; ++u) {
      float w = Wl0[u * 64 + v];
      acc[0] = fmaf(sX[0 * 256 + u], w, acc[0]);
      acc[1] = fmaf(sX[1 * 256 + u], w, acc[1]);
      acc[2] = fmaf(sX[2 * 256 + u], w, acc[2]);
      acc[3] = fmaf(sX[3 * 256 + u], w, acc[3]);
    }
  } else {
    const int i = t - 64;
    const int v = i / 3;
    const int m = i - v * 3;
    for (int u = 0; u < 64; ++u) {
      float w = Wl1[u * 64 + v];
      int xi = 64 + u * 3 + m;
      acc[0] = fmaf(sX[0 * 256 + xi], w, acc[0]);
      acc[1] = fmaf(sX[1 * 256 + xi], w, acc[1]);
      acc[2] = fmaf(sX[2 * 256 + xi], w, acc[2]);
      acc[3] = fmaf(sX[3 * 256 + xi], w, acc[3]);
    }
  }
  #pragma unroll
  for (int nb = 0; nb < 4; ++nb)
    y[(size_t)(n0 + nb) * 256 + t] = acc[nb] * 0.125f;   // nl = 1/sqrt(64)
}

// GEMV helper (fallback paths, f32)
__device__ __forceinline__ void wgemv(float (&wa)[64], const float* __restrict__ Wm3,
                                      const float* h2col, int p)
{
  #pragma unroll
  for (int v = 0; v < 64; ++v) wa[v] = 0.f;
  #pragma unroll 2
  for (int k = 0; k < 64; ++k) {
    float h2k = h2col[k * 256];
    const float* wrow = Wm3 + k * 256 + p * 64;
    #pragma unroll
    for (int v = 0; v < 64; ++v) wa[v] = fmaf(h2k, wrow[v], wa[v]);
  }
}

// ---------------- tier-1 phase A: MLP h2 (dot2) + MFMA w-GEMM ----------------
// D = Wm3T x h2; results staged in wave-private LDS slab, drained as
// 128B-per-edge-row global stores (full sectors).
__global__ __launch_bounds__(256, 4) void w_kernel(
    const int* __restrict__ csr_edge, const float* __restrict__ emb,
    const float* __restrict__ Wm1, const unsigned* __restrict__ Wm2P,
    const unsigned* __restrict__ Wm3T, __half* __restrict__ w_sorted)
{
  __shared__ unsigned sA[256 * 32];   // h2 f16 [edge][k2] swizzled; then slabs
  const int tid = threadIdx.x;
  const int i = blockIdx.x * 256 + tid;
  const int e = csr_edge[i];

  float e8[8];
  ld8(e8, emb + (size_t)e * 8);
  float h2a[64];
  #pragma unroll
  for (int v = 0; v < 64; ++v) h2a[v] = 0.f;
  #pragma unroll 1
  for (int k2 = 0; k2 < 32; ++k2) {
    float a0 = 0.f, a1 = 0.f;
    #pragma unroll
    for (int j = 0; j < 8; ++j) {
      a0 = fmaf(e8[j], Wm1[j * 64 + 2 * k2], a0);
      a1 = fmaf(e8[j], Wm1[j * 64 + 2 * k2 + 1], a1);
    }
    h2v ph = packh2v(swishf(a0 * 0.35355339059327373f),
                     swishf(a1 * 0.35355339059327373f));
    const unsigned* wrow = Wm2P + k2 * 64;
    #pragma unroll
    for (int v = 0; v < 64; ++v)
      h2a[v] = __builtin_amdgcn_fdot2(ph, u32h2(wrow[v]), h2a[v], false);
  }
  {
    const int r = tid;
    #pragma unroll
    for (int c = 0; c < 8; ++c) {
      uint4 v;
      v.x = pack2h(swishf(h2a[8 * c + 0] * 0.125f), swishf(h2a[8 * c + 1] * 0.125f));
      v.y = pack2h(swishf(h2a[8 * c + 2] * 0.125f), swishf(h2a[8 * c + 3] * 0.125f));
      v.z = pack2h(swishf(h2a[8 * c + 4] * 0.125f), swishf(h2a[8 * c + 5] * 0.125f));
      v.w = pack2h(swishf(h2a[8 * c + 6] * 0.125f), swishf(h2a[8 * c + 7] * 0.125f));
      *(uint4*)&sA[r * 32 + ((c ^ (r & 7)) << 2)] = v;
    }
  }
  __syncthreads();

  const int l = tid & 63;
  const int wv = tid >> 6;
  const int lg = l >> 4;
  const int lm = l & 15;

  f16x8 bfr[4][2];
  #pragma unroll
  for (int nt = 0; nt < 4; ++nt) {
    int row = wv * 64 + nt * 16 + lm;
    #pragma unroll
    for (int kh = 0; kh < 2; ++kh) {
      uint4 u = *(const uint4*)&sA[row * 32 + ((((kh << 2) + lg) ^ (row & 7)) << 2)];
      bfr[nt][kh] = u4f16(u);
    }
  }
  unsigned* sTw = sA + wv * 2048;
  const int eb = blockIdx.x * 256 + wv * 64;

  #pragma unroll 1
  for (int p = 0; p < 4; ++p) {
    #pragma unroll
    for (int mtl = 0; mtl < 4; ++mtl) {
      const int mt = p * 4 + mtl;
      int arow = mt * 16 + lm;
      uint4 u0 = *(const uint4*)&Wm3T[arow * 32 + (lg << 2)];
      uint4 u1 = *(const uint4*)&Wm3T[arow * 32 + 16 + (lg << 2)];
      f16x8 a0 = u4f16(u0), a1 = u4f16(u1);
      #pragma unroll
      for (int nt = 0; nt < 4; ++nt) {
        f32x4 acc = {0.f, 0.f, 0.f, 0.f};
        acc = __builtin_amdgcn_mfma_f32_16x16x32_f16(a0, bfr[nt][0], acc, 0, 0, 0);
        acc = __builtin_amdgcn_mfma_f32_16x16x32_f16(a1, bfr[nt][1], acc, 0, 0, 0);
        const int r = nt * 16 + lm;
        const int u = mtl * 4 + lg;
        const int pos8 = ((((u >> 1) ^ (r & 7)) << 1) | (u & 1));
        uint2 pk;
        pk.x = pack2h(acc[0], acc[1]);
        pk.y = pack2h(acc[2], acc[3]);
        *(uint2*)&sTw[r * 32 + pos8 * 2] = pk;
      }
    }
    #pragma unroll
    for (int g = 0; g < 8; ++g) {
      const int er = g * 8 + (l >> 3);
      const int c8 = l & 7;
      uint4 v = *(const uint4*)&sTw[er * 32 + ((c8 ^ (er & 7)) << 2)];
      *(uint4*)(w_sorted + (size_t)(eb + er) * 256 + p * 64 + c8 * 8) = v;
    }
  }
}

// ---------------- tier-1 phase B: per-node gather + tensor product ----------
__global__ __launch_bounds__(256) void gather_tp(
    const float* __restrict__ y, const __half* __restrict__ w_sorted,
    const float* __restrict__ sh_sorted, const int* __restrict__ snd_sorted,
    const int* __restrict__ offsets, float* __restrict__ agg)
{
  const int l = threadIdx.x & 63;
  const int wv = threadIdx.x >> 6;
  const int n = blockIdx.x * 4 + wv;
  const int row0 = offsets[n];
  const int row1 = offsets[n + 1];

  float s0 = 0.f, s1 = 0.f;
  float v0x = 0.f, v0y = 0.f, v0z = 0.f;
  float v1x = 0.f, v1y = 0.f, v1z = 0.f;

  for (int i = row0; i < row1; ++i) {
    const int s = snd_sorted[i];
    const float4 sh = *(const float4*)(sh_sorted + (size_t)i * 4);
    const __half* wr = w_sorted + (size_t)i * 256;
    float w1 = __half2float(wr[l]);
    float w2 = __half2float(wr[64 + l]);
    float w3 = __half2float(wr[128 + l]);
    float w4 = __half2float(wr[192 + l]);
    const float* yr = y + (size_t)s * 256;
    float e0 = yr[l];
    float ex = yr[64 + 3 * l], ey = yr[65 + 3 * l], ez = yr[66 + 3 * l];

    s0 = fmaf(w1 * e0, sh.x, s0);
    s1 = fmaf(w4, fmaf(ex, sh.y, fmaf(ey, sh.z, ez * sh.w)), s1);
    float t2 = w2 * e0;
    v0x = fmaf(t2, sh.y, v0x); v0y = fmaf(t2, sh.z, v0y); v0z = fmaf(t2, sh.w, v0z);
    float t3 = w3 * sh.x;
    v1x = fmaf(t3, ex, v1x); v1y = fmaf(t3, ey, v1y); v1z = fmaf(t3, ez, v1z);
  }

  const float SCL = 0.0078125f;                          // (1/8 w-scale) / 16
  const float C4  = 0.125f / (16.0f * 1.7320508075688772f);
  float* ar = agg + (size_t)n * 512;
  ar[l]       = s0 * SCL;
  ar[64 + l]  = s1 * C4;
  ar[128 + 3 * l]     = v0x * SCL;
  ar[128 + 3 * l + 1] = v0y * SCL;
  ar[128 + 3 * l + 2] = v0z * SCL;
  ar[320 + 3 * l]     = v1x * SCL;
  ar[320 + 3 * l + 1] = v1y * SCL;
  ar[320 + 3 * l + 2] = v1z * SCL;
}

// ---------------- tier-1: node-side MFMA GEMM + fused gate epilogue ----------
// z written to dead sX LDS (zs f32 + zv f16); output phase applies gating.
// B fragments register-preloaded per job (breaks L2-latency serialization).
__global__ __launch_bounds__(256) void node_gemm(
    const float* __restrict__ feats, const float* __restrict__ attrs,
    const float* __restrict__ agg, const unsigned* __restrict__ BsT,
    const unsigned* __restrict__ BvT, float* __restrict__ out)
{
  __shared__ unsigned sAK[64 * 224];   // 57344B
  __shared__ float sX[16 * 257];       // staging; later z buffers
  __shared__ float sAt[16 * 5];
  const int t = threadIdx.x;
  const int n0 = blockIdx.x * 16;

  float* zsL = sX;                         // 16*128 f32 = 8KB
  __half* zvL = (__half*)(sX + 2048);      // 48*64 f16 = 6KB

  #pragma unroll
  for (int nb = 0; nb < 16; ++nb)
    sX[nb * 257 + t] = feats[(size_t)(n0 + nb) * 256 + t];
  if (t < 80) sAt[t] = attrs[(size_t)n0 * 5 + t];
  __syncthreads();

  {
    const int row = t >> 2;
    const int part = t & 3;
    const bool is_s = row < 16;
    int node, m = 0;
    if (is_s) node = row;
    else { int vi = row - 16; node = vi / 3; m = vi - node * 3; }
    const float* xrow = &sX[node * 257];
    const float* atr = &sAt[node * 5];
    const float* aggr = agg + (size_t)(n0 + node) * 512;
    unsigned* arow = &sAK[row * 224];
    #pragma unroll 8
    for (int jj = 0; jj < 56; ++jj) {
      const int j = part + 4 * jj;
      float v0, v1;
      if (jj < 40) {
        int s = j >> 5;
        int u0 = (j & 31) << 1;
        float a = atr[s];
        float x0 = is_s ? xrow[u0]     : xrow[64 + 3 * u0 + m];
        float x1 = is_s ? xrow[u0 + 1] : xrow[64 + 3 * u0 + 3 + m];
        v0 = x0 * a;
        v1 = x1 * a;
      } else {
        int c0 = (j - 160) << 1;
        if (is_s) { v0 = aggr[c0]; v1 = aggr[c0 + 1]; }
        else {
          v0 = aggr[128 + 3 * c0 + m];
          v1 = aggr[128 + 3 * c0 + 3 + m];
        }
      }
      int chs = (jj & ~7) | ((jj ^ row) & 7);
      arow[(chs << 2) + part] = pack2h(v0, v1);
    }
  }
  __syncthreads();          // builds done; sX dead -> zsL/zvL writable

  const int l = t & 63;
  const int wv = t >> 6;
  const int lm = l & 15;
  const int lg = l >> 4;

  #pragma unroll 1
  for (int jj = 0; jj < 5; ++jj) {
    const int jd = wv + 4 * jj;
    int mtile, ntile;
    const unsigned* Bt;
    if (jd < 8) { mtile = 0; ntile = jd; Bt = BsT; }
    else { int q = jd - 8; mtile = 1 + (q >> 2); ntile = q & 3; Bt = BvT; }

    const int arow0 = mtile * 16 + lm;
    const unsigned* brow = Bt + (ntile * 16 + lm) * 224;

    // register-preload all 14 B fragments (static indexing -> VGPRs)
    uint4 ubr[14];
    #pragma unroll
    for (int ks = 0; ks < 14; ++ks)
      ubr[ks] = *(const uint4*)&brow[(ks * 4 + lg) << 2];

    f32x4 acc = {0.f, 0.f, 0.f, 0.f};
    #pragma unroll
    for (int ks = 0; ks < 14; ++ks) {
      int ch = ks * 4 + lg;
      int chs = (ch & ~7) | ((ch ^ arow0) & 7);
      uint4 ua = *(const uint4*)&sAK[arow0 * 224 + (chs << 2)];
      acc = __builtin_amdgcn_mfma_f32_16x16x32_f16(u4f16(ua), u4f16(ubr[ks]), acc, 0, 0, 0);
    }
    const int drow = mtile * 16 + lg * 4;
    if (jd < 8) {
      #pragma unroll
      for (int rr = 0; rr < 4; ++rr)
        zsL[(drow + rr) * 128 + ntile * 16 + lm] = acc[rr];
    } else {
      const int vi0 = drow - 16;
      #pragma unroll
      for (int rr = 0; rr < 4; ++rr)
        zvL[(vi0 + rr) * 64 + ntile * 16 + lm] = __float2half(acc[rr]);
    }
  }
  __syncthreads();          // all z in LDS

  // gate epilogue: out[n][t]
  int ug = 0, mg = 0;
  if (t >= 64) { ug = (t - 64) / 3; mg = (t - 64) - ug * 3; }
  #pragma unroll 4
  for (int nb = 0; nb < 16; ++nb) {
    float val;
    if (t < 64) {
      val = swishf(zsL[nb * 128 + t]);
    } else {
      float gate = swishf(zsL[nb * 128 + 64 + ug]);
      val = gate * __half2float(zvL[(nb * 3 + mg) * 64 + ug]);
    }
    out[(size_t)(n0 + nb) * 256 + t] = val;
  }
}

// ---------------- tier-2: r7 fused gather ----------------
__global__ __launch_bounds__(512, 2) void gather_fused(
    const float* __restrict__ y, const int* __restrict__ csr_edge,
    const int* __restrict__ snd, const float* __restrict__ esh,
    const float* __restrict__ emb, const float* __restrict__ Wm1,
    const float* __restrict__ Wm2, const float* __restrict__ Wm3,
    const int* __restrict__ offsets, float* __restrict__ agg)
{
  __shared__ __align__(16) float sW3[64 * 256];
  __shared__ __align__(16) float sH[8 * 4 * 64];
  const int t = threadIdx.x;

  #pragma unroll 4
  for (int i = 0; i < 32; ++i) {
    int idx = i * 512 + t;
    int k = idx >> 8;
    int c = idx & 255;
    float v = Wm3[idx];
    int kg = k >> 2, kk = k & 3;
    sW3[c * 64 + (((kg ^ (c & 15)) & 15) << 2) + kk] = v;
  }
  __syncthreads();

  const int l = t & 63;
  const int wv = t >> 6;
  const int n = blockIdx.x * 8 + wv;
  const int row0 = offsets[n];
  const int row1 = offsets[n + 1];

  float* sHw = &sH[wv * 256];

  float wm1r[8];
  #pragma unroll
  for (int j = 0; j < 8; ++j) wm1r[j] = Wm1[j * 64 + l];

  float s0 = 0.f, s1 = 0.f;
  float v0x = 0.f, v0y = 0.f, v0z = 0.f;
  float v1x = 0.f, v1y = 0.f, v1z = 0.f;

  const int swz = ((l & 15) << 2);

  for (int i = row0; i < row1; i += 4) {
    const int nb = row1 - i;

    int   sn[4];
    float4 sh[4];
    #pragma unroll
    for (int b = 0; b < 4; ++b) {
      int idx = (b < nb) ? (i + b) : i;
      int e = csr_edge[idx];
      sn[b] = snd[e];
      float4 s = *(const float4*)(esh + (size_t)e * 4);
      if (b >= nb) s = make_float4(0.f, 0.f, 0.f, 0.f);
      sh[b] = s;
      float em8[8];
      ld8(em8, emb + (size_t)e * 8);
      float a = 0.f;
      #pragma unroll
      for (int j = 0; j < 8; ++j) a = fmaf(em8[j], wm1r[j], a);
      sHw[b * 64 + l] = swishf(a * 0.35355339059327373f);
    }

    float h2[4] = {0.f, 0.f, 0.f, 0.f};
    #pragma unroll 4
    for (int q = 0; q < 16; ++q) {
      float wq0 = Wm2[(4 * q + 0) * 64 + l];
      float wq1 = Wm2[(4 * q + 1) * 64 + l];
      float wq2 = Wm2[(4 * q + 2) * 64 + l];
      float wq3 = Wm2[(4 * q + 3) * 64 + l];
      #pragma unroll
      for (int b = 0; b < 4; ++b) {
        float4 h = *(const float4*)&sHw[b * 64 + 4 * q];
        h2[b] = fmaf(h.x, wq0, h2[b]);
        h2[b] = fmaf(h.y, wq1, h2[b]);
        h2[b] = fmaf(h.z, wq2, h2[b]);
        h2[b] = fmaf(h.w, wq3, h2[b]);
      }
    }
    #pragma unroll
    for (int b = 0; b < 4; ++b)
      h2[b] = swishf(h2[b] * 0.125f);
    #pragma unroll
    for (int b = 0; b < 4; ++b)
      sHw[b * 64 + l] = h2[b];

    float w0[4]  = {0,0,0,0}, w1a[4] = {0,0,0,0};
    float w2a[4] = {0,0,0,0}, w3a[4] = {0,0,0,0};
    #pragma unroll 1
    for (int g = 0; g < 16; ++g) {
      int sbase = l * 64 + (((g << 2) ^ swz) & 63);
      float4 m0 = *(const float4*)&sW3[sbase];
      float4 m1 = *(const float4*)&sW3[sbase + 4096];
      float4 m2 = *(const float4*)&sW3[sbase + 8192];
      float4 m3 = *(const float4*)&sW3[sbase + 12288];
      #pragma unroll
      for (int b = 0; b < 4; ++b) {
        float4 hb = *(const float4*)&sHw[b * 64 + 4 * g];
        #pragma unroll
        for (int kk = 0; kk < 4; ++kk) {
          float bc = (&hb.x)[kk];
          w0[b]  = fmaf(bc, (&m0.x)[kk], w0[b]);
          w1a[b] = fmaf(bc, (&m1.x)[kk], w1a[b]);
          w2a[b] = fmaf(bc, (&m2.x)[kk], w2a[b]);
          w3a[b] = fmaf(bc, (&m3.x)[kk], w3a[b]);
        }
      }
    }

    #pragma unroll
    for (int b = 0; b < 4; ++b) {
      const float* yr = y + (size_t)sn[b] * 256;
      float e0 = yr[l];
      float ex = yr[64 + 3 * l], ey = yr[65 + 3 * l], ez = yr[66 + 3 * l];
      float4 s = sh[b];
      s0 = fmaf(w0[b] * e0, s.x, s0);
      s1 = fmaf(w3a[b], fmaf(ex, s.y, fmaf(ey, s.z, ez * s.w)), s1);
      float t2 = w1a[b] * e0;
      v0x = fmaf(t2, s.y, v0x); v0y = fmaf(t2, s.z, v0y); v0z = fmaf(t2, s.w, v0z);
      float t3 = w2a[b] * s.x;
      v1x = fmaf(t3, ex, v1x); v1y = fmaf(t3, ey, v1y); v1z = fmaf(t3, ez, v1z);
    }
  }

  const float SCL = 0.0078125f;
  const float C4  = 0.125f / (16.0f * 1.7320508075688772f);
  float* ar = agg + (size_t)n * 512;
  ar[l]       = s0 * SCL;
  ar[64 + l]  = s1 * C4;
  ar[128 + 3 * l]     = v0x * SCL;
  ar[128 + 3 * l + 1] = v0y * SCL;
  ar[128 + 3 * l + 2] = v0z * SCL;
  ar[320 + 3 * l]     = v1x * SCL;
  ar[320 + 3 * l + 1] = v1y * SCL;
  ar[320 + 3 * l + 2] = v1z * SCL;
}

// ---------------- tier-3: atomic edge kernel ----------------
__global__ __launch_bounds__(256) void edge_kernel(
    const float* __restrict__ y, const float* __restrict__ edge_sh,
    const int* __restrict__ senders, const int* __restrict__ receivers,
    const float* __restrict__ emb, const float* __restrict__ Wm1,
    const float* __restrict__ Wm2, const float* __restrict__ Wm3,
    float* __restrict__ agg)
{
  __shared__ float h2s[64 * 256];
  const int tid = threadIdx.x;
  const int e = blockIdx.x * 256 + tid;
  const int s = senders[e];
  const int r = receivers[e];
  const float4 shv = *(const float4*)(edge_sh + (size_t)e * 4);
  float e8[8];
  ld8(e8, emb + (size_t)e * 8);

  float h2a[64];
  #pragma unroll
  for (int v = 0; v < 64; ++v) h2a[v] = 0.f;
  #pragma unroll 2
  for (int k = 0; k < 64; ++k) {
    float a = 0.f;
    #pragma unroll
    for (int j = 0; j < 8; ++j) a = fmaf(e8[j], Wm1[j * 64 + k], a);
    float h1k = swishf(a * 0.35355339059327373f);
    const float* wrow = Wm2 + k * 64;
    #pragma unroll
    for (int v = 0; v < 64; ++v) h2a[v] = fmaf(h1k, wrow[v], h2a[v]);
  }
  #pragma unroll
  for (int v = 0; v < 64; ++v)
    h2s[v * 256 + tid] = swishf(h2a[v] * 0.125f);

  const float* yrow = y + (size_t)s * 256;
  float* aggr = agg + (size_t)r * 512;
  const float SCL = 0.0078125f;
  const float c0  = shv.x * SCL;
  const float c1x = shv.y * SCL, c1y = shv.z * SCL, c1z = shv.w * SCL;
  const float c4  = 0.125f / (16.0f * 1.7320508075688772f);

  float wa[64];

  wgemv(wa, Wm3, h2s + tid, 0);
  #pragma unroll
  for (int uc = 0; uc < 8; ++uc) {
    float ev[8];
    ld8(ev, yrow + uc * 8);
    #pragma unroll
    for (int j = 0; j < 8; ++j) {
      int u = uc * 8 + j;
      atomicAdd(&aggr[u], wa[u] * ev[j] * c0);
    }
  }
  wgemv(wa, Wm3, h2s + tid, 1);
  #pragma unroll
  for (int uc = 0; uc < 8; ++uc) {
    float ev[8];
    ld8(ev, yrow + uc * 8);
    #pragma unroll
    for (int j = 0; j < 8; ++j) {
      int u = uc * 8 + j;
      float tt = wa[u] * ev[j];
      atomicAdd(&aggr[128 + 3 * u    ], tt * c1x);
      atomicAdd(&aggr[128 + 3 * u + 1], tt * c1y);
      atomicAdd(&aggr[128 + 3 * u + 2], tt * c1z);
    }
  }
  wgemv(wa, Wm3, h2s + tid, 2);
  #pragma unroll
  for (int uc = 0; uc < 8; ++uc) {
    float ev[24];
    ld8(ev,      yrow + 64 + uc * 24);
    ld8(ev + 8,  yrow + 64 + uc * 24 + 8);
    ld8(ev + 16, yrow + 64 + uc * 24 + 16);
    #pragma unroll
    for (int j = 0; j < 8; ++j) {
      int u = uc * 8 + j;
      float tt = wa[u] * c0;
      atomicAdd(&aggr[320 + 3 * u    ], tt * ev[3 * j    ]);
      atomicAdd(&aggr[320 + 3 * u + 1], tt * ev[3 * j + 1]);
      atomicAdd(&aggr[320 + 3 * u + 2], tt * ev[3 * j + 2]);
    }
  }
  wgemv(wa, Wm3, h2s + tid, 3);
  #pragma unroll
  for (int uc = 0; uc < 8; ++uc) {
    float ev[24];
    ld8(ev,      yrow + 64 + uc * 24);
    ld8(ev + 8,  yrow + 64 + uc * 24 + 8);
    ld8(ev + 16, yrow + 64 + uc * 24 + 16);
    #pragma unroll
    for (int j = 0; j < 8; ++j) {
      int u = uc * 8 + j;
      float d = ev[3*j]*shv.y + ev[3*j+1]*shv.z + ev[3*j+2]*shv.w;
      atomicAdd(&aggr[64 + u], wa[u] * d * c4);
    }
  }
}

// ---------------- VALU node_post (tier-2/3 fallback) ----------------
__global__ __launch_bounds__(256) void node_post(
    const float* __restrict__ feats, const float* __restrict__ attrs,
    const float* __restrict__ agg, const float* __restrict__ W2s,
    const float* __restrict__ W2v, const float* __restrict__ Wr_s,
    const float* __restrict__ Wr_v, float* __restrict__ out)
{
  __shared__ __align__(16) float sA[320 * 8];
  __shared__ __align__(16) float sX0[64 * 8];
  __shared__ __align__(16) float sX1[192 * 8];
  __shared__ __align__(16) float sAt[5 * 8];
  __shared__ __align__(16) float sAggS[128 * 8];
  __shared__ __align__(16) float sAggV[384 * 8];
  __shared__ __align__(16) float sZs[8 * 128];
  __shared__ __align__(16) float sZv[8 * 192];

  const int t = threadIdx.x;
  const int n0 = blockIdx.x * 8;
  const float nr = 0.05590169943749474f;
  const float n2 = 0.08838834764831845f;

  #pragma unroll
  for (int nb = 0; nb < 8; ++nb) {
    float v = feats[(size_t)(n0 + nb) * 256 + t];
    if (t < 64) sX0[t * 8 + nb] = v;
    else        sX1[(t - 64) * 8 + nb] = v;
  }
  if (t < 40) {
    int nb = t & 7, s = t >> 3;
    sAt[s * 8 + nb] = attrs[(size_t)(n0 + nb) * 5 + s] * nr;
  }
  #pragma unroll
  for (int i = 0; i < 16; ++i) {
    int idx = i * 256 + t;
    int nb = idx >> 9;
    int c = idx & 511;
    float v = agg[(size_t)(n0 + nb) * 512 + c] * n2;
    if (c < 128) sAggS[c * 8 + nb] = v;
    else         sAggV[(c - 128) * 8 + nb] = v;
  }
  __syncthreads();

  #pragma unroll
  for (int i = 0; i < 10; ++i) {
    int idx = i * 256 + t;
    int nb = idx & 7;
    int us = idx >> 3;
    int u = us / 5;
    int s = us - u * 5;
    sA[us * 8 + nb] = sX0[u * 8 + nb] * sAt[s * 8 + nb];
  }
  __syncthreads();

  float av[8][3];

  if (t < 128) {
    const int v = t;
    float acc[8];
    #pragma unroll
    for (int nb = 0; nb < 8; ++nb) acc[nb] = 0.f;
    for (int us = 0; us < 320; ++us)
      fma8v(acc, &sA[us * 8], Wr_s[us * 128 + v]);
    for (int c = 0; c < 128; ++c)
      fma8v(acc, &sAggS[c * 8], W2s[c * 128 + v]);
    #pragma unroll
    for (int nb = 0; nb < 8; ++nb) sZs[nb * 128 + v] = acc[nb];
  } else {
    const int tv = t - 128;
    const int v = tv & 63;
    const int half = tv >> 6;
    #pragma unroll
    for (int nb = 0; nb < 8; ++nb)
      #pragma unroll
      for (int m = 0; m < 3; ++m) av[nb][m] = 0.f;

    const int u0 = half * 32;
    for (int u = u0; u < u0 + 32; ++u) {
      float xr0[8], xr1[8], xr2[8];
      ld8(xr0, &sX1[(u * 3 + 0) * 8]);
      ld8(xr1, &sX1[(u * 3 + 1) * 8]);
      ld8(xr2, &sX1[(u * 3 + 2) * 8]);
      #pragma unroll
      for (int s = 0; s < 5; ++s) {
        float w = Wr_v[(u * 5 + s) * 64 + v];
        float at[8];
        ld8(at, &sAt[s * 8]);
        #pragma unroll
        for (int nb = 0; nb < 8; ++nb) {
          float tt = at[nb] * w;
          av[nb][0] = fmaf(xr0[nb], tt, av[nb][0]);
          av[nb][1] = fmaf(xr1[nb], tt, av[nb][1]);
          av[nb][2] = fmaf(xr2[nb], tt, av[nb][2]);
        }
      }
    }
    const int c0 = half * 64;
    for (int c = c0; c < c0 + 64; ++c) {
      float w = W2v[c * 64 + v];
      float g0[8], g1[8], g2[8];
      ld8(g0, &sAggV[(c * 3 + 0) * 8]);
      ld8(g1, &sAggV[(c * 3 + 1) * 8]);
      ld8(g2, &sAggV[(c * 3 + 2) * 8]);
      #pragma unroll
      for (int nb = 0; nb < 8; ++nb) {
        av[nb][0] = fmaf(g0[nb], w, av[nb][0]);
        av[nb][1] = fmaf(g1[nb], w, av[nb][1]);
        av[nb][2] = fmaf(g2[nb], w, av[nb][2]);
      }
    }
    if (half == 0) {
      #pragma unroll
      for (int nb = 0; nb < 8; ++nb)
        #pragma unroll
        for (int m = 0; m < 3; ++m)
          sZv[nb * 192 + v * 3 + m] = av[nb][m];
    }
  }
  __syncthreads();
  if (t >= 192) {
    const int v = (t - 128) & 63;
    #pragma unroll
    for (int nb = 0; nb < 8; ++nb)
      #pragma unroll
      for (int m = 0; m < 3; ++m)
        sZv[nb * 192 + v * 3 + m] += av[nb][m];
  }
  __syncthreads();

  const int i = t - 64;
  const int ug = (t >= 64) ? (i / 3) : 0;
  #pragma unroll
  for (int nb = 0; nb < 8; ++nb) {
    float val;
    if (t < 64) {
      val = swishf(sZs[nb * 128 + t]);
    } else {
      float gate = swishf(sZs[nb * 128 + 64 + ug]);
      val = gate * sZv[nb * 192 + i];
    }
    out[(size_t)(n0 + nb) * 256 + t] = val;
  }
}

extern "C" void kernel_launch(void* const* d_in, const int* in_sizes, int n_in,
                              void* d_out, int out_size, void* d_ws, size_t ws_size,
                              hipStream_t stream)
{
  const float* feats = (const float*)d_in[0];
  const float* attrs = (const float*)d_in[1];
  const float* esh   = (const float*)d_in[2];
  const int*   snd   = (const int*)d_in[3];
  const int*   rcv   = (const int*)d_in[4];
  const float* emb   = (const float*)d_in[5];
  const float* Wl0   = (const float*)d_in[6];
  const float* Wl1   = (const float*)d_in[7];
  const float* Wm1   = (const float*)d_in[8];
  const float* Wm2   = (const float*)d_in[9];
  const float* Wm3   = (const float*)d_in[10];
  const float* W2s   = (const float*)d_in[11];
  const float* W2v   = (const float*)d_in[12];
  const float* Wr_s  = (const float*)d_in[13];
  const float* Wr_v  = (const float*)d_in[14];
  float* out = (float*)d_out;

  float* y   = (float*)d_ws;                     // NN*256 f32
  float* agg = y + (size_t)NN * 256;             // NN*512 f32
  int* counts = (int*)agg;                       // aliased transients
  int* cursor = counts + NN;
  int* csr_edge = (int*)(agg + (size_t)NN * 512);   // NE ints
  int* offsets  = csr_edge + NE;                    // NN+1 ints
  int* snd_sorted = offsets + NN + 1;               // NE ints
  float* sh_sorted = (float*)(snd_sorted + NE);     // NE*4 f32
  __half* w_sorted = (__half*)(sh_sorted + (size_t)NE * 4);  // NE*256 f16
  unsigned* Wm2P = (unsigned*)(w_sorted + (size_t)NE * 256); // 2048 u32
  unsigned* Wm3P = Wm2P + 2048;                              // 8192 u32
  unsigned* Wm3T = Wm3P + 8192;                              // 8192 u32
  unsigned* BsT  = Wm3T + 8192;                              // 28672 u32
  unsigned* BvT  = BsT + 28672;                              // 14336 u32
  size_t need1 = (size_t)((char*)(BvT + 14336) - (char*)d_ws);
  size_t need2 = (size_t)((char*)(offsets + NN + 1) - (char*)d_ws);

  if (ws_size >= need1) {
    hipMemsetAsync(counts, 0, (size_t)NN * sizeof(int), stream);
    hist_kernel<<<NE / 256, 256, 0, stream>>>(rcv, counts);
    scan_kernel<<<1, 1024, 0, stream>>>(counts, offsets, cursor);
    scatter_full<<<NE / 256, 256, 0, stream>>>(rcv, snd, esh, cursor,
                                               csr_edge, snd_sorted, sh_sorted);
    pack_weights<<<72, 256, 0, stream>>>(Wm2, Wm3, Wm2P, Wm3P, Wm3T);
    pack_node_B<<<168, 256, 0, stream>>>(Wr_s, W2s, Wr_v, W2v, BsT, BvT);
    node_prep<<<NN / 4, 256, 0, stream>>>(feats, Wl0, Wl1, y);
    w_kernel<<<NE / 256, 256, 0, stream>>>(csr_edge, emb, Wm1, Wm2P, Wm3T, w_sorted);
    gather_tp<<<NN / 4, 256, 0, stream>>>(y, w_sorted, sh_sorted, snd_sorted,
                                          offsets, agg);
    node_gemm<<<NN / 16, 256, 0, stream>>>(feats, attrs, agg, BsT, BvT, out);
  } else if (ws_size >= need2) {
    hipMemsetAsync(counts, 0, (size_t)NN * sizeof(int), stream);
    hist_kernel<<<NE / 256, 256, 0, stream>>>(rcv, counts);
    scan_kernel<<<1, 1024, 0, stream>>>(counts, offsets, cursor);
    scatter_kernel<<<NE / 256, 256, 0, stream>>>(rcv, cursor, csr_edge);
    node_prep<<<NN / 4, 256, 0, stream>>>(feats, Wl0, Wl1, y);
    gather_fused<<<NN / 8, 512, 0, stream>>>(y, csr_edge, snd, esh, emb,
                                             Wm1, Wm2, Wm3, offsets, agg);
    node_post<<<NN / 8, 256, 0, stream>>>(feats, attrs, agg, W2s, W2v, Wr_s, Wr_v, out);
  } else {
    hipMemsetAsync(agg, 0, (size_t)NN * 512 * sizeof(float), stream);
    node_prep<<<NN / 4, 256, 0, stream>>>(feats, Wl0, Wl1, y);
    edge_kernel<<<NE / 256, 256, 0, stream>>>(y, esh, snd, rcv, emb, Wm1, Wm2, Wm3, agg);
    node_post<<<NN / 8, 256, 0, stream>>>(feats, attrs, agg, W2s, W2v, Wr_s, Wr_v, out);
  }
}

// Round 19
// 337.538 us; speedup vs baseline: 1.1335x; 1.0140x over previous
//
#include <hip/hip_runtime.h>
#include <hip/hip_fp16.h>

// NequIP-style layer, f32.
// Tier 1 (~234MB ws): CSR sort -> pack_weights/pack_node_B -> node_prep ->
//   w_kernel (dot2 MLP + MFMA w-GEMM, LDS store-staging) -> gather_tp
//   (v-plane agg layout) -> node_gemm (MFMA, K-split LDS w/ 128-u32 padded
//   rows, no feats staging, fused gate epilogue -> out).
// Tier 2 (~62.8MB ws): r7 fused gather + VALU node_post (old agg layout).
// Tier 3 (~61.4MB ws): atomic kernel + VALU node_post.

#define NN 20000
#define NE 320000

typedef _Float16 h2v __attribute__((ext_vector_type(2)));
typedef _Float16 f16x8 __attribute__((ext_vector_type(8)));
typedef float f32x4 __attribute__((ext_vector_type(4)));

__device__ __forceinline__ float swishf(float x) {
  float t = __expf(-fabsf(x));
  float r = 1.0f / (1.0f + t);
  float sig = (x >= 0.0f) ? r : t * r;
  return x * sig;
}

__device__ __forceinline__ unsigned pack2h(float a, float b) {
  __half2 h = __floats2half2_rn(a, b);
  return *reinterpret_cast<unsigned*>(&h);
}

__device__ __forceinline__ h2v u32h2(unsigned u) {
  union { unsigned u; h2v h; } x; x.u = u; return x.h;
}

__device__ __forceinline__ h2v packh2v(float a, float b) {
  h2v h; h.x = (_Float16)a; h.y = (_Float16)b; return h;
}

__device__ __forceinline__ f16x8 u4f16(uint4 u) {
  union { uint4 u; f16x8 h; } x; x.u = u; return x.h;
}

__device__ __forceinline__ void ld8(float d[8], const float* p) {
  float4 a0 = *(const float4*)p;
  float4 a1 = *(const float4*)(p + 4);
  d[0]=a0.x; d[1]=a0.y; d[2]=a0.z; d[3]=a0.w;
  d[4]=a1.x; d[5]=a1.y; d[6]=a1.z; d[7]=a1.w;
}

__device__ __forceinline__ void fma8v(float (&acc)[8], const float* p, float w) {
  float4 a0 = *(const float4*)p;
  float4 a1 = *(const float4*)(p + 4);
  acc[0] = fmaf(a0.x, w, acc[0]); acc[1] = fmaf(a0.y, w, acc[1]);
  acc[2] = fmaf(a0.z, w, acc[2]); acc[3] = fmaf(a0.w, w, acc[3]);
  acc[4] = fmaf(a1.x, w, acc[4]); acc[5] = fmaf(a1.y, w, acc[5]);
  acc[6] = fmaf(a1.z, w, acc[6]); acc[7] = fmaf(a1.w, w, acc[7]);
}

// ---------------- CSR build ----------------
__global__ __launch_bounds__(256) void hist_kernel(const int* __restrict__ rcv,
                                                   int* __restrict__ counts) {
  int e = blockIdx.x * 256 + threadIdx.x;
  atomicAdd(&counts[rcv[e]], 1);
}

__global__ __launch_bounds__(1024) void scan_kernel(const int* __restrict__ counts,
                                                    int* __restrict__ offsets,
                                                    int* __restrict__ cursor) {
  __shared__ int part[1024];
  const int t = threadIdx.x;
  const int base = t * 20;
  int loc[20];
  int s = 0;
  #pragma unroll
  for (int j = 0; j < 20; ++j) {
    int idx = base + j;
    int c = (idx < NN) ? counts[idx] : 0;
    loc[j] = s;
    s += c;
  }
  part[t] = s;
  __syncthreads();
  for (int d = 1; d < 1024; d <<= 1) {
    int v = (t >= d) ? part[t - d] : 0;
    __syncthreads();
    part[t] += v;
    __syncthreads();
  }
  int excl = (t > 0) ? part[t - 1] : 0;
  #pragma unroll
  for (int j = 0; j < 20; ++j) {
    int idx = base + j;
    if (idx < NN) {
      int o = excl + loc[j];
      offsets[idx] = o;
      cursor[idx] = o;
    }
  }
  if (t == 1023) offsets[NN] = part[1023];
}

__global__ __launch_bounds__(256) void scatter_full(
    const int* __restrict__ rcv, const int* __restrict__ snd,
    const float* __restrict__ esh, int* __restrict__ cursor,
    int* __restrict__ csr_edge, int* __restrict__ snd_sorted,
    float* __restrict__ sh_sorted) {
  int e = blockIdx.x * 256 + threadIdx.x;
  int r = rcv[e];
  int pos = atomicAdd(&cursor[r], 1);
  csr_edge[pos] = e;
  snd_sorted[pos] = snd[e];
  float4 sh = *(const float4*)(esh + (size_t)e * 4);
  *(float4*)(sh_sorted + (size_t)pos * 4) = sh;
}

__global__ __launch_bounds__(256) void scatter_kernel(
    const int* __restrict__ rcv, int* __restrict__ cursor,
    int* __restrict__ csr_edge) {
  int e = blockIdx.x * 256 + threadIdx.x;
  int r = rcv[e];
  int pos = atomicAdd(&cursor[r], 1);
  csr_edge[pos] = e;
}

// ---------------- pack Wm2/Wm3 into f16 k-pair tables ----------------
__global__ __launch_bounds__(256) void pack_weights(
    const float* __restrict__ Wm2, const float* __restrict__ Wm3,
    unsigned* __restrict__ Wm2P, unsigned* __restrict__ Wm3P,
    unsigned* __restrict__ Wm3T) {
  int idx = blockIdx.x * 256 + threadIdx.x;
  if (idx < 2048) {
    int k2 = idx >> 6, v = idx & 63;
    Wm2P[idx] = pack2h(Wm2[(2 * k2) * 64 + v], Wm2[(2 * k2 + 1) * 64 + v]);
  } else if (idx < 10240) {
    int r = idx - 2048;
    int k2 = r >> 8, c = r & 255;
    Wm3P[r] = pack2h(Wm3[(2 * k2) * 256 + c], Wm3[(2 * k2 + 1) * 256 + c]);
  } else if (idx < 18432) {
    int r = idx - 10240;
    int c = r >> 5, j = r & 31;
    Wm3T[r] = pack2h(Wm3[(2 * j) * 256 + c], Wm3[(2 * j + 1) * 256 + c]);
  }
}

// ---------------- pack node-side B^T tables (scales folded) ----------------
__global__ __launch_bounds__(256) void pack_node_B(
    const float* __restrict__ Wr_s, const float* __restrict__ W2s,
    const float* __restrict__ Wr_v, const float* __restrict__ W2v,
    unsigned* __restrict__ BsT, unsigned* __restrict__ BvT) {
  const float nr = 0.05590169943749474f;   // 1/sqrt(320)
  const float n2 = 0.08838834764831845f;   // 1/sqrt(128)
  int idx = blockIdx.x * 256 + threadIdx.x;
  if (idx < 28672) {
    int v = idx / 224, j = idx % 224;
    float a, b;
    if (j < 160) {
      int s = j >> 5, u0 = (j & 31) << 1;
      a = Wr_s[(u0 * 5 + s) * 128 + v] * nr;
      b = Wr_s[((u0 + 1) * 5 + s) * 128 + v] * nr;
    } else {
      int c0 = (j - 160) << 1;
      a = W2s[c0 * 128 + v] * n2;
      b = W2s[(c0 + 1) * 128 + v] * n2;
    }
    BsT[idx] = pack2h(a, b);
  } else if (idx < 43008) {
    int r = idx - 28672;
    int v = r / 224, j = r % 224;
    float a, b;
    if (j < 160) {
      int s = j >> 5, u0 = (j & 31) << 1;
      a = Wr_v[(u0 * 5 + s) * 64 + v] * nr;
      b = Wr_v[((u0 + 1) * 5 + s) * 64 + v] * nr;
    } else {
      int c0 = (j - 160) << 1;
      a = W2v[c0 * 64 + v] * n2;
      b = W2v[(c0 + 1) * 64 + v] * n2;
    }
    BvT[r] = pack2h(a, b);
  }
}

// ---------------- node_prep: y = [x0@Wl0, x1@Wl1] * nl ----------------
__global__ __launch_bounds__(256) void node_prep(
    const float* __restrict__ feats, const float* __restrict__ Wl0,
    const float* __restrict__ Wl1, float* __restrict__ y)
{
  __shared__ __align__(16) float sX[4 * 256];
  const int t = threadIdx.x;
  const int n0 = blockIdx.x * 4;
  #pragma unroll
  for (int nb = 0; nb < 4; ++nb)
    sX[nb * 256 + t] = feats[(size_t)(n0 + nb) * 256 + t];
  __syncthreads();

  float acc[4] = {0.f, 0.f, 0.f, 0.f};
  if (t < 64) {
    const int v = t;
    for (int u = 0; u < 64; ++u) {
      float w = Wl0[u * 64 + v];
      acc[0] = fmaf(sX[0 * 256 + u], w, acc[0]);
      acc[1] = fmaf(sX[1 * 256 + u], w, acc[1]);
      acc[2] = fmaf(sX[2 * 256 + u], w, acc[2]);
      acc[3] = fmaf(sX[3 * 256 + u], w, acc[3]);
    }
  } else {
    const int i = t - 64;
    const int v = i / 3;
    const int m = i - v * 3;
    for (int u = 0; u < 64; ++u) {
      float w = Wl1[u * 64 + v];
      int xi = 64 + u * 3 + m;
      acc[0] = fmaf(sX[0 * 256 + xi], w, acc[0]);
      acc[1] = fmaf(sX[1 * 256 + xi], w, acc[1]);
      acc[2] = fmaf(sX[2 * 256 + xi], w, acc[2]);
      acc[3] = fmaf(sX[3 * 256 + xi], w, acc[3]);
    }
  }
  #pragma unroll
  for (int nb = 0; nb < 4; ++nb)
    y[(size_t)(n0 + nb) * 256 + t] = acc[nb] * 0.125f;   // nl = 1/sqrt(64)
}

// GEMV helper (fallback paths, f32)
__device__ __forceinline__ void wgemv(float (&wa)[64], const float* __restrict__ Wm3,
                                      const float* h2col, int p)
{
  #pragma unroll
  for (int v = 0; v < 64; ++v) wa[v] = 0.f;
  #pragma unroll 2
  for (int k = 0; k < 64; ++k) {
    float h2k = h2col[k * 256];
    const float* wrow = Wm3 + k * 256 + p * 64;
    #pragma unroll
    for (int v = 0; v < 64; ++v) wa[v] = fmaf(h2k, wrow[v], wa[v]);
  }
}

// ---------------- tier-1 phase A: MLP h2 (dot2) + MFMA w-GEMM ----------------
__global__ __launch_bounds__(256, 4) void w_kernel(
    const int* __restrict__ csr_edge, const float* __restrict__ emb,
    const float* __restrict__ Wm1, const unsigned* __restrict__ Wm2P,
    const unsigned* __restrict__ Wm3T, __half* __restrict__ w_sorted)
{
  __shared__ unsigned sA[256 * 32];   // h2 f16 [edge][k2] swizzled; then slabs
  const int tid = threadIdx.x;
  const int i = blockIdx.x * 256 + tid;
  const int e = csr_edge[i];

  float e8[8];
  ld8(e8, emb + (size_t)e * 8);
  float h2a[64];
  #pragma unroll
  for (int v = 0; v < 64; ++v) h2a[v] = 0.f;
  #pragma unroll 1
  for (int k2 = 0; k2 < 32; ++k2) {
    float a0 = 0.f, a1 = 0.f;
    #pragma unroll
    for (int j = 0; j < 8; ++j) {
      a0 = fmaf(e8[j], Wm1[j * 64 + 2 * k2], a0);
      a1 = fmaf(e8[j], Wm1[j * 64 + 2 * k2 + 1], a1);
    }
    h2v ph = packh2v(swishf(a0 * 0.35355339059327373f),
                     swishf(a1 * 0.35355339059327373f));
    const unsigned* wrow = Wm2P + k2 * 64;
    #pragma unroll
    for (int v = 0; v < 64; ++v)
      h2a[v] = __builtin_amdgcn_fdot2(ph, u32h2(wrow[v]), h2a[v], false);
  }
  {
    const int r = tid;
    #pragma unroll
    for (int c = 0; c < 8; ++c) {
      uint4 v;
      v.x = pack2h(swishf(h2a[8 * c + 0] * 0.125f), swishf(h2a[8 * c + 1] * 0.125f));
      v.y = pack2h(swishf(h2a[8 * c + 2] * 0.125f), swishf(h2a[8 * c + 3] * 0.125f));
      v.z = pack2h(swishf(h2a[8 * c + 4] * 0.125f), swishf(h2a[8 * c + 5] * 0.125f));
      v.w = pack2h(swishf(h2a[8 * c + 6] * 0.125f), swishf(h2a[8 * c + 7] * 0.125f));
      *(uint4*)&sA[r * 32 + ((c ^ (r & 7)) << 2)] = v;
    }
  }
  __syncthreads();

  const int l = tid & 63;
  const int wv = tid >> 6;
  const int lg = l >> 4;
  const int lm = l & 15;

  f16x8 bfr[4][2];
  #pragma unroll
  for (int nt = 0; nt < 4; ++nt) {
    int row = wv * 64 + nt * 16 + lm;
    #pragma unroll
    for (int kh = 0; kh < 2; ++kh) {
      uint4 u = *(const uint4*)&sA[row * 32 + ((((kh << 2) + lg) ^ (row & 7)) << 2)];
      bfr[nt][kh] = u4f16(u);
    }
  }
  unsigned* sTw = sA + wv * 2048;
  const int eb = blockIdx.x * 256 + wv * 64;

  #pragma unroll 1
  for (int p = 0; p < 4; ++p) {
    #pragma unroll
    for (int mtl = 0; mtl < 4; ++mtl) {
      const int mt = p * 4 + mtl;
      int arow = mt * 16 + lm;
      uint4 u0 = *(const uint4*)&Wm3T[arow * 32 + (lg << 2)];
      uint4 u1 = *(const uint4*)&Wm3T[arow * 32 + 16 + (lg << 2)];
      f16x8 a0 = u4f16(u0), a1 = u4f16(u1);
      #pragma unroll
      for (int nt = 0; nt < 4; ++nt) {
        f32x4 acc = {0.f, 0.f, 0.f, 0.f};
        acc = __builtin_amdgcn_mfma_f32_16x16x32_f16(a0, bfr[nt][0], acc, 0, 0, 0);
        acc = __builtin_amdgcn_mfma_f32_16x16x32_f16(a1, bfr[nt][1], acc, 0, 0, 0);
        const int r = nt * 16 + lm;
        const int u = mtl * 4 + lg;
        const int pos8 = ((((u >> 1) ^ (r & 7)) << 1) | (u & 1));
        uint2 pk;
        pk.x = pack2h(acc[0], acc[1]);
        pk.y = pack2h(acc[2], acc[3]);
        *(uint2*)&sTw[r * 32 + pos8 * 2] = pk;
      }
    }
    #pragma unroll
    for (int g = 0; g < 8; ++g) {
      const int er = g * 8 + (l >> 3);
      const int c8 = l & 7;
      uint4 v = *(const uint4*)&sTw[er * 32 + ((c8 ^ (er & 7)) << 2)];
      *(uint4*)(w_sorted + (size_t)(eb + er) * 256 + p * 64 + c8 * 8) = v;
    }
  }
}

// ---------------- tier-1 phase B: per-node gather + tensor product ----------
// agg layout (tier-1): [0:64] s0, [64:128] s1, then v planes
// [128+m*128 + c]: c<64 = v-first (w2 path), c>=64 = v-second (w3 path).
__global__ __launch_bounds__(256) void gather_tp(
    const float* __restrict__ y, const __half* __restrict__ w_sorted,
    const float* __restrict__ sh_sorted, const int* __restrict__ snd_sorted,
    const int* __restrict__ offsets, float* __restrict__ agg)
{
  const int l = threadIdx.x & 63;
  const int wv = threadIdx.x >> 6;
  const int n = blockIdx.x * 4 + wv;
  const int row0 = offsets[n];
  const int row1 = offsets[n + 1];

  float s0 = 0.f, s1 = 0.f;
  float v0x = 0.f, v0y = 0.f, v0z = 0.f;
  float v1x = 0.f, v1y = 0.f, v1z = 0.f;

  for (int i = row0; i < row1; ++i) {
    const int s = snd_sorted[i];
    const float4 sh = *(const float4*)(sh_sorted + (size_t)i * 4);
    const __half* wr = w_sorted + (size_t)i * 256;
    float w1 = __half2float(wr[l]);
    float w2 = __half2float(wr[64 + l]);
    float w3 = __half2float(wr[128 + l]);
    float w4 = __half2float(wr[192 + l]);
    const float* yr = y + (size_t)s * 256;
    float e0 = yr[l];
    float ex = yr[64 + 3 * l], ey = yr[65 + 3 * l], ez = yr[66 + 3 * l];

    s0 = fmaf(w1 * e0, sh.x, s0);
    s1 = fmaf(w4, fmaf(ex, sh.y, fmaf(ey, sh.z, ez * sh.w)), s1);
    float t2 = w2 * e0;
    v0x = fmaf(t2, sh.y, v0x); v0y = fmaf(t2, sh.z, v0y); v0z = fmaf(t2, sh.w, v0z);
    float t3 = w3 * sh.x;
    v1x = fmaf(t3, ex, v1x); v1y = fmaf(t3, ey, v1y); v1z = fmaf(t3, ez, v1z);
  }

  const float SCL = 0.0078125f;                          // (1/8 w-scale) / 16
  const float C4  = 0.125f / (16.0f * 1.7320508075688772f);
  float* ar = agg + (size_t)n * 512;
  ar[l]       = s0 * SCL;
  ar[64 + l]  = s1 * C4;
  ar[128 + l]        = v0x * SCL;
  ar[128 + 64 + l]   = v1x * SCL;
  ar[256 + l]        = v0y * SCL;
  ar[256 + 64 + l]   = v1y * SCL;
  ar[384 + l]        = v0z * SCL;
  ar[384 + 64 + l]   = v1z * SCL;
}

// ---------------- tier-1: node-side MFMA GEMM + fused gate epilogue ----------
// K-split: sAK holds one 224-element K-half; rows PADDED to 128 u32 (32 chunks
// = 4 full swizzle groups, so the chunk-XOR stays in-bounds). ~47KB LDS ->
// 3 blocks/CU. No feats staging (direct global reads, L1/L2 5x reuse).
__global__ __launch_bounds__(256) void node_gemm(
    const float* __restrict__ feats, const float* __restrict__ attrs,
    const float* __restrict__ agg, const unsigned* __restrict__ BsT,
    const unsigned* __restrict__ BvT, float* __restrict__ out)
{
  __shared__ unsigned sAK[64 * 128];   // 32768B, one K-half (28 chunks used)
  __shared__ float zsL[16 * 128];      // 8192B
  __shared__ __half zvL[48 * 64];      // 6144B
  __shared__ float sAt[16 * 5];
  const int t = threadIdx.x;
  const int n0 = blockIdx.x * 16;

  if (t < 80) sAt[t] = attrs[(size_t)n0 * 5 + t];
  __syncthreads();

  const int l = t & 63;
  const int wv = t >> 6;
  const int lm = l & 15;
  const int lg = l >> 4;

  f32x4 acc[5];
  #pragma unroll
  for (int jj = 0; jj < 5; ++jj) acc[jj] = (f32x4){0.f, 0.f, 0.f, 0.f};

  #pragma unroll 1
  for (int h = 0; h < 2; ++h) {
    // ---- build A half h ----
    {
      const int row = t >> 2;
      const int part = t & 3;
      const bool is_s = row < 16;
      int node, m = 0;
      if (is_s) node = row;
      else { int vi = row - 16; node = vi / 3; m = vi - node * 3; }
      const float* xrow = feats + (size_t)(n0 + node) * 256;
      const float* atr = &sAt[node * 5];
      const float* aggr = agg + (size_t)(n0 + node) * 512;
      unsigned* arow = &sAK[row * 128];
      #pragma unroll 7
      for (int jj = 0; jj < 28; ++jj) {
        const int jl = part + 4 * jj;
        const int jg = h * 112 + jl;
        float v0, v1;
        if (jg < 160) {           // x (x) attrs, k = s*64+u
          int s = jg >> 5;
          int u0 = (jg & 31) << 1;
          float a = atr[s];
          float x0 = is_s ? xrow[u0]     : xrow[64 + 3 * u0 + m];
          float x1 = is_s ? xrow[u0 + 1] : xrow[64 + 3 * u0 + 3 + m];
          v0 = x0 * a;
          v1 = x1 * a;
        } else {                  // agg
          int c0 = (jg - 160) << 1;
          if (is_s) { v0 = aggr[c0]; v1 = aggr[c0 + 1]; }
          else {
            v0 = aggr[128 + m * 128 + c0];
            v1 = aggr[128 + m * 128 + c0 + 1];
          }
        }
        int chs = (jj & ~7) | ((jj ^ row) & 7);
        arow[(chs << 2) + part] = pack2h(v0, v1);
      }
    }
    __syncthreads();

    // ---- jobs: accumulate this half's 7 MFMA steps ----
    #pragma unroll
    for (int jj = 0; jj < 5; ++jj) {
      const int jd = wv + 4 * jj;
      int mtile, ntile;
      const unsigned* Bt;
      if (jd < 8) { mtile = 0; ntile = jd; Bt = BsT; }
      else { int q = jd - 8; mtile = 1 + (q >> 2); ntile = q & 3; Bt = BvT; }

      const int arow0 = mtile * 16 + lm;
      const unsigned* brow = Bt + (ntile * 16 + lm) * 224 + h * 112;

      uint4 ubr[7];
      #pragma unroll
      for (int ks = 0; ks < 7; ++ks)
        ubr[ks] = *(const uint4*)&brow[(ks * 4 + lg) << 2];

      f32x4 a = acc[jj];
      #pragma unroll
      for (int ks = 0; ks < 7; ++ks) {
        int ch = ks * 4 + lg;
        int chs = (ch & ~7) | ((ch ^ arow0) & 7);
        uint4 ua = *(const uint4*)&sAK[arow0 * 128 + (chs << 2)];
        a = __builtin_amdgcn_mfma_f32_16x16x32_f16(u4f16(ua), u4f16(ubr[ks]), a, 0, 0, 0);
      }
      acc[jj] = a;
    }
    __syncthreads();   // before next half's build overwrites sAK
  }

  // ---- store z to LDS ----
  #pragma unroll
  for (int jj = 0; jj < 5; ++jj) {
    const int jd = wv + 4 * jj;
    int mtile, ntile;
    if (jd < 8) { mtile = 0; ntile = jd; }
    else { int q = jd - 8; mtile = 1 + (q >> 2); ntile = q & 3; }
    const int drow = mtile * 16 + lg * 4;
    if (jd < 8) {
      #pragma unroll
      for (int rr = 0; rr < 4; ++rr)
        zsL[(drow + rr) * 128 + ntile * 16 + lm] = acc[jj][rr];
    } else {
      const int vi0 = drow - 16;
      #pragma unroll
      for (int rr = 0; rr < 4; ++rr)
        zvL[(vi0 + rr) * 64 + ntile * 16 + lm] = __float2half(acc[jj][rr]);
    }
  }
  __syncthreads();

  // ---- gate epilogue ----
  int ug = 0, mg = 0;
  if (t >= 64) { ug = (t - 64) / 3; mg = (t - 64) - ug * 3; }
  #pragma unroll 4
  for (int nb = 0; nb < 16; ++nb) {
    float val;
    if (t < 64) {
      val = swishf(zsL[nb * 128 + t]);
    } else {
      float gate = swishf(zsL[nb * 128 + 64 + ug]);
      val = gate * __half2float(zvL[(nb * 3 + mg) * 64 + ug]);
    }
    out[(size_t)(n0 + nb) * 256 + t] = val;
  }
}

// ---------------- tier-2: r7 fused gather (old agg layout) ----------------
__global__ __launch_bounds__(512, 2) void gather_fused(
    const float* __restrict__ y, const int* __restrict__ csr_edge,
    const int* __restrict__ snd, const float* __restrict__ esh,
    const float* __restrict__ emb, const float* __restrict__ Wm1,
    const float* __restrict__ Wm2, const float* __restrict__ Wm3,
    const int* __restrict__ offsets, float* __restrict__ agg)
{
  __shared__ __align__(16) float sW3[64 * 256];
  __shared__ __align__(16) float sH[8 * 4 * 64];
  const int t = threadIdx.x;

  #pragma unroll 4
  for (int i = 0; i < 32; ++i) {
    int idx = i * 512 + t;
    int k = idx >> 8;
    int c = idx & 255;
    float v = Wm3[idx];
    int kg = k >> 2, kk = k & 3;
    sW3[c * 64 + (((kg ^ (c & 15)) & 15) << 2) + kk] = v;
  }
  __syncthreads();

  const int l = t & 63;
  const int wv = t >> 6;
  const int n = blockIdx.x * 8 + wv;
  const int row0 = offsets[n];
  const int row1 = offsets[n + 1];

  float* sHw = &sH[wv * 256];

  float wm1r[8];
  #pragma unroll
  for (int j = 0; j < 8; ++j) wm1r[j] = Wm1[j * 64 + l];

  float s0 = 0.f, s1 = 0.f;
  float v0x = 0.f, v0y = 0.f, v0z = 0.f;
  float v1x = 0.f, v1y = 0.f, v1z = 0.f;

  const int swz = ((l & 15) << 2);

  for (int i = row0; i < row1; i += 4) {
    const int nb = row1 - i;

    int   sn[4];
    float4 sh[4];
    #pragma unroll
    for (int b = 0; b < 4; ++b) {
      int idx = (b < nb) ? (i + b) : i;
      int e = csr_edge[idx];
      sn[b] = snd[e];
      float4 s = *(const float4*)(esh + (size_t)e * 4);
      if (b >= nb) s = make_float4(0.f, 0.f, 0.f, 0.f);
      sh[b] = s;
      float em8[8];
      ld8(em8, emb + (size_t)e * 8);
      float a = 0.f;
      #pragma unroll
      for (int j = 0; j < 8; ++j) a = fmaf(em8[j], wm1r[j], a);
      sHw[b * 64 + l] = swishf(a * 0.35355339059327373f);
    }

    float h2[4] = {0.f, 0.f, 0.f, 0.f};
    #pragma unroll 4
    for (int q = 0; q < 16; ++q) {
      float wq0 = Wm2[(4 * q + 0) * 64 + l];
      float wq1 = Wm2[(4 * q + 1) * 64 + l];
      float wq2 = Wm2[(4 * q + 2) * 64 + l];
      float wq3 = Wm2[(4 * q + 3) * 64 + l];
      #pragma unroll
      for (int b = 0; b < 4; ++b) {
        float4 h = *(const float4*)&sHw[b * 64 + 4 * q];
        h2[b] = fmaf(h.x, wq0, h2[b]);
        h2[b] = fmaf(h.y, wq1, h2[b]);
        h2[b] = fmaf(h.z, wq2, h2[b]);
        h2[b] = fmaf(h.w, wq3, h2[b]);
      }
    }
    #pragma unroll
    for (int b = 0; b < 4; ++b)
      h2[b] = swishf(h2[b] * 0.125f);
    #pragma unroll
    for (int b = 0; b < 4; ++b)
      sHw[b * 64 + l] = h2[b];

    float w0[4]  = {0,0,0,0}, w1a[4] = {0,0,0,0};
    float w2a[4] = {0,0,0,0}, w3a[4] = {0,0,0,0};
    #pragma unroll 1
    for (int g = 0; g < 16; ++g) {
      int sbase = l * 64 + (((g << 2) ^ swz) & 63);
      float4 m0 = *(const float4*)&sW3[sbase];
      float4 m1 = *(const float4*)&sW3[sbase + 4096];
      float4 m2 = *(const float4*)&sW3[sbase + 8192];
      float4 m3 = *(const float4*)&sW3[sbase + 12288];
      #pragma unroll
      for (int b = 0; b < 4; ++b) {
        float4 hb = *(const float4*)&sHw[b * 64 + 4 * g];
        #pragma unroll
        for (int kk = 0; kk < 4; ++kk) {
          float bc = (&hb.x)[kk];
          w0[b]  = fmaf(bc, (&m0.x)[kk], w0[b]);
          w1a[b] = fmaf(bc, (&m1.x)[kk], w1a[b]);
          w2a[b] = fmaf(bc, (&m2.x)[kk], w2a[b]);
          w3a[b] = fmaf(bc, (&m3.x)[kk], w3a[b]);
        }
      }
    }

    #pragma unroll
    for (int b = 0; b < 4; ++b) {
      const float* yr = y + (size_t)sn[b] * 256;
      float e0 = yr[l];
      float ex = yr[64 + 3 * l], ey = yr[65 + 3 * l], ez = yr[66 + 3 * l];
      float4 s = sh[b];
      s0 = fmaf(w0[b] * e0, s.x, s0);
      s1 = fmaf(w3a[b], fmaf(ex, s.y, fmaf(ey, s.z, ez * s.w)), s1);
      float t2 = w1a[b] * e0;
      v0x = fmaf(t2, s.y, v0x); v0y = fmaf(t2, s.z, v0y); v0z = fmaf(t2, s.w, v0z);
      float t3 = w2a[b] * s.x;
      v1x = fmaf(t3, ex, v1x); v1y = fmaf(t3, ey, v1y); v1z = fmaf(t3, ez, v1z);
    }
  }

  const float SCL = 0.0078125f;
  const float C4  = 0.125f / (16.0f * 1.7320508075688772f);
  float* ar = agg + (size_t)n * 512;
  ar[l]       = s0 * SCL;
  ar[64 + l]  = s1 * C4;
  ar[128 + 3 * l]     = v0x * SCL;
  ar[128 + 3 * l + 1] = v0y * SCL;
  ar[128 + 3 * l + 2] = v0z * SCL;
  ar[320 + 3 * l]     = v1x * SCL;
  ar[320 + 3 * l + 1] = v1y * SCL;
  ar[320 + 3 * l + 2] = v1z * SCL;
}

// ---------------- tier-3: atomic edge kernel ----------------
__global__ __launch_bounds__(256) void edge_kernel(
    const float* __restrict__ y, const float* __restrict__ edge_sh,
    const int* __restrict__ senders, const int* __restrict__ receivers,
    const float* __restrict__ emb, const float* __restrict__ Wm1,
    const float* __restrict__ Wm2, const float* __restrict__ Wm3,
    float* __restrict__ agg)
{
  __shared__ float h2s[64 * 256];
  const int tid = threadIdx.x;
  const int e = blockIdx.x * 256 + tid;
  const int s = senders[e];
  const int r = receivers[e];
  const float4 shv = *(const float4*)(edge_sh + (size_t)e * 4);
  float e8[8];
  ld8(e8, emb + (size_t)e * 8);

  float h2a[64];
  #pragma unroll
  for (int v = 0; v < 64; ++v) h2a[v] = 0.f;
  #pragma unroll 2
  for (int k = 0; k < 64; ++k) {
    float a = 0.f;
    #pragma unroll
    for (int j = 0; j < 8; ++j) a = fmaf(e8[j], Wm1[j * 64 + k], a);
    float h1k = swishf(a * 0.35355339059327373f);
    const float* wrow = Wm2 + k * 64;
    #pragma unroll
    for (int v = 0; v < 64; ++v) h2a[v] = fmaf(h1k, wrow[v], h2a[v]);
  }
  #pragma unroll
  for (int v = 0; v < 64; ++v)
    h2s[v * 256 + tid] = swishf(h2a[v] * 0.125f);

  const float* yrow = y + (size_t)s * 256;
  float* aggr = agg + (size_t)r * 512;
  const float SCL = 0.0078125f;
  const float c0  = shv.x * SCL;
  const float c1x = shv.y * SCL, c1y = shv.z * SCL, c1z = shv.w * SCL;
  const float c4  = 0.125f / (16.0f * 1.7320508075688772f);

  float wa[64];

  wgemv(wa, Wm3, h2s + tid, 0);
  #pragma unroll
  for (int uc = 0; uc < 8; ++uc) {
    float ev[8];
    ld8(ev, yrow + uc * 8);
    #pragma unroll
    for (int j = 0; j < 8; ++j) {
      int u = uc * 8 + j;
      atomicAdd(&aggr[u], wa[u] * ev[j] * c0);
    }
  }
  wgemv(wa, Wm3, h2s + tid, 1);
  #pragma unroll
  for (int uc = 0; uc < 8; ++uc) {
    float ev[8];
    ld8(ev, yrow + uc * 8);
    #pragma unroll
    for (int j = 0; j < 8; ++j) {
      int u = uc * 8 + j;
      float tt = wa[u] * ev[j];
      atomicAdd(&aggr[128 + 3 * u    ], tt * c1x);
      atomicAdd(&aggr[128 + 3 * u + 1], tt * c1y);
      atomicAdd(&aggr[128 + 3 * u + 2], tt * c1z);
    }
  }
  wgemv(wa, Wm3, h2s + tid, 2);
  #pragma unroll
  for (int uc = 0; uc < 8; ++uc) {
    float ev[24];
    ld8(ev,      yrow + 64 + uc * 24);
    ld8(ev + 8,  yrow + 64 + uc * 24 + 8);
    ld8(ev + 16, yrow + 64 + uc * 24 + 16);
    #pragma unroll
    for (int j = 0; j < 8; ++j) {
      int u = uc * 8 + j;
      float tt = wa[u] * c0;
      atomicAdd(&aggr[320 + 3 * u    ], tt * ev[3 * j    ]);
      atomicAdd(&aggr[320 + 3 * u + 1], tt * ev[3 * j + 1]);
      atomicAdd(&aggr[320 + 3 * u + 2], tt * ev[3 * j + 2]);
    }
  }
  wgemv(wa, Wm3, h2s + tid, 3);
  #pragma unroll
  for (int uc = 0; uc < 8; ++uc) {
    float ev[24];
    ld8(ev,      yrow + 64 + uc * 24);
    ld8(ev + 8,  yrow + 64 + uc * 24 + 8);
    ld8(ev + 16, yrow + 64 + uc * 24 + 16);
    #pragma unroll
    for (int j = 0; j < 8; ++j) {
      int u = uc * 8 + j;
      float d = ev[3*j]*shv.y + ev[3*j+1]*shv.z + ev[3*j+2]*shv.w;
      atomicAdd(&aggr[64 + u], wa[u] * d * c4);
    }
  }
}

// ---------------- VALU node_post (tier-2/3 fallback, old agg layout) --------
__global__ __launch_bounds__(256) void node_post(
    const float* __restrict__ feats, const float* __restrict__ attrs,
    const float* __restrict__ agg, const float* __restrict__ W2s,
    const float* __restrict__ W2v, const float* __restrict__ Wr_s,
    const float* __restrict__ Wr_v, float* __restrict__ out)
{
  __shared__ __align__(16) float sA[320 * 8];
  __shared__ __align__(16) float sX0[64 * 8];
  __shared__ __align__(16) float sX1[192 * 8];
  __shared__ __align__(16) float sAt[5 * 8];
  __shared__ __align__(16) float sAggS[128 * 8];
  __shared__ __align__(16) float sAggV[384 * 8];
  __shared__ __align__(16) float sZs[8 * 128];
  __shared__ __align__(16) float sZv[8 * 192];

  const int t = threadIdx.x;
  const int n0 = blockIdx.x * 8;
  const float nr = 0.05590169943749474f;
  const float n2 = 0.08838834764831845f;

  #pragma unroll
  for (int nb = 0; nb < 8; ++nb) {
    float v = feats[(size_t)(n0 + nb) * 256 + t];
    if (t < 64) sX0[t * 8 + nb] = v;
    else        sX1[(t - 64) * 8 + nb] = v;
  }
  if (t < 40) {
    int nb = t & 7, s = t >> 3;
    sAt[s * 8 + nb] = attrs[(size_t)(n0 + nb) * 5 + s] * nr;
  }
  #pragma unroll
  for (int i = 0; i < 16; ++i) {
    int idx = i * 256 + t;
    int nb = idx >> 9;
    int c = idx & 511;
    float v = agg[(size_t)(n0 + nb) * 512 + c] * n2;
    if (c < 128) sAggS[c * 8 + nb] = v;
    else         sAggV[(c - 128) * 8 + nb] = v;
  }
  __syncthreads();

  #pragma unroll
  for (int i = 0; i < 10; ++i) {
    int idx = i * 256 + t;
    int nb = idx & 7;
    int us = idx >> 3;
    int u = us / 5;
    int s = us - u * 5;
    sA[us * 8 + nb] = sX0[u * 8 + nb] * sAt[s * 8 + nb];
  }
  __syncthreads();

  float av[8][3];

  if (t < 128) {
    const int v = t;
    float acc[8];
    #pragma unroll
    for (int nb = 0; nb < 8; ++nb) acc[nb] = 0.f;
    for (int us = 0; us < 320; ++us)
      fma8v(acc, &sA[us * 8], Wr_s[us * 128 + v]);
    for (int c = 0; c < 128; ++c)
      fma8v(acc, &sAggS[c * 8], W2s[c * 128 + v]);
    #pragma unroll
    for (int nb = 0; nb < 8; ++nb) sZs[nb * 128 + v] = acc[nb];
  } else {
    const int tv = t - 128;
    const int v = tv & 63;
    const int half = tv >> 6;
    #pragma unroll
    for (int nb = 0; nb < 8; ++nb)
      #pragma unroll
      for (int m = 0; m < 3; ++m) av[nb][m] = 0.f;

    const int u0 = half * 32;
    for (int u = u0; u < u0 + 32; ++u) {
      float xr0[8], xr1[8], xr2[8];
      ld8(xr0, &sX1[(u * 3 + 0) * 8]);
      ld8(xr1, &sX1[(u * 3 + 1) * 8]);
      ld8(xr2, &sX1[(u * 3 + 2) * 8]);
      #pragma unroll
      for (int s = 0; s < 5; ++s) {
        float w = Wr_v[(u * 5 + s) * 64 + v];
        float at[8];
        ld8(at, &sAt[s * 8]);
        #pragma unroll
        for (int nb = 0; nb < 8; ++nb) {
          float tt = at[nb] * w;
          av[nb][0] = fmaf(xr0[nb], tt, av[nb][0]);
          av[nb][1] = fmaf(xr1[nb], tt, av[nb][1]);
          av[nb][2] = fmaf(xr2[nb], tt, av[nb][2]);
        }
      }
    }
    const int c0 = half * 64;
    for (int c = c0; c < c0 + 64; ++c) {
      float w = W2v[c * 64 + v];
      float g0[8], g1[8], g2[8];
      ld8(g0, &sAggV[(c * 3 + 0) * 8]);
      ld8(g1, &sAggV[(c * 3 + 1) * 8]);
      ld8(g2, &sAggV[(c * 3 + 2) * 8]);
      #pragma unroll
      for (int nb = 0; nb < 8; ++nb) {
        av[nb][0] = fmaf(g0[nb], w, av[nb][0]);
        av[nb][1] = fmaf(g1[nb], w, av[nb][1]);
        av[nb][2] = fmaf(g2[nb], w, av[nb][2]);
      }
    }
    if (half == 0) {
      #pragma unroll
      for (int nb = 0; nb < 8; ++nb)
        #pragma unroll
        for (int m = 0; m < 3; ++m)
          sZv[nb * 192 + v * 3 + m] = av[nb][m];
    }
  }
  __syncthreads();
  if (t >= 192) {
    const int v = (t - 128) & 63;
    #pragma unroll
    for (int nb = 0; nb < 8; ++nb)
      #pragma unroll
      for (int m = 0; m < 3; ++m)
        sZv[nb * 192 + v * 3 + m] += av[nb][m];
  }
  __syncthreads();

  const int i = t - 64;
  const int ug = (t >= 64) ? (i / 3) : 0;
  #pragma unroll
  for (int nb = 0; nb < 8; ++nb) {
    float val;
    if (t < 64) {
      val = swishf(sZs[nb * 128 + t]);
    } else {
      float gate = swishf(sZs[nb * 128 + 64 + ug]);
      val = gate * sZv[nb * 192 + i];
    }
    out[(size_t)(n0 + nb) * 256 + t] = val;
  }
}

extern "C" void kernel_launch(void* const* d_in, const int* in_sizes, int n_in,
                              void* d_out, int out_size, void* d_ws, size_t ws_size,
                              hipStream_t stream)
{
  const float* feats = (const float*)d_in[0];
  const float* attrs = (const float*)d_in[1];
  const float* esh   = (const float*)d_in[2];
  const int*   snd   = (const int*)d_in[3];
  const int*   rcv   = (const int*)d_in[4];
  const float* emb   = (const float*)d_in[5];
  const float* Wl0   = (const float*)d_in[6];
  const float* Wl1   = (const float*)d_in[7];
  const float* Wm1   = (const float*)d_in[8];
  const float* Wm2   = (const float*)d_in[9];
  const float* Wm3   = (const float*)d_in[10];
  const float* W2s   = (const float*)d_in[11];
  const float* W2v   = (const float*)d_in[12];
  const float* Wr_s  = (const float*)d_in[13];
  const float* Wr_v  = (const float*)d_in[14];
  float* out = (float*)d_out;

  float* y   = (float*)d_ws;                     // NN*256 f32
  float* agg = y + (size_t)NN * 256;             // NN*512 f32
  int* counts = (int*)agg;                       // aliased transients
  int* cursor = counts + NN;
  int* csr_edge = (int*)(agg + (size_t)NN * 512);   // NE ints
  int* offsets  = csr_edge + NE;                    // NN+1 ints
  int* snd_sorted = offsets + NN + 1;               // NE ints
  float* sh_sorted = (float*)(snd_sorted + NE);     // NE*4 f32
  __half* w_sorted = (__half*)(sh_sorted + (size_t)NE * 4);  // NE*256 f16
  unsigned* Wm2P = (unsigned*)(w_sorted + (size_t)NE * 256); // 2048 u32
  unsigned* Wm3P = Wm2P + 2048;                              // 8192 u32
  unsigned* Wm3T = Wm3P + 8192;                              // 8192 u32
  unsigned* BsT  = Wm3T + 8192;                              // 28672 u32
  unsigned* BvT  = BsT + 28672;                              // 14336 u32
  size_t need1 = (size_t)((char*)(BvT + 14336) - (char*)d_ws);
  size_t need2 = (size_t)((char*)(offsets + NN + 1) - (char*)d_ws);

  if (ws_size >= need1) {
    hipMemsetAsync(counts, 0, (size_t)NN * sizeof(int), stream);
    hist_kernel<<<NE / 256, 256, 0, stream>>>(rcv, counts);
    scan_kernel<<<1, 1024, 0, stream>>>(counts, offsets, cursor);
    scatter_full<<<NE / 256, 256, 0, stream>>>(rcv, snd, esh, cursor,
                                               csr_edge, snd_sorted, sh_sorted);
    pack_weights<<<72, 256, 0, stream>>>(Wm2, Wm3, Wm2P, Wm3P, Wm3T);
    pack_node_B<<<168, 256, 0, stream>>>(Wr_s, W2s, Wr_v, W2v, BsT, BvT);
    node_prep<<<NN / 4, 256, 0, stream>>>(feats, Wl0, Wl1, y);
    w_kernel<<<NE / 256, 256, 0, stream>>>(csr_edge, emb, Wm1, Wm2P, Wm3T, w_sorted);
    gather_tp<<<NN / 4, 256, 0, stream>>>(y, w_sorted, sh_sorted, snd_sorted,
                                          offsets, agg);
    node_gemm<<<NN / 16, 256, 0, stream>>>(feats, attrs, agg, BsT, BvT, out);
  } else if (ws_size >= need2) {
    hipMemsetAsync(counts, 0, (size_t)NN * sizeof(int), stream);
    hist_kernel<<<NE / 256, 256, 0, stream>>>(rcv, counts);
    scan_kernel<<<1, 1024, 0, stream>>>(counts, offsets, cursor);
    scatter_kernel<<<NE / 256, 256, 0, stream>>>(rcv, cursor, csr_edge);
    node_prep<<<NN / 4, 256, 0, stream>>>(feats, Wl0, Wl1, y);
    gather_fused<<<NN / 8, 512, 0, stream>>>(y, csr_edge, snd, esh, emb,
                                             Wm1, Wm2, Wm3, offsets, agg);
    node_post<<<NN / 8, 256, 0, stream>>>(feats, attrs, agg, W2s, W2v, Wr_s, Wr_v, out);
  } else {
    hipMemsetAsync(agg, 0, (size_t)NN * 512 * sizeof(float), stream);
    node_prep<<<NN / 4, 256, 0, stream>>>(feats, Wl0, Wl1, y);
    edge_kernel<<<NE / 256, 256, 0, stream>>>(y, esh, snd, rcv, emb, Wm1, Wm2, Wm3, agg);
    node_post<<<NN / 8, 256, 0, stream>>>(feats, attrs, agg, W2s, W2v, Wr_s, Wr_v, out);
  }
}

// Round 20
// 332.524 us; speedup vs baseline: 1.1505x; 1.0151x over previous
//
#include <hip/hip_runtime.h>
#include <hip/hip_fp16.h>

// NequIP-style layer, f32.
// Tier 1 (~234MB ws): CSR sort -> pack_weights/pack_node_B -> node_prep ->
//   w_kernel (dot2 MLP + MFMA w-GEMM, LDS store-staging) -> gather_tp
//   (v-plane agg layout) -> node_gemm (MFMA, K-split padded LDS, register-
//   prefetched A-build pipeline, fused gate epilogue -> out).
// Tier 2 (~62.8MB ws): r7 fused gather + VALU node_post (old agg layout).
// Tier 3 (~61.4MB ws): atomic kernel + VALU node_post.

#define NN 20000
#define NE 320000

typedef _Float16 h2v __attribute__((ext_vector_type(2)));
typedef _Float16 f16x8 __attribute__((ext_vector_type(8)));
typedef float f32x4 __attribute__((ext_vector_type(4)));

__device__ __forceinline__ float swishf(float x) {
  float t = __expf(-fabsf(x));
  float r = 1.0f / (1.0f + t);
  float sig = (x >= 0.0f) ? r : t * r;
  return x * sig;
}

__device__ __forceinline__ unsigned pack2h(float a, float b) {
  __half2 h = __floats2half2_rn(a, b);
  return *reinterpret_cast<unsigned*>(&h);
}

__device__ __forceinline__ h2v u32h2(unsigned u) {
  union { unsigned u; h2v h; } x; x.u = u; return x.h;
}

__device__ __forceinline__ h2v packh2v(float a, float b) {
  h2v h; h.x = (_Float16)a; h.y = (_Float16)b; return h;
}

__device__ __forceinline__ f16x8 u4f16(uint4 u) {
  union { uint4 u; f16x8 h; } x; x.u = u; return x.h;
}

__device__ __forceinline__ void ld8(float d[8], const float* p) {
  float4 a0 = *(const float4*)p;
  float4 a1 = *(const float4*)(p + 4);
  d[0]=a0.x; d[1]=a0.y; d[2]=a0.z; d[3]=a0.w;
  d[4]=a1.x; d[5]=a1.y; d[6]=a1.z; d[7]=a1.w;
}

__device__ __forceinline__ void fma8v(float (&acc)[8], const float* p, float w) {
  float4 a0 = *(const float4*)p;
  float4 a1 = *(const float4*)(p + 4);
  acc[0] = fmaf(a0.x, w, acc[0]); acc[1] = fmaf(a0.y, w, acc[1]);
  acc[2] = fmaf(a0.z, w, acc[2]); acc[3] = fmaf(a0.w, w, acc[3]);
  acc[4] = fmaf(a1.x, w, acc[4]); acc[5] = fmaf(a1.y, w, acc[5]);
  acc[6] = fmaf(a1.z, w, acc[6]); acc[7] = fmaf(a1.w, w, acc[7]);
}

// ---------------- CSR build ----------------
__global__ __launch_bounds__(256) void hist_kernel(const int* __restrict__ rcv,
                                                   int* __restrict__ counts) {
  int e = blockIdx.x * 256 + threadIdx.x;
  atomicAdd(&counts[rcv[e]], 1);
}

__global__ __launch_bounds__(1024) void scan_kernel(const int* __restrict__ counts,
                                                    int* __restrict__ offsets,
                                                    int* __restrict__ cursor) {
  __shared__ int part[1024];
  const int t = threadIdx.x;
  const int base = t * 20;
  int loc[20];
  int s = 0;
  #pragma unroll
  for (int j = 0; j < 20; ++j) {
    int idx = base + j;
    int c = (idx < NN) ? counts[idx] : 0;
    loc[j] = s;
    s += c;
  }
  part[t] = s;
  __syncthreads();
  for (int d = 1; d < 1024; d <<= 1) {
    int v = (t >= d) ? part[t - d] : 0;
    __syncthreads();
    part[t] += v;
    __syncthreads();
  }
  int excl = (t > 0) ? part[t - 1] : 0;
  #pragma unroll
  for (int j = 0; j < 20; ++j) {
    int idx = base + j;
    if (idx < NN) {
      int o = excl + loc[j];
      offsets[idx] = o;
      cursor[idx] = o;
    }
  }
  if (t == 1023) offsets[NN] = part[1023];
}

__global__ __launch_bounds__(256) void scatter_full(
    const int* __restrict__ rcv, const int* __restrict__ snd,
    const float* __restrict__ esh, int* __restrict__ cursor,
    int* __restrict__ csr_edge, int* __restrict__ snd_sorted,
    float* __restrict__ sh_sorted) {
  int e = blockIdx.x * 256 + threadIdx.x;
  int r = rcv[e];
  int pos = atomicAdd(&cursor[r], 1);
  csr_edge[pos] = e;
  snd_sorted[pos] = snd[e];
  float4 sh = *(const float4*)(esh + (size_t)e * 4);
  *(float4*)(sh_sorted + (size_t)pos * 4) = sh;
}

__global__ __launch_bounds__(256) void scatter_kernel(
    const int* __restrict__ rcv, int* __restrict__ cursor,
    int* __restrict__ csr_edge) {
  int e = blockIdx.x * 256 + threadIdx.x;
  int r = rcv[e];
  int pos = atomicAdd(&cursor[r], 1);
  csr_edge[pos] = e;
}

// ---------------- pack Wm2/Wm3 into f16 k-pair tables ----------------
__global__ __launch_bounds__(256) void pack_weights(
    const float* __restrict__ Wm2, const float* __restrict__ Wm3,
    unsigned* __restrict__ Wm2P, unsigned* __restrict__ Wm3P,
    unsigned* __restrict__ Wm3T) {
  int idx = blockIdx.x * 256 + threadIdx.x;
  if (idx < 2048) {
    int k2 = idx >> 6, v = idx & 63;
    Wm2P[idx] = pack2h(Wm2[(2 * k2) * 64 + v], Wm2[(2 * k2 + 1) * 64 + v]);
  } else if (idx < 10240) {
    int r = idx - 2048;
    int k2 = r >> 8, c = r & 255;
    Wm3P[r] = pack2h(Wm3[(2 * k2) * 256 + c], Wm3[(2 * k2 + 1) * 256 + c]);
  } else if (idx < 18432) {
    int r = idx - 10240;
    int c = r >> 5, j = r & 31;
    Wm3T[r] = pack2h(Wm3[(2 * j) * 256 + c], Wm3[(2 * j + 1) * 256 + c]);
  }
}

// ---------------- pack node-side B^T tables (scales folded) ----------------
__global__ __launch_bounds__(256) void pack_node_B(
    const float* __restrict__ Wr_s, const float* __restrict__ W2s,
    const float* __restrict__ Wr_v, const float* __restrict__ W2v,
    unsigned* __restrict__ BsT, unsigned* __restrict__ BvT) {
  const float nr = 0.05590169943749474f;   // 1/sqrt(320)
  const float n2 = 0.08838834764831845f;   // 1/sqrt(128)
  int idx = blockIdx.x * 256 + threadIdx.x;
  if (idx < 28672) {
    int v = idx / 224, j = idx % 224;
    float a, b;
    if (j < 160) {
      int s = j >> 5, u0 = (j & 31) << 1;
      a = Wr_s[(u0 * 5 + s) * 128 + v] * nr;
      b = Wr_s[((u0 + 1) * 5 + s) * 128 + v] * nr;
    } else {
      int c0 = (j - 160) << 1;
      a = W2s[c0 * 128 + v] * n2;
      b = W2s[(c0 + 1) * 128 + v] * n2;
    }
    BsT[idx] = pack2h(a, b);
  } else if (idx < 43008) {
    int r = idx - 28672;
    int v = r / 224, j = r % 224;
    float a, b;
    if (j < 160) {
      int s = j >> 5, u0 = (j & 31) << 1;
      a = Wr_v[(u0 * 5 + s) * 64 + v] * nr;
      b = Wr_v[((u0 + 1) * 5 + s) * 64 + v] * nr;
    } else {
      int c0 = (j - 160) << 1;
      a = W2v[c0 * 64 + v] * n2;
      b = W2v[(c0 + 1) * 64 + v] * n2;
    }
    BvT[r] = pack2h(a, b);
  }
}

// ---------------- node_prep: y = [x0@Wl0, x1@Wl1] * nl ----------------
__global__ __launch_bounds__(256) void node_prep(
    const float* __restrict__ feats, const float* __restrict__ Wl0,
    const float* __restrict__ Wl1, float* __restrict__ y)
{
  __shared__ __align__(16) float sX[4 * 256];
  const int t = threadIdx.x;
  const int n0 = blockIdx.x * 4;
  #pragma unroll
  for (int nb = 0; nb < 4; ++nb)
    sX[nb * 256 + t] = feats[(size_t)(n0 + nb) * 256 + t];
  __syncthreads();

  float acc[4] = {0.f, 0.f, 0.f, 0.f};
  if (t < 64) {
    const int v = t;
    for (int u = 0; u < 64; ++u) {
      float w = Wl0[u * 64 + v];
      acc[0] = fmaf(sX[0 * 256 + u], w, acc[0]);
      acc[1] = fmaf(sX[1 * 256 + u], w, acc[1]);
      acc[2] = fmaf(sX[2 * 256 + u], w, acc[2]);
      acc[3] = fmaf(sX[3 * 256 + u], w, acc[3]);
    }
  } else {
    const int i = t - 64;
    const int v = i / 3;
    const int m = i - v * 3;
    for (int u = 0; u < 64; ++u) {
      float w = Wl1[u * 64 + v];
      int xi = 64 + u * 3 + m;
      acc[0] = fmaf(sX[0 * 256 + xi], w, acc[0]);
      acc[1] = fmaf(sX[1 * 256 + xi], w, acc[1]);
      acc[2] = fmaf(sX[2 * 256 + xi], w, acc[2]);
      acc[3] = fmaf(sX[3 * 256 + xi], w, acc[3]);
    }
  }
  #pragma unroll
  for (int nb = 0; nb < 4; ++nb)
    y[(size_t)(n0 + nb) * 256 + t] = acc[nb] * 0.125f;   // nl = 1/sqrt(64)
}

// GEMV helper (fallback paths, f32)
__device__ __forceinline__ void wgemv(float (&wa)[64], const float* __restrict__ Wm3,
                                      const float* h2col, int p)
{
  #pragma unroll
  for (int v = 0; v < 64; ++v) wa[v] = 0.f;
  #pragma unroll 2
  for (int k = 0; k < 64; ++k) {
    float h2k = h2col[k * 256];
    const float* wrow = Wm3 + k * 256 + p * 64;
    #pragma unroll
    for (int v = 0; v < 64; ++v) wa[v] = fmaf(h2k, wrow[v], wa[v]);
  }
}

// ---------------- tier-1 phase A: MLP h2 (dot2) + MFMA w-GEMM ----------------
__global__ __launch_bounds__(256, 4) void w_kernel(
    const int* __restrict__ csr_edge, const float* __restrict__ emb,
    const float* __restrict__ Wm1, const unsigned* __restrict__ Wm2P,
    const unsigned* __restrict__ Wm3T, __half* __restrict__ w_sorted)
{
  __shared__ unsigned sA[256 * 32];   // h2 f16 [edge][k2] swizzled; then slabs
  const int tid = threadIdx.x;
  const int i = blockIdx.x * 256 + tid;
  const int e = csr_edge[i];

  float e8[8];
  ld8(e8, emb + (size_t)e * 8);
  float h2a[64];
  #pragma unroll
  for (int v = 0; v < 64; ++v) h2a[v] = 0.f;
  #pragma unroll 1
  for (int k2 = 0; k2 < 32; ++k2) {
    float a0 = 0.f, a1 = 0.f;
    #pragma unroll
    for (int j = 0; j < 8; ++j) {
      a0 = fmaf(e8[j], Wm1[j * 64 + 2 * k2], a0);
      a1 = fmaf(e8[j], Wm1[j * 64 + 2 * k2 + 1], a1);
    }
    h2v ph = packh2v(swishf(a0 * 0.35355339059327373f),
                     swishf(a1 * 0.35355339059327373f));
    const unsigned* wrow = Wm2P + k2 * 64;
    #pragma unroll
    for (int v = 0; v < 64; ++v)
      h2a[v] = __builtin_amdgcn_fdot2(ph, u32h2(wrow[v]), h2a[v], false);
  }
  {
    const int r = tid;
    #pragma unroll
    for (int c = 0; c < 8; ++c) {
      uint4 v;
      v.x = pack2h(swishf(h2a[8 * c + 0] * 0.125f), swishf(h2a[8 * c + 1] * 0.125f));
      v.y = pack2h(swishf(h2a[8 * c + 2] * 0.125f), swishf(h2a[8 * c + 3] * 0.125f));
      v.z = pack2h(swishf(h2a[8 * c + 4] * 0.125f), swishf(h2a[8 * c + 5] * 0.125f));
      v.w = pack2h(swishf(h2a[8 * c + 6] * 0.125f), swishf(h2a[8 * c + 7] * 0.125f));
      *(uint4*)&sA[r * 32 + ((c ^ (r & 7)) << 2)] = v;
    }
  }
  __syncthreads();

  const int l = tid & 63;
  const int wv = tid >> 6;
  const int lg = l >> 4;
  const int lm = l & 15;

  f16x8 bfr[4][2];
  #pragma unroll
  for (int nt = 0; nt < 4; ++nt) {
    int row = wv * 64 + nt * 16 + lm;
    #pragma unroll
    for (int kh = 0; kh < 2; ++kh) {
      uint4 u = *(const uint4*)&sA[row * 32 + ((((kh << 2) + lg) ^ (row & 7)) << 2)];
      bfr[nt][kh] = u4f16(u);
    }
  }
  unsigned* sTw = sA + wv * 2048;
  const int eb = blockIdx.x * 256 + wv * 64;

  #pragma unroll 1
  for (int p = 0; p < 4; ++p) {
    #pragma unroll
    for (int mtl = 0; mtl < 4; ++mtl) {
      const int mt = p * 4 + mtl;
      int arow = mt * 16 + lm;
      uint4 u0 = *(const uint4*)&Wm3T[arow * 32 + (lg << 2)];
      uint4 u1 = *(const uint4*)&Wm3T[arow * 32 + 16 + (lg << 2)];
      f16x8 a0 = u4f16(u0), a1 = u4f16(u1);
      #pragma unroll
      for (int nt = 0; nt < 4; ++nt) {
        f32x4 acc = {0.f, 0.f, 0.f, 0.f};
        acc = __builtin_amdgcn_mfma_f32_16x16x32_f16(a0, bfr[nt][0], acc, 0, 0, 0);
        acc = __builtin_amdgcn_mfma_f32_16x16x32_f16(a1, bfr[nt][1], acc, 0, 0, 0);
        const int r = nt * 16 + lm;
        const int u = mtl * 4 + lg;
        const int pos8 = ((((u >> 1) ^ (r & 7)) << 1) | (u & 1));
        uint2 pk;
        pk.x = pack2h(acc[0], acc[1]);
        pk.y = pack2h(acc[2], acc[3]);
        *(uint2*)&sTw[r * 32 + pos8 * 2] = pk;
      }
    }
    #pragma unroll
    for (int g = 0; g < 8; ++g) {
      const int er = g * 8 + (l >> 3);
      const int c8 = l & 7;
      uint4 v = *(const uint4*)&sTw[er * 32 + ((c8 ^ (er & 7)) << 2)];
      *(uint4*)(w_sorted + (size_t)(eb + er) * 256 + p * 64 + c8 * 8) = v;
    }
  }
}

// ---------------- tier-1 phase B: per-node gather + tensor product ----------
// agg layout (tier-1): [0:64] s0, [64:128] s1, then v planes
// [128+m*128 + c]: c<64 = v-first (w2 path), c>=64 = v-second (w3 path).
__global__ __launch_bounds__(256) void gather_tp(
    const float* __restrict__ y, const __half* __restrict__ w_sorted,
    const float* __restrict__ sh_sorted, const int* __restrict__ snd_sorted,
    const int* __restrict__ offsets, float* __restrict__ agg)
{
  const int l = threadIdx.x & 63;
  const int wv = threadIdx.x >> 6;
  const int n = blockIdx.x * 4 + wv;
  const int row0 = offsets[n];
  const int row1 = offsets[n + 1];

  float s0 = 0.f, s1 = 0.f;
  float v0x = 0.f, v0y = 0.f, v0z = 0.f;
  float v1x = 0.f, v1y = 0.f, v1z = 0.f;

  for (int i = row0; i < row1; ++i) {
    const int s = snd_sorted[i];
    const float4 sh = *(const float4*)(sh_sorted + (size_t)i * 4);
    const __half* wr = w_sorted + (size_t)i * 256;
    float w1 = __half2float(wr[l]);
    float w2 = __half2float(wr[64 + l]);
    float w3 = __half2float(wr[128 + l]);
    float w4 = __half2float(wr[192 + l]);
    const float* yr = y + (size_t)s * 256;
    float e0 = yr[l];
    float ex = yr[64 + 3 * l], ey = yr[65 + 3 * l], ez = yr[66 + 3 * l];

    s0 = fmaf(w1 * e0, sh.x, s0);
    s1 = fmaf(w4, fmaf(ex, sh.y, fmaf(ey, sh.z, ez * sh.w)), s1);
    float t2 = w2 * e0;
    v0x = fmaf(t2, sh.y, v0x); v0y = fmaf(t2, sh.z, v0y); v0z = fmaf(t2, sh.w, v0z);
    float t3 = w3 * sh.x;
    v1x = fmaf(t3, ex, v1x); v1y = fmaf(t3, ey, v1y); v1z = fmaf(t3, ez, v1z);
  }

  const float SCL = 0.0078125f;                          // (1/8 w-scale) / 16
  const float C4  = 0.125f / (16.0f * 1.7320508075688772f);
  float* ar = agg + (size_t)n * 512;
  ar[l]       = s0 * SCL;
  ar[64 + l]  = s1 * C4;
  ar[128 + l]        = v0x * SCL;
  ar[128 + 64 + l]   = v1x * SCL;
  ar[256 + l]        = v0y * SCL;
  ar[256 + 64 + l]   = v1y * SCL;
  ar[384 + l]        = v0z * SCL;
  ar[384 + 64 + l]   = v1z * SCL;
}

// ---------------- tier-1: node-side MFMA GEMM + fused gate epilogue ----------
// K-split (padded 128-u32 rows) + register-prefetch pipeline:
//   prefetch(0); write(0); bar; prefetch(1); mfma(0); bar; write(1); bar;
//   mfma(1); z-store; bar; gate.
__global__ __launch_bounds__(256) void node_gemm(
    const float* __restrict__ feats, const float* __restrict__ attrs,
    const float* __restrict__ agg, const unsigned* __restrict__ BsT,
    const unsigned* __restrict__ BvT, float* __restrict__ out)
{
  __shared__ unsigned sAK[64 * 128];   // 32768B, one K-half (28 chunks used)
  __shared__ float zsL[16 * 128];      // 8192B
  __shared__ __half zvL[48 * 64];      // 6144B
  __shared__ float sAt[16 * 5];
  const int t = threadIdx.x;
  const int n0 = blockIdx.x * 16;

  if (t < 80) sAt[t] = attrs[(size_t)n0 * 5 + t];
  __syncthreads();

  const int l = t & 63;
  const int wv = t >> 6;
  const int lm = l & 15;
  const int lg = l >> 4;

  const int row = t >> 2;
  const int part = t & 3;
  const bool is_s = row < 16;
  int node, m = 0;
  if (is_s) node = row;
  else { int vi = row - 16; node = vi / 3; m = vi - node * 3; }
  const float* xrow = feats + (size_t)(n0 + node) * 256;
  const float* atr = &sAt[node * 5];
  const float* aggr = agg + (size_t)(n0 + node) * 512;
  unsigned* arow = &sAK[row * 128];

  f32x4 acc[5];
  #pragma unroll
  for (int jj = 0; jj < 5; ++jj) acc[jj] = (f32x4){0.f, 0.f, 0.f, 0.f};

  auto mfma_phase = [&](int h) {
    #pragma unroll
    for (int jj = 0; jj < 5; ++jj) {
      const int jd = wv + 4 * jj;
      int mtile, ntile;
      const unsigned* Bt;
      if (jd < 8) { mtile = 0; ntile = jd; Bt = BsT; }
      else { int q = jd - 8; mtile = 1 + (q >> 2); ntile = q & 3; Bt = BvT; }

      const int arow0 = mtile * 16 + lm;
      const unsigned* brow = Bt + (ntile * 16 + lm) * 224 + h * 112;

      uint4 ubr[7];
      #pragma unroll
      for (int ks = 0; ks < 7; ++ks)
        ubr[ks] = *(const uint4*)&brow[(ks * 4 + lg) << 2];

      f32x4 a = acc[jj];
      #pragma unroll
      for (int ks = 0; ks < 7; ++ks) {
        int ch = ks * 4 + lg;
        int chs = (ch & ~7) | ((ch ^ arow0) & 7);
        uint4 ua = *(const uint4*)&sAK[arow0 * 128 + (chs << 2)];
        a = __builtin_amdgcn_mfma_f32_16x16x32_f16(u4f16(ua), u4f16(ubr[ks]), a, 0, 0, 0);
      }
      acc[jj] = a;
    }
  };

  float r0[28], r1[28];

  // ---- prefetch half 0 (all x-part: jg = part+4*jj <= 111 < 160) ----
  #pragma unroll
  for (int jj = 0; jj < 28; ++jj) {
    const int jg = part + 4 * jj;
    int u0 = (jg & 31) << 1;
    if (is_s) { r0[jj] = xrow[u0];              r1[jj] = xrow[u0 + 1]; }
    else      { r0[jj] = xrow[64 + 3 * u0 + m]; r1[jj] = xrow[64 + 3 * u0 + 3 + m]; }
  }

  // ---- write half 0 ----
  #pragma unroll
  for (int jj = 0; jj < 28; ++jj) {
    const int jg = part + 4 * jj;
    float a = atr[jg >> 5];
    int chs = (jj & ~7) | ((jj ^ row) & 7);
    arow[(chs << 2) + part] = pack2h(r0[jj] * a, r1[jj] * a);
  }
  __syncthreads();

  // ---- prefetch half 1 (jj<12: x-part; jj>=12: agg) — overlaps mfma(0) ----
  #pragma unroll
  for (int jj = 0; jj < 28; ++jj) {
    const int jg = 112 + part + 4 * jj;
    if (jj < 12) {
      int u0 = (jg & 31) << 1;
      if (is_s) { r0[jj] = xrow[u0];              r1[jj] = xrow[u0 + 1]; }
      else      { r0[jj] = xrow[64 + 3 * u0 + m]; r1[jj] = xrow[64 + 3 * u0 + 3 + m]; }
    } else {
      int c0 = (jg - 160) << 1;
      if (is_s) { r0[jj] = aggr[c0];                  r1[jj] = aggr[c0 + 1]; }
      else      { r0[jj] = aggr[128 + m * 128 + c0];  r1[jj] = aggr[128 + m * 128 + c0 + 1]; }
    }
  }

  mfma_phase(0);
  __syncthreads();

  // ---- write half 1 (loads landed during mfma(0)) ----
  #pragma unroll
  for (int jj = 0; jj < 28; ++jj) {
    const int jg = 112 + part + 4 * jj;
    float v0, v1;
    if (jj < 12) {
      float a = atr[jg >> 5];
      v0 = r0[jj] * a; v1 = r1[jj] * a;
    } else {
      v0 = r0[jj]; v1 = r1[jj];
    }
    int chs = (jj & ~7) | ((jj ^ row) & 7);
    arow[(chs << 2) + part] = pack2h(v0, v1);
  }
  __syncthreads();

  mfma_phase(1);

  // ---- store z to LDS ----
  #pragma unroll
  for (int jj = 0; jj < 5; ++jj) {
    const int jd = wv + 4 * jj;
    int mtile, ntile;
    if (jd < 8) { mtile = 0; ntile = jd; }
    else { int q = jd - 8; mtile = 1 + (q >> 2); ntile = q & 3; }
    const int drow = mtile * 16 + lg * 4;
    if (jd < 8) {
      #pragma unroll
      for (int rr = 0; rr < 4; ++rr)
        zsL[(drow + rr) * 128 + ntile * 16 + lm] = acc[jj][rr];
    } else {
      const int vi0 = drow - 16;
      #pragma unroll
      for (int rr = 0; rr < 4; ++rr)
        zvL[(vi0 + rr) * 64 + ntile * 16 + lm] = __float2half(acc[jj][rr]);
    }
  }
  __syncthreads();

  // ---- gate epilogue ----
  int ug = 0, mg = 0;
  if (t >= 64) { ug = (t - 64) / 3; mg = (t - 64) - ug * 3; }
  #pragma unroll 4
  for (int nb = 0; nb < 16; ++nb) {
    float val;
    if (t < 64) {
      val = swishf(zsL[nb * 128 + t]);
    } else {
      float gate = swishf(zsL[nb * 128 + 64 + ug]);
      val = gate * __half2float(zvL[(nb * 3 + mg) * 64 + ug]);
    }
    out[(size_t)(n0 + nb) * 256 + t] = val;
  }
}

// ---------------- tier-2: r7 fused gather (old agg layout) ----------------
__global__ __launch_bounds__(512, 2) void gather_fused(
    const float* __restrict__ y, const int* __restrict__ csr_edge,
    const int* __restrict__ snd, const float* __restrict__ esh,
    const float* __restrict__ emb, const float* __restrict__ Wm1,
    const float* __restrict__ Wm2, const float* __restrict__ Wm3,
    const int* __restrict__ offsets, float* __restrict__ agg)
{
  __shared__ __align__(16) float sW3[64 * 256];
  __shared__ __align__(16) float sH[8 * 4 * 64];
  const int t = threadIdx.x;

  #pragma unroll 4
  for (int i = 0; i < 32; ++i) {
    int idx = i * 512 + t;
    int k = idx >> 8;
    int c = idx & 255;
    float v = Wm3[idx];
    int kg = k >> 2, kk = k & 3;
    sW3[c * 64 + (((kg ^ (c & 15)) & 15) << 2) + kk] = v;
  }
  __syncthreads();

  const int l = t & 63;
  const int wv = t >> 6;
  const int n = blockIdx.x * 8 + wv;
  const int row0 = offsets[n];
  const int row1 = offsets[n + 1];

  float* sHw = &sH[wv * 256];

  float wm1r[8];
  #pragma unroll
  for (int j = 0; j < 8; ++j) wm1r[j] = Wm1[j * 64 + l];

  float s0 = 0.f, s1 = 0.f;
  float v0x = 0.f, v0y = 0.f, v0z = 0.f;
  float v1x = 0.f, v1y = 0.f, v1z = 0.f;

  const int swz = ((l & 15) << 2);

  for (int i = row0; i < row1; i += 4) {
    const int nb = row1 - i;

    int   sn[4];
    float4 sh[4];
    #pragma unroll
    for (int b = 0; b < 4; ++b) {
      int idx = (b < nb) ? (i + b) : i;
      int e = csr_edge[idx];
      sn[b] = snd[e];
      float4 s = *(const float4*)(esh + (size_t)e * 4);
      if (b >= nb) s = make_float4(0.f, 0.f, 0.f, 0.f);
      sh[b] = s;
      float em8[8];
      ld8(em8, emb + (size_t)e * 8);
      float a = 0.f;
      #pragma unroll
      for (int j = 0; j < 8; ++j) a = fmaf(em8[j], wm1r[j], a);
      sHw[b * 64 + l] = swishf(a * 0.35355339059327373f);
    }

    float h2[4] = {0.f, 0.f, 0.f, 0.f};
    #pragma unroll 4
    for (int q = 0; q < 16; ++q) {
      float wq0 = Wm2[(4 * q + 0) * 64 + l];
      float wq1 = Wm2[(4 * q + 1) * 64 + l];
      float wq2 = Wm2[(4 * q + 2) * 64 + l];
      float wq3 = Wm2[(4 * q + 3) * 64 + l];
      #pragma unroll
      for (int b = 0; b < 4; ++b) {
        float4 h = *(const float4*)&sHw[b * 64 + 4 * q];
        h2[b] = fmaf(h.x, wq0, h2[b]);
        h2[b] = fmaf(h.y, wq1, h2[b]);
        h2[b] = fmaf(h.z, wq2, h2[b]);
        h2[b] = fmaf(h.w, wq3, h2[b]);
      }
    }
    #pragma unroll
    for (int b = 0; b < 4; ++b)
      h2[b] = swishf(h2[b] * 0.125f);
    #pragma unroll
    for (int b = 0; b < 4; ++b)
      sHw[b * 64 + l] = h2[b];

    float w0[4]  = {0,0,0,0}, w1a[4] = {0,0,0,0};
    float w2a[4] = {0,0,0,0}, w3a[4] = {0,0,0,0};
    #pragma unroll 1
    for (int g = 0; g < 16; ++g) {
      int sbase = l * 64 + (((g << 2) ^ swz) & 63);
      float4 m0 = *(const float4*)&sW3[sbase];
      float4 m1 = *(const float4*)&sW3[sbase + 4096];
      float4 m2 = *(const float4*)&sW3[sbase + 8192];
      float4 m3 = *(const float4*)&sW3[sbase + 12288];
      #pragma unroll
      for (int b = 0; b < 4; ++b) {
        float4 hb = *(const float4*)&sHw[b * 64 + 4 * g];
        #pragma unroll
        for (int kk = 0; kk < 4; ++kk) {
          float bc = (&hb.x)[kk];
          w0[b]  = fmaf(bc, (&m0.x)[kk], w0[b]);
          w1a[b] = fmaf(bc, (&m1.x)[kk], w1a[b]);
          w2a[b] = fmaf(bc, (&m2.x)[kk], w2a[b]);
          w3a[b] = fmaf(bc, (&m3.x)[kk], w3a[b]);
        }
      }
    }

    #pragma unroll
    for (int b = 0; b < 4; ++b) {
      const float* yr = y + (size_t)sn[b] * 256;
      float e0 = yr[l];
      float ex = yr[64 + 3 * l], ey = yr[65 + 3 * l], ez = yr[66 + 3 * l];
      float4 s = sh[b];
      s0 = fmaf(w0[b] * e0, s.x, s0);
      s1 = fmaf(w3a[b], fmaf(ex, s.y, fmaf(ey, s.z, ez * s.w)), s1);
      float t2 = w1a[b] * e0;
      v0x = fmaf(t2, s.y, v0x); v0y = fmaf(t2, s.z, v0y); v0z = fmaf(t2, s.w, v0z);
      float t3 = w2a[b] * s.x;
      v1x = fmaf(t3, ex, v1x); v1y = fmaf(t3, ey, v1y); v1z = fmaf(t3, ez, v1z);
    }
  }

  const float SCL = 0.0078125f;
  const float C4  = 0.125f / (16.0f * 1.7320508075688772f);
  float* ar = agg + (size_t)n * 512;
  ar[l]       = s0 * SCL;
  ar[64 + l]  = s1 * C4;
  ar[128 + 3 * l]     = v0x * SCL;
  ar[128 + 3 * l + 1] = v0y * SCL;
  ar[128 + 3 * l + 2] = v0z * SCL;
  ar[320 + 3 * l]     = v1x * SCL;
  ar[320 + 3 * l + 1] = v1y * SCL;
  ar[320 + 3 * l + 2] = v1z * SCL;
}

// ---------------- tier-3: atomic edge kernel ----------------
__global__ __launch_bounds__(256) void edge_kernel(
    const float* __restrict__ y, const float* __restrict__ edge_sh,
    const int* __restrict__ senders, const int* __restrict__ receivers,
    const float* __restrict__ emb, const float* __restrict__ Wm1,
    const float* __restrict__ Wm2, const float* __restrict__ Wm3,
    float* __restrict__ agg)
{
  __shared__ float h2s[64 * 256];
  const int tid = threadIdx.x;
  const int e = blockIdx.x * 256 + tid;
  const int s = senders[e];
  const int r = receivers[e];
  const float4 shv = *(const float4*)(edge_sh + (size_t)e * 4);
  float e8[8];
  ld8(e8, emb + (size_t)e * 8);

  float h2a[64];
  #pragma unroll
  for (int v = 0; v < 64; ++v) h2a[v] = 0.f;
  #pragma unroll 2
  for (int k = 0; k < 64; ++k) {
    float a = 0.f;
    #pragma unroll
    for (int j = 0; j < 8; ++j) a = fmaf(e8[j], Wm1[j * 64 + k], a);
    float h1k = swishf(a * 0.35355339059327373f);
    const float* wrow = Wm2 + k * 64;
    #pragma unroll
    for (int v = 0; v < 64; ++v) h2a[v] = fmaf(h1k, wrow[v], h2a[v]);
  }
  #pragma unroll
  for (int v = 0; v < 64; ++v)
    h2s[v * 256 + tid] = swishf(h2a[v] * 0.125f);

  const float* yrow = y + (size_t)s * 256;
  float* aggr = agg + (size_t)r * 512;
  const float SCL = 0.0078125f;
  const float c0  = shv.x * SCL;
  const float c1x = shv.y * SCL, c1y = shv.z * SCL, c1z = shv.w * SCL;
  const float c4  = 0.125f / (16.0f * 1.7320508075688772f);

  float wa[64];

  wgemv(wa, Wm3, h2s + tid, 0);
  #pragma unroll
  for (int uc = 0; uc < 8; ++uc) {
    float ev[8];
    ld8(ev, yrow + uc * 8);
    #pragma unroll
    for (int j = 0; j < 8; ++j) {
      int u = uc * 8 + j;
      atomicAdd(&aggr[u], wa[u] * ev[j] * c0);
    }
  }
  wgemv(wa, Wm3, h2s + tid, 1);
  #pragma unroll
  for (int uc = 0; uc < 8; ++uc) {
    float ev[8];
    ld8(ev, yrow + uc * 8);
    #pragma unroll
    for (int j = 0; j < 8; ++j) {
      int u = uc * 8 + j;
      float tt = wa[u] * ev[j];
      atomicAdd(&aggr[128 + 3 * u    ], tt * c1x);
      atomicAdd(&aggr[128 + 3 * u + 1], tt * c1y);
      atomicAdd(&aggr[128 + 3 * u + 2], tt * c1z);
    }
  }
  wgemv(wa, Wm3, h2s + tid, 2);
  #pragma unroll
  for (int uc = 0; uc < 8; ++uc) {
    float ev[24];
    ld8(ev,      yrow + 64 + uc * 24);
    ld8(ev + 8,  yrow + 64 + uc * 24 + 8);
    ld8(ev + 16, yrow + 64 + uc * 24 + 16);
    #pragma unroll
    for (int j = 0; j < 8; ++j) {
      int u = uc * 8 + j;
      float tt = wa[u] * c0;
      atomicAdd(&aggr[320 + 3 * u    ], tt * ev[3 * j    ]);
      atomicAdd(&aggr[320 + 3 * u + 1], tt * ev[3 * j + 1]);
      atomicAdd(&aggr[320 + 3 * u + 2], tt * ev[3 * j + 2]);
    }
  }
  wgemv(wa, Wm3, h2s + tid, 3);
  #pragma unroll
  for (int uc = 0; uc < 8; ++uc) {
    float ev[24];
    ld8(ev,      yrow + 64 + uc * 24);
    ld8(ev + 8,  yrow + 64 + uc * 24 + 8);
    ld8(ev + 16, yrow + 64 + uc * 24 + 16);
    #pragma unroll
    for (int j = 0; j < 8; ++j) {
      int u = uc * 8 + j;
      float d = ev[3*j]*shv.y + ev[3*j+1]*shv.z + ev[3*j+2]*shv.w;
      atomicAdd(&aggr[64 + u], wa[u] * d * c4);
    }
  }
}

// ---------------- VALU node_post (tier-2/3 fallback, old agg layout) --------
__global__ __launch_bounds__(256) void node_post(
    const float* __restrict__ feats, const float* __restrict__ attrs,
    const float* __restrict__ agg, const float* __restrict__ W2s,
    const float* __restrict__ W2v, const float* __restrict__ Wr_s,
    const float* __restrict__ Wr_v, float* __restrict__ out)
{
  __shared__ __align__(16) float sA[320 * 8];
  __shared__ __align__(16) float sX0[64 * 8];
  __shared__ __align__(16) float sX1[192 * 8];
  __shared__ __align__(16) float sAt[5 * 8];
  __shared__ __align__(16) float sAggS[128 * 8];
  __shared__ __align__(16) float sAggV[384 * 8];
  __shared__ __align__(16) float sZs[8 * 128];
  __shared__ __align__(16) float sZv[8 * 192];

  const int t = threadIdx.x;
  const int n0 = blockIdx.x * 8;
  const float nr = 0.05590169943749474f;
  const float n2 = 0.08838834764831845f;

  #pragma unroll
  for (int nb = 0; nb < 8; ++nb) {
    float v = feats[(size_t)(n0 + nb) * 256 + t];
    if (t < 64) sX0[t * 8 + nb] = v;
    else        sX1[(t - 64) * 8 + nb] = v;
  }
  if (t < 40) {
    int nb = t & 7, s = t >> 3;
    sAt[s * 8 + nb] = attrs[(size_t)(n0 + nb) * 5 + s] * nr;
  }
  #pragma unroll
  for (int i = 0; i < 16; ++i) {
    int idx = i * 256 + t;
    int nb = idx >> 9;
    int c = idx & 511;
    float v = agg[(size_t)(n0 + nb) * 512 + c] * n2;
    if (c < 128) sAggS[c * 8 + nb] = v;
    else         sAggV[(c - 128) * 8 + nb] = v;
  }
  __syncthreads();

  #pragma unroll
  for (int i = 0; i < 10; ++i) {
    int idx = i * 256 + t;
    int nb = idx & 7;
    int us = idx >> 3;
    int u = us / 5;
    int s = us - u * 5;
    sA[us * 8 + nb] = sX0[u * 8 + nb] * sAt[s * 8 + nb];
  }
  __syncthreads();

  float av[8][3];

  if (t < 128) {
    const int v = t;
    float acc[8];
    #pragma unroll
    for (int nb = 0; nb < 8; ++nb) acc[nb] = 0.f;
    for (int us = 0; us < 320; ++us)
      fma8v(acc, &sA[us * 8], Wr_s[us * 128 + v]);
    for (int c = 0; c < 128; ++c)
      fma8v(acc, &sAggS[c * 8], W2s[c * 128 + v]);
    #pragma unroll
    for (int nb = 0; nb < 8; ++nb) sZs[nb * 128 + v] = acc[nb];
  } else {
    const int tv = t - 128;
    const int v = tv & 63;
    const int half = tv >> 6;
    #pragma unroll
    for (int nb = 0; nb < 8; ++nb)
      #pragma unroll
      for (int m = 0; m < 3; ++m) av[nb][m] = 0.f;

    const int u0 = half * 32;
    for (int u = u0; u < u0 + 32; ++u) {
      float xr0[8], xr1[8], xr2[8];
      ld8(xr0, &sX1[(u * 3 + 0) * 8]);
      ld8(xr1, &sX1[(u * 3 + 1) * 8]);
      ld8(xr2, &sX1[(u * 3 + 2) * 8]);
      #pragma unroll
      for (int s = 0; s < 5; ++s) {
        float w = Wr_v[(u * 5 + s) * 64 + v];
        float at[8];
        ld8(at, &sAt[s * 8]);
        #pragma unroll
        for (int nb = 0; nb < 8; ++nb) {
          float tt = at[nb] * w;
          av[nb][0] = fmaf(xr0[nb], tt, av[nb][0]);
          av[nb][1] = fmaf(xr1[nb], tt, av[nb][1]);
          av[nb][2] = fmaf(xr2[nb], tt, av[nb][2]);
        }
      }
    }
    const int c0 = half * 64;
    for (int c = c0; c < c0 + 64; ++c) {
      float w = W2v[c * 64 + v];
      float g0[8], g1[8], g2[8];
      ld8(g0, &sAggV[(c * 3 + 0) * 8]);
      ld8(g1, &sAggV[(c * 3 + 1) * 8]);
      ld8(g2, &sAggV[(c * 3 + 2) * 8]);
      #pragma unroll
      for (int nb = 0; nb < 8; ++nb) {
        av[nb][0] = fmaf(g0[nb], w, av[nb][0]);
        av[nb][1] = fmaf(g1[nb], w, av[nb][1]);
        av[nb][2] = fmaf(g2[nb], w, av[nb][2]);
      }
    }
    if (half == 0) {
      #pragma unroll
      for (int nb = 0; nb < 8; ++nb)
        #pragma unroll
        for (int m = 0; m < 3; ++m)
          sZv[nb * 192 + v * 3 + m] = av[nb][m];
    }
  }
  __syncthreads();
  if (t >= 192) {
    const int v = (t - 128) & 63;
    #pragma unroll
    for (int nb = 0; nb < 8; ++nb)
      #pragma unroll
      for (int m = 0; m < 3; ++m)
        sZv[nb * 192 + v * 3 + m] += av[nb][m];
  }
  __syncthreads();

  const int i = t - 64;
  const int ug = (t >= 64) ? (i / 3) : 0;
  #pragma unroll
  for (int nb = 0; nb < 8; ++nb) {
    float val;
    if (t < 64) {
      val = swishf(sZs[nb * 128 + t]);
    } else {
      float gate = swishf(sZs[nb * 128 + 64 + ug]);
      val = gate * sZv[nb * 192 + i];
    }
    out[(size_t)(n0 + nb) * 256 + t] = val;
  }
}

extern "C" void kernel_launch(void* const* d_in, const int* in_sizes, int n_in,
                              void* d_out, int out_size, void* d_ws, size_t ws_size,
                              hipStream_t stream)
{
  const float* feats = (const float*)d_in[0];
  const float* attrs = (const float*)d_in[1];
  const float* esh   = (const float*)d_in[2];
  const int*   snd   = (const int*)d_in[3];
  const int*   rcv   = (const int*)d_in[4];
  const float* emb   = (const float*)d_in[5];
  const float* Wl0   = (const float*)d_in[6];
  const float* Wl1   = (const float*)d_in[7];
  const float* Wm1   = (const float*)d_in[8];
  const float* Wm2   = (const float*)d_in[9];
  const float* Wm3   = (const float*)d_in[10];
  const float* W2s   = (const float*)d_in[11];
  const float* W2v   = (const float*)d_in[12];
  const float* Wr_s  = (const float*)d_in[13];
  const float* Wr_v  = (const float*)d_in[14];
  float* out = (float*)d_out;

  float* y   = (float*)d_ws;                     // NN*256 f32
  float* agg = y + (size_t)NN * 256;             // NN*512 f32
  int* counts = (int*)agg;                       // aliased transients
  int* cursor = counts + NN;
  int* csr_edge = (int*)(agg + (size_t)NN * 512);   // NE ints
  int* offsets  = csr_edge + NE;                    // NN+1 ints
  int* snd_sorted = offsets + NN + 1;               // NE ints
  float* sh_sorted = (float*)(snd_sorted + NE);     // NE*4 f32
  __half* w_sorted = (__half*)(sh_sorted + (size_t)NE * 4);  // NE*256 f16
  unsigned* Wm2P = (unsigned*)(w_sorted + (size_t)NE * 256); // 2048 u32
  unsigned* Wm3P = Wm2P + 2048;                              // 8192 u32
  unsigned* Wm3T = Wm3P + 8192;                              // 8192 u32
  unsigned* BsT  = Wm3T + 8192;                              // 28672 u32
  unsigned* BvT  = BsT + 28672;                              // 14336 u32
  size_t need1 = (size_t)((char*)(BvT + 14336) - (char*)d_ws);
  size_t need2 = (size_t)((char*)(offsets + NN + 1) - (char*)d_ws);

  if (ws_size >= need1) {
    hipMemsetAsync(counts, 0, (size_t)NN * sizeof(int), stream);
    hist_kernel<<<NE / 256, 256, 0, stream>>>(rcv, counts);
    scan_kernel<<<1, 1024, 0, stream>>>(counts, offsets, cursor);
    scatter_full<<<NE / 256, 256, 0, stream>>>(rcv, snd, esh, cursor,
                                               csr_edge, snd_sorted, sh_sorted);
    pack_weights<<<72, 256, 0, stream>>>(Wm2, Wm3, Wm2P, Wm3P, Wm3T);
    pack_node_B<<<168, 256, 0, stream>>>(Wr_s, W2s, Wr_v, W2v, BsT, BvT);
    node_prep<<<NN / 4, 256, 0, stream>>>(feats, Wl0, Wl1, y);
    w_kernel<<<NE / 256, 256, 0, stream>>>(csr_edge, emb, Wm1, Wm2P, Wm3T, w_sorted);
    gather_tp<<<NN / 4, 256, 0, stream>>>(y, w_sorted, sh_sorted, snd_sorted,
                                          offsets, agg);
    node_gemm<<<NN / 16, 256, 0, stream>>>(feats, attrs, agg, BsT, BvT, out);
  } else if (ws_size >= need2) {
    hipMemsetAsync(counts, 0, (size_t)NN * sizeof(int), stream);
    hist_kernel<<<NE / 256, 256, 0, stream>>>(rcv, counts);
    scan_kernel<<<1, 1024, 0, stream>>>(counts, offsets, cursor);
    scatter_kernel<<<NE / 256, 256, 0, stream>>>(rcv, cursor, csr_edge);
    node_prep<<<NN / 4, 256, 0, stream>>>(feats, Wl0, Wl1, y);
    gather_fused<<<NN / 8, 512, 0, stream>>>(y, csr_edge, snd, esh, emb,
                                             Wm1, Wm2, Wm3, offsets, agg);
    node_post<<<NN / 8, 256, 0, stream>>>(feats, attrs, agg, W2s, W2v, Wr_s, Wr_v, out);
  } else {
    hipMemsetAsync(agg, 0, (size_t)NN * 512 * sizeof(float), stream);
    node_prep<<<NN / 4, 256, 0, stream>>>(feats, Wl0, Wl1, y);
    edge_kernel<<<NE / 256, 256, 0, stream>>>(y, esh, snd, rcv, emb, Wm1, Wm2, Wm3, agg);
    node_post<<<NN / 8, 256, 0, stream>>>(feats, attrs, agg, W2s, W2v, Wr_s, Wr_v, out);
  }
}

// Round 21
// 317.289 us; speedup vs baseline: 1.2058x; 1.0480x over previous
//
#include <hip/hip_runtime.h>
#include <hip/hip_fp16.h>

// NequIP-style layer, f32.
// Tier 1 (~234MB ws): CSR sort -> pack_weights/pack_node_B -> node_prep ->
//   w_kernel (h1 VALU; h2 via MFMA; MFMA w-GEMM; LDS store-staging) ->
//   gather_tp (v-plane agg) -> node_gemm (MFMA, K-split, reg-prefetch
//   pipeline, fused gate -> out).
// Tier 2 (~62.8MB ws): r7 fused gather + VALU node_post (old agg layout).
// Tier 3 (~61.4MB ws): atomic kernel + VALU node_post.

#define NN 20000
#define NE 320000

typedef _Float16 h2v __attribute__((ext_vector_type(2)));
typedef _Float16 f16x8 __attribute__((ext_vector_type(8)));
typedef float f32x4 __attribute__((ext_vector_type(4)));

__device__ __forceinline__ float swishf(float x) {
  float t = __expf(-fabsf(x));
  float r = 1.0f / (1.0f + t);
  float sig = (x >= 0.0f) ? r : t * r;
  return x * sig;
}

__device__ __forceinline__ unsigned pack2h(float a, float b) {
  __half2 h = __floats2half2_rn(a, b);
  return *reinterpret_cast<unsigned*>(&h);
}

__device__ __forceinline__ h2v u32h2(unsigned u) {
  union { unsigned u; h2v h; } x; x.u = u; return x.h;
}

__device__ __forceinline__ f16x8 u4f16(uint4 u) {
  union { uint4 u; f16x8 h; } x; x.u = u; return x.h;
}

__device__ __forceinline__ void ld8(float d[8], const float* p) {
  float4 a0 = *(const float4*)p;
  float4 a1 = *(const float4*)(p + 4);
  d[0]=a0.x; d[1]=a0.y; d[2]=a0.z; d[3]=a0.w;
  d[4]=a1.x; d[5]=a1.y; d[6]=a1.z; d[7]=a1.w;
}

__device__ __forceinline__ void fma8v(float (&acc)[8], const float* p, float w) {
  float4 a0 = *(const float4*)p;
  float4 a1 = *(const float4*)(p + 4);
  acc[0] = fmaf(a0.x, w, acc[0]); acc[1] = fmaf(a0.y, w, acc[1]);
  acc[2] = fmaf(a0.z, w, acc[2]); acc[3] = fmaf(a0.w, w, acc[3]);
  acc[4] = fmaf(a1.x, w, acc[4]); acc[5] = fmaf(a1.y, w, acc[5]);
  acc[6] = fmaf(a1.z, w, acc[6]); acc[7] = fmaf(a1.w, w, acc[7]);
}

// ---------------- CSR build ----------------
__global__ __launch_bounds__(256) void hist_kernel(const int* __restrict__ rcv,
                                                   int* __restrict__ counts) {
  int e = blockIdx.x * 256 + threadIdx.x;
  atomicAdd(&counts[rcv[e]], 1);
}

__global__ __launch_bounds__(1024) void scan_kernel(const int* __restrict__ counts,
                                                    int* __restrict__ offsets,
                                                    int* __restrict__ cursor) {
  __shared__ int part[1024];
  const int t = threadIdx.x;
  const int base = t * 20;
  int loc[20];
  int s = 0;
  #pragma unroll
  for (int j = 0; j < 20; ++j) {
    int idx = base + j;
    int c = (idx < NN) ? counts[idx] : 0;
    loc[j] = s;
    s += c;
  }
  part[t] = s;
  __syncthreads();
  for (int d = 1; d < 1024; d <<= 1) {
    int v = (t >= d) ? part[t - d] : 0;
    __syncthreads();
    part[t] += v;
    __syncthreads();
  }
  int excl = (t > 0) ? part[t - 1] : 0;
  #pragma unroll
  for (int j = 0; j < 20; ++j) {
    int idx = base + j;
    if (idx < NN) {
      int o = excl + loc[j];
      offsets[idx] = o;
      cursor[idx] = o;
    }
  }
  if (t == 1023) offsets[NN] = part[1023];
}

__global__ __launch_bounds__(256) void scatter_full(
    const int* __restrict__ rcv, const int* __restrict__ snd,
    const float* __restrict__ esh, int* __restrict__ cursor,
    int* __restrict__ csr_edge, int* __restrict__ snd_sorted,
    float* __restrict__ sh_sorted) {
  int e = blockIdx.x * 256 + threadIdx.x;
  int r = rcv[e];
  int pos = atomicAdd(&cursor[r], 1);
  csr_edge[pos] = e;
  snd_sorted[pos] = snd[e];
  float4 sh = *(const float4*)(esh + (size_t)e * 4);
  *(float4*)(sh_sorted + (size_t)pos * 4) = sh;
}

__global__ __launch_bounds__(256) void scatter_kernel(
    const int* __restrict__ rcv, int* __restrict__ cursor,
    int* __restrict__ csr_edge) {
  int e = blockIdx.x * 256 + threadIdx.x;
  int r = rcv[e];
  int pos = atomicAdd(&cursor[r], 1);
  csr_edge[pos] = e;
}

// ---------------- pack Wm2/Wm3 into f16 tables ----------------
// Wm2P[k2*64+v] (k-major, legacy), Wm3P (legacy), Wm3T[c*32+k2] (c-major),
// Wm2T[v*32+k2] (v-major, for h2 MFMA A-fragments).
__global__ __launch_bounds__(256) void pack_weights(
    const float* __restrict__ Wm2, const float* __restrict__ Wm3,
    unsigned* __restrict__ Wm2P, unsigned* __restrict__ Wm3P,
    unsigned* __restrict__ Wm3T, unsigned* __restrict__ Wm2T) {
  int idx = blockIdx.x * 256 + threadIdx.x;
  if (idx < 2048) {
    int k2 = idx >> 6, v = idx & 63;
    Wm2P[idx] = pack2h(Wm2[(2 * k2) * 64 + v], Wm2[(2 * k2 + 1) * 64 + v]);
  } else if (idx < 10240) {
    int r = idx - 2048;
    int k2 = r >> 8, c = r & 255;
    Wm3P[r] = pack2h(Wm3[(2 * k2) * 256 + c], Wm3[(2 * k2 + 1) * 256 + c]);
  } else if (idx < 18432) {
    int r = idx - 10240;
    int c = r >> 5, j = r & 31;
    Wm3T[r] = pack2h(Wm3[(2 * j) * 256 + c], Wm3[(2 * j + 1) * 256 + c]);
  } else if (idx < 20480) {
    int r = idx - 18432;
    int v = r >> 5, k2 = r & 31;
    Wm2T[r] = pack2h(Wm2[(2 * k2) * 64 + v], Wm2[(2 * k2 + 1) * 64 + v]);
  }
}

// ---------------- pack node-side B^T tables (scales folded) ----------------
__global__ __launch_bounds__(256) void pack_node_B(
    const float* __restrict__ Wr_s, const float* __restrict__ W2s,
    const float* __restrict__ Wr_v, const float* __restrict__ W2v,
    unsigned* __restrict__ BsT, unsigned* __restrict__ BvT) {
  const float nr = 0.05590169943749474f;   // 1/sqrt(320)
  const float n2 = 0.08838834764831845f;   // 1/sqrt(128)
  int idx = blockIdx.x * 256 + threadIdx.x;
  if (idx < 28672) {
    int v = idx / 224, j = idx % 224;
    float a, b;
    if (j < 160) {
      int s = j >> 5, u0 = (j & 31) << 1;
      a = Wr_s[(u0 * 5 + s) * 128 + v] * nr;
      b = Wr_s[((u0 + 1) * 5 + s) * 128 + v] * nr;
    } else {
      int c0 = (j - 160) << 1;
      a = W2s[c0 * 128 + v] * n2;
      b = W2s[(c0 + 1) * 128 + v] * n2;
    }
    BsT[idx] = pack2h(a, b);
  } else if (idx < 43008) {
    int r = idx - 28672;
    int v = r / 224, j = r % 224;
    float a, b;
    if (j < 160) {
      int s = j >> 5, u0 = (j & 31) << 1;
      a = Wr_v[(u0 * 5 + s) * 64 + v] * nr;
      b = Wr_v[((u0 + 1) * 5 + s) * 64 + v] * nr;
    } else {
      int c0 = (j - 160) << 1;
      a = W2v[c0 * 64 + v] * n2;
      b = W2v[(c0 + 1) * 64 + v] * n2;
    }
    BvT[r] = pack2h(a, b);
  }
}

// ---------------- node_prep: y = [x0@Wl0, x1@Wl1] * nl ----------------
__global__ __launch_bounds__(256) void node_prep(
    const float* __restrict__ feats, const float* __restrict__ Wl0,
    const float* __restrict__ Wl1, float* __restrict__ y)
{
  __shared__ __align__(16) float sX[4 * 256];
  const int t = threadIdx.x;
  const int n0 = blockIdx.x * 4;
  #pragma unroll
  for (int nb = 0; nb < 4; ++nb)
    sX[nb * 256 + t] = feats[(size_t)(n0 + nb) * 256 + t];
  __syncthreads();

  float acc[4] = {0.f, 0.f, 0.f, 0.f};
  if (t < 64) {
    const int v = t;
    for (int u = 0; u < 64; ++u) {
      float w = Wl0[u * 64 + v];
      acc[0] = fmaf(sX[0 * 256 + u], w, acc[0]);
      acc[1] = fmaf(sX[1 * 256 + u], w, acc[1]);
      acc[2] = fmaf(sX[2 * 256 + u], w, acc[2]);
      acc[3] = fmaf(sX[3 * 256 + u], w, acc[3]);
    }
  } else {
    const int i = t - 64;
    const int v = i / 3;
    const int m = i - v * 3;
    for (int u = 0; u < 64; ++u) {
      float w = Wl1[u * 64 + v];
      int xi = 64 + u * 3 + m;
      acc[0] = fmaf(sX[0 * 256 + xi], w, acc[0]);
      acc[1] = fmaf(sX[1 * 256 + xi], w, acc[1]);
      acc[2] = fmaf(sX[2 * 256 + xi], w, acc[2]);
      acc[3] = fmaf(sX[3 * 256 + xi], w, acc[3]);
    }
  }
  #pragma unroll
  for (int nb = 0; nb < 4; ++nb)
    y[(size_t)(n0 + nb) * 256 + t] = acc[nb] * 0.125f;   // nl = 1/sqrt(64)
}

// GEMV helper (fallback paths, f32)
__device__ __forceinline__ void wgemv(float (&wa)[64], const float* __restrict__ Wm3,
                                      const float* h2col, int p)
{
  #pragma unroll
  for (int v = 0; v < 64; ++v) wa[v] = 0.f;
  #pragma unroll 2
  for (int k = 0; k < 64; ++k) {
    float h2k = h2col[k * 256];
    const float* wrow = Wm3 + k * 256 + p * 64;
    #pragma unroll
    for (int v = 0; v < 64; ++v) wa[v] = fmaf(h2k, wrow[v], wa[v]);
  }
}

// ---------------- tier-1 phase A: h1 (VALU) + h2 (MFMA) + w-GEMM (MFMA) ----
__global__ __launch_bounds__(256, 4) void w_kernel(
    const int* __restrict__ csr_edge, const float* __restrict__ emb,
    const float* __restrict__ Wm1, const unsigned* __restrict__ Wm2T,
    const unsigned* __restrict__ Wm3T, __half* __restrict__ w_sorted)
{
  __shared__ unsigned sA[256 * 32];   // h1 then h2 [edge][k2] swizzled; slabs
  const int tid = threadIdx.x;
  const int i = blockIdx.x * 256 + tid;
  const int e = csr_edge[i];

  // ---- h1[64] per edge (K=8 stays VALU), pack into sA swizzled ----
  float e8[8];
  ld8(e8, emb + (size_t)e * 8);
  {
    const int r = tid;
    #pragma unroll
    for (int c = 0; c < 8; ++c) {
      float h[8];
      #pragma unroll
      for (int j2 = 0; j2 < 8; ++j2) {
        const int k = c * 8 + j2;
        float a = 0.f;
        #pragma unroll
        for (int j = 0; j < 8; ++j) a = fmaf(e8[j], Wm1[j * 64 + k], a);
        h[j2] = swishf(a * 0.35355339059327373f);   // /sqrt(8)
      }
      uint4 v;
      v.x = pack2h(h[0], h[1]);
      v.y = pack2h(h[2], h[3]);
      v.z = pack2h(h[4], h[5]);
      v.w = pack2h(h[6], h[7]);
      *(uint4*)&sA[r * 32 + ((c ^ (r & 7)) << 2)] = v;
    }
  }
  __syncthreads();

  const int l = tid & 63;
  const int wv = tid >> 6;
  const int lg = l >> 4;
  const int lm = l & 15;

  // ---- B-frags: wave's 64 edges of h1 (all K in registers) ----
  f16x8 bfr[4][2];
  #pragma unroll
  for (int nt = 0; nt < 4; ++nt) {
    int row = wv * 64 + nt * 16 + lm;
    #pragma unroll
    for (int kh = 0; kh < 2; ++kh) {
      uint4 u = *(const uint4*)&sA[row * 32 + ((((kh << 2) + lg) ^ (row & 7)) << 2)];
      bfr[nt][kh] = u4f16(u);
    }
  }

  // ---- h2 GEMM: D = Wm2T x h1; swish; write back into own wave rows ----
  #pragma unroll
  for (int mt = 0; mt < 4; ++mt) {
    const int arow = mt * 16 + lm;
    uint4 u0 = *(const uint4*)&Wm2T[arow * 32 + (lg << 2)];
    uint4 u1 = *(const uint4*)&Wm2T[arow * 32 + 16 + (lg << 2)];
    f16x8 a0 = u4f16(u0), a1 = u4f16(u1);
    #pragma unroll
    for (int nt = 0; nt < 4; ++nt) {
      f32x4 acc = {0.f, 0.f, 0.f, 0.f};
      acc = __builtin_amdgcn_mfma_f32_16x16x32_f16(a0, bfr[nt][0], acc, 0, 0, 0);
      acc = __builtin_amdgcn_mfma_f32_16x16x32_f16(a1, bfr[nt][1], acc, 0, 0, 0);
      // lane: h2 rows mt*16+lg*4+{0..3} of edge row r
      const int r = wv * 64 + nt * 16 + lm;
      const int k2b = mt * 8 + lg * 2;       // even
      const int c = k2b >> 2, wi = k2b & 3;  // wi in {0,2}
      uint2 pk;
      pk.x = pack2h(swishf(acc[0] * 0.125f), swishf(acc[1] * 0.125f));
      pk.y = pack2h(swishf(acc[2] * 0.125f), swishf(acc[3] * 0.125f));
      *(uint2*)&sA[r * 32 + ((c ^ (r & 7)) << 2) + wi] = pk;
    }
  }

  // ---- B-frags reload: now h2 ----
  f16x8 bfr2[4][2];
  #pragma unroll
  for (int nt = 0; nt < 4; ++nt) {
    int row = wv * 64 + nt * 16 + lm;
    #pragma unroll
    for (int kh = 0; kh < 2; ++kh) {
      uint4 u = *(const uint4*)&sA[row * 32 + ((((kh << 2) + lg) ^ (row & 7)) << 2)];
      bfr2[nt][kh] = u4f16(u);
    }
  }
  unsigned* sTw = sA + wv * 2048;
  const int eb = blockIdx.x * 256 + wv * 64;

  #pragma unroll 1
  for (int p = 0; p < 4; ++p) {
    #pragma unroll
    for (int mtl = 0; mtl < 4; ++mtl) {
      const int mt = p * 4 + mtl;
      int arow = mt * 16 + lm;
      uint4 u0 = *(const uint4*)&Wm3T[arow * 32 + (lg << 2)];
      uint4 u1 = *(const uint4*)&Wm3T[arow * 32 + 16 + (lg << 2)];
      f16x8 a0 = u4f16(u0), a1 = u4f16(u1);
      #pragma unroll
      for (int nt = 0; nt < 4; ++nt) {
        f32x4 acc = {0.f, 0.f, 0.f, 0.f};
        acc = __builtin_amdgcn_mfma_f32_16x16x32_f16(a0, bfr2[nt][0], acc, 0, 0, 0);
        acc = __builtin_amdgcn_mfma_f32_16x16x32_f16(a1, bfr2[nt][1], acc, 0, 0, 0);
        const int r = nt * 16 + lm;
        const int u = mtl * 4 + lg;
        const int pos8 = ((((u >> 1) ^ (r & 7)) << 1) | (u & 1));
        uint2 pk;
        pk.x = pack2h(acc[0], acc[1]);
        pk.y = pack2h(acc[2], acc[3]);
        *(uint2*)&sTw[r * 32 + pos8 * 2] = pk;
      }
    }
    #pragma unroll
    for (int g = 0; g < 8; ++g) {
      const int er = g * 8 + (l >> 3);
      const int c8 = l & 7;
      uint4 v = *(const uint4*)&sTw[er * 32 + ((c8 ^ (er & 7)) << 2)];
      *(uint4*)(w_sorted + (size_t)(eb + er) * 256 + p * 64 + c8 * 8) = v;
    }
  }
}

// ---------------- tier-1 phase B: per-node gather + tensor product ----------
__global__ __launch_bounds__(256) void gather_tp(
    const float* __restrict__ y, const __half* __restrict__ w_sorted,
    const float* __restrict__ sh_sorted, const int* __restrict__ snd_sorted,
    const int* __restrict__ offsets, float* __restrict__ agg)
{
  const int l = threadIdx.x & 63;
  const int wv = threadIdx.x >> 6;
  const int n = blockIdx.x * 4 + wv;
  const int row0 = offsets[n];
  const int row1 = offsets[n + 1];

  float s0 = 0.f, s1 = 0.f;
  float v0x = 0.f, v0y = 0.f, v0z = 0.f;
  float v1x = 0.f, v1y = 0.f, v1z = 0.f;

  for (int i = row0; i < row1; ++i) {
    const int s = snd_sorted[i];
    const float4 sh = *(const float4*)(sh_sorted + (size_t)i * 4);
    const __half* wr = w_sorted + (size_t)i * 256;
    float w1 = __half2float(wr[l]);
    float w2 = __half2float(wr[64 + l]);
    float w3 = __half2float(wr[128 + l]);
    float w4 = __half2float(wr[192 + l]);
    const float* yr = y + (size_t)s * 256;
    float e0 = yr[l];
    float ex = yr[64 + 3 * l], ey = yr[65 + 3 * l], ez = yr[66 + 3 * l];

    s0 = fmaf(w1 * e0, sh.x, s0);
    s1 = fmaf(w4, fmaf(ex, sh.y, fmaf(ey, sh.z, ez * sh.w)), s1);
    float t2 = w2 * e0;
    v0x = fmaf(t2, sh.y, v0x); v0y = fmaf(t2, sh.z, v0y); v0z = fmaf(t2, sh.w, v0z);
    float t3 = w3 * sh.x;
    v1x = fmaf(t3, ex, v1x); v1y = fmaf(t3, ey, v1y); v1z = fmaf(t3, ez, v1z);
  }

  const float SCL = 0.0078125f;                          // (1/8 w-scale) / 16
  const float C4  = 0.125f / (16.0f * 1.7320508075688772f);
  float* ar = agg + (size_t)n * 512;
  ar[l]       = s0 * SCL;
  ar[64 + l]  = s1 * C4;
  ar[128 + l]        = v0x * SCL;
  ar[128 + 64 + l]   = v1x * SCL;
  ar[256 + l]        = v0y * SCL;
  ar[256 + 64 + l]   = v1y * SCL;
  ar[384 + l]        = v0z * SCL;
  ar[384 + 64 + l]   = v1z * SCL;
}

// ---------------- tier-1: node-side MFMA GEMM + fused gate epilogue ----------
__global__ __launch_bounds__(256) void node_gemm(
    const float* __restrict__ feats, const float* __restrict__ attrs,
    const float* __restrict__ agg, const unsigned* __restrict__ BsT,
    const unsigned* __restrict__ BvT, float* __restrict__ out)
{
  __shared__ unsigned sAK[64 * 128];   // 32768B, one K-half (28 chunks used)
  __shared__ float zsL[16 * 128];      // 8192B
  __shared__ __half zvL[48 * 64];      // 6144B
  __shared__ float sAt[16 * 5];
  const int t = threadIdx.x;
  const int n0 = blockIdx.x * 16;

  if (t < 80) sAt[t] = attrs[(size_t)n0 * 5 + t];
  __syncthreads();

  const int l = t & 63;
  const int wv = t >> 6;
  const int lm = l & 15;
  const int lg = l >> 4;

  const int row = t >> 2;
  const int part = t & 3;
  const bool is_s = row < 16;
  int node, m = 0;
  if (is_s) node = row;
  else { int vi = row - 16; node = vi / 3; m = vi - node * 3; }
  const float* xrow = feats + (size_t)(n0 + node) * 256;
  const float* atr = &sAt[node * 5];
  const float* aggr = agg + (size_t)(n0 + node) * 512;
  unsigned* arow = &sAK[row * 128];

  f32x4 acc[5];
  #pragma unroll
  for (int jj = 0; jj < 5; ++jj) acc[jj] = (f32x4){0.f, 0.f, 0.f, 0.f};

  auto mfma_phase = [&](int h) {
    #pragma unroll
    for (int jj = 0; jj < 5; ++jj) {
      const int jd = wv + 4 * jj;
      int mtile, ntile;
      const unsigned* Bt;
      if (jd < 8) { mtile = 0; ntile = jd; Bt = BsT; }
      else { int q = jd - 8; mtile = 1 + (q >> 2); ntile = q & 3; Bt = BvT; }

      const int arow0 = mtile * 16 + lm;
      const unsigned* brow = Bt + (ntile * 16 + lm) * 224 + h * 112;

      uint4 ubr[7];
      #pragma unroll
      for (int ks = 0; ks < 7; ++ks)
        ubr[ks] = *(const uint4*)&brow[(ks * 4 + lg) << 2];

      f32x4 a = acc[jj];
      #pragma unroll
      for (int ks = 0; ks < 7; ++ks) {
        int ch = ks * 4 + lg;
        int chs = (ch & ~7) | ((ch ^ arow0) & 7);
        uint4 ua = *(const uint4*)&sAK[arow0 * 128 + (chs << 2)];
        a = __builtin_amdgcn_mfma_f32_16x16x32_f16(u4f16(ua), u4f16(ubr[ks]), a, 0, 0, 0);
      }
      acc[jj] = a;
    }
  };

  float r0[28], r1[28];

  #pragma unroll
  for (int jj = 0; jj < 28; ++jj) {
    const int jg = part + 4 * jj;
    int u0 = (jg & 31) << 1;
    if (is_s) { r0[jj] = xrow[u0];              r1[jj] = xrow[u0 + 1]; }
    else      { r0[jj] = xrow[64 + 3 * u0 + m]; r1[jj] = xrow[64 + 3 * u0 + 3 + m]; }
  }

  #pragma unroll
  for (int jj = 0; jj < 28; ++jj) {
    const int jg = part + 4 * jj;
    float a = atr[jg >> 5];
    int chs = (jj & ~7) | ((jj ^ row) & 7);
    arow[(chs << 2) + part] = pack2h(r0[jj] * a, r1[jj] * a);
  }
  __syncthreads();

  #pragma unroll
  for (int jj = 0; jj < 28; ++jj) {
    const int jg = 112 + part + 4 * jj;
    if (jj < 12) {
      int u0 = (jg & 31) << 1;
      if (is_s) { r0[jj] = xrow[u0];              r1[jj] = xrow[u0 + 1]; }
      else      { r0[jj] = xrow[64 + 3 * u0 + m]; r1[jj] = xrow[64 + 3 * u0 + 3 + m]; }
    } else {
      int c0 = (jg - 160) << 1;
      if (is_s) { r0[jj] = aggr[c0];                  r1[jj] = aggr[c0 + 1]; }
      else      { r0[jj] = aggr[128 + m * 128 + c0];  r1[jj] = aggr[128 + m * 128 + c0 + 1]; }
    }
  }

  mfma_phase(0);
  __syncthreads();

  #pragma unroll
  for (int jj = 0; jj < 28; ++jj) {
    const int jg = 112 + part + 4 * jj;
    float v0, v1;
    if (jj < 12) {
      float a = atr[jg >> 5];
      v0 = r0[jj] * a; v1 = r1[jj] * a;
    } else {
      v0 = r0[jj]; v1 = r1[jj];
    }
    int chs = (jj & ~7) | ((jj ^ row) & 7);
    arow[(chs << 2) + part] = pack2h(v0, v1);
  }
  __syncthreads();

  mfma_phase(1);

  #pragma unroll
  for (int jj = 0; jj < 5; ++jj) {
    const int jd = wv + 4 * jj;
    int mtile, ntile;
    if (jd < 8) { mtile = 0; ntile = jd; }
    else { int q = jd - 8; mtile = 1 + (q >> 2); ntile = q & 3; }
    const int drow = mtile * 16 + lg * 4;
    if (jd < 8) {
      #pragma unroll
      for (int rr = 0; rr < 4; ++rr)
        zsL[(drow + rr) * 128 + ntile * 16 + lm] = acc[jj][rr];
    } else {
      const int vi0 = drow - 16;
      #pragma unroll
      for (int rr = 0; rr < 4; ++rr)
        zvL[(vi0 + rr) * 64 + ntile * 16 + lm] = __float2half(acc[jj][rr]);
    }
  }
  __syncthreads();

  int ug = 0, mg = 0;
  if (t >= 64) { ug = (t - 64) / 3; mg = (t - 64) - ug * 3; }
  #pragma unroll 4
  for (int nb = 0; nb < 16; ++nb) {
    float val;
    if (t < 64) {
      val = swishf(zsL[nb * 128 + t]);
    } else {
      float gate = swishf(zsL[nb * 128 + 64 + ug]);
      val = gate * __half2float(zvL[(nb * 3 + mg) * 64 + ug]);
    }
    out[(size_t)(n0 + nb) * 256 + t] = val;
  }
}

// ---------------- tier-2: r7 fused gather (old agg layout) ----------------
__global__ __launch_bounds__(512, 2) void gather_fused(
    const float* __restrict__ y, const int* __restrict__ csr_edge,
    const int* __restrict__ snd, const float* __restrict__ esh,
    const float* __restrict__ emb, const float* __restrict__ Wm1,
    const float* __restrict__ Wm2, const float* __restrict__ Wm3,
    const int* __restrict__ offsets, float* __restrict__ agg)
{
  __shared__ __align__(16) float sW3[64 * 256];
  __shared__ __align__(16) float sH[8 * 4 * 64];
  const int t = threadIdx.x;

  #pragma unroll 4
  for (int i = 0; i < 32; ++i) {
    int idx = i * 512 + t;
    int k = idx >> 8;
    int c = idx & 255;
    float v = Wm3[idx];
    int kg = k >> 2, kk = k & 3;
    sW3[c * 64 + (((kg ^ (c & 15)) & 15) << 2) + kk] = v;
  }
  __syncthreads();

  const int l = t & 63;
  const int wv = t >> 6;
  const int n = blockIdx.x * 8 + wv;
  const int row0 = offsets[n];
  const int row1 = offsets[n + 1];

  float* sHw = &sH[wv * 256];

  float wm1r[8];
  #pragma unroll
  for (int j = 0; j < 8; ++j) wm1r[j] = Wm1[j * 64 + l];

  float s0 = 0.f, s1 = 0.f;
  float v0x = 0.f, v0y = 0.f, v0z = 0.f;
  float v1x = 0.f, v1y = 0.f, v1z = 0.f;

  const int swz = ((l & 15) << 2);

  for (int i = row0; i < row1; i += 4) {
    const int nb = row1 - i;

    int   sn[4];
    float4 sh[4];
    #pragma unroll
    for (int b = 0; b < 4; ++b) {
      int idx = (b < nb) ? (i + b) : i;
      int e = csr_edge[idx];
      sn[b] = snd[e];
      float4 s = *(const float4*)(esh + (size_t)e * 4);
      if (b >= nb) s = make_float4(0.f, 0.f, 0.f, 0.f);
      sh[b] = s;
      float em8[8];
      ld8(em8, emb + (size_t)e * 8);
      float a = 0.f;
      #pragma unroll
      for (int j = 0; j < 8; ++j) a = fmaf(em8[j], wm1r[j], a);
      sHw[b * 64 + l] = swishf(a * 0.35355339059327373f);
    }

    float h2[4] = {0.f, 0.f, 0.f, 0.f};
    #pragma unroll 4
    for (int q = 0; q < 16; ++q) {
      float wq0 = Wm2[(4 * q + 0) * 64 + l];
      float wq1 = Wm2[(4 * q + 1) * 64 + l];
      float wq2 = Wm2[(4 * q + 2) * 64 + l];
      float wq3 = Wm2[(4 * q + 3) * 64 + l];
      #pragma unroll
      for (int b = 0; b < 4; ++b) {
        float4 h = *(const float4*)&sHw[b * 64 + 4 * q];
        h2[b] = fmaf(h.x, wq0, h2[b]);
        h2[b] = fmaf(h.y, wq1, h2[b]);
        h2[b] = fmaf(h.z, wq2, h2[b]);
        h2[b] = fmaf(h.w, wq3, h2[b]);
      }
    }
    #pragma unroll
    for (int b = 0; b < 4; ++b)
      h2[b] = swishf(h2[b] * 0.125f);
    #pragma unroll
    for (int b = 0; b < 4; ++b)
      sHw[b * 64 + l] = h2[b];

    float w0[4]  = {0,0,0,0}, w1a[4] = {0,0,0,0};
    float w2a[4] = {0,0,0,0}, w3a[4] = {0,0,0,0};
    #pragma unroll 1
    for (int g = 0; g < 16; ++g) {
      int sbase = l * 64 + (((g << 2) ^ swz) & 63);
      float4 m0 = *(const float4*)&sW3[sbase];
      float4 m1 = *(const float4*)&sW3[sbase + 4096];
      float4 m2 = *(const float4*)&sW3[sbase + 8192];
      float4 m3 = *(const float4*)&sW3[sbase + 12288];
      #pragma unroll
      for (int b = 0; b < 4; ++b) {
        float4 hb = *(const float4*)&sHw[b * 64 + 4 * g];
        #pragma unroll
        for (int kk = 0; kk < 4; ++kk) {
          float bc = (&hb.x)[kk];
          w0[b]  = fmaf(bc, (&m0.x)[kk], w0[b]);
          w1a[b] = fmaf(bc, (&m1.x)[kk], w1a[b]);
          w2a[b] = fmaf(bc, (&m2.x)[kk], w2a[b]);
          w3a[b] = fmaf(bc, (&m3.x)[kk], w3a[b]);
        }
      }
    }

    #pragma unroll
    for (int b = 0; b < 4; ++b) {
      const float* yr = y + (size_t)sn[b] * 256;
      float e0 = yr[l];
      float ex = yr[64 + 3 * l], ey = yr[65 + 3 * l], ez = yr[66 + 3 * l];
      float4 s = sh[b];
      s0 = fmaf(w0[b] * e0, s.x, s0);
      s1 = fmaf(w3a[b], fmaf(ex, s.y, fmaf(ey, s.z, ez * s.w)), s1);
      float t2 = w1a[b] * e0;
      v0x = fmaf(t2, s.y, v0x); v0y = fmaf(t2, s.z, v0y); v0z = fmaf(t2, s.w, v0z);
      float t3 = w2a[b] * s.x;
      v1x = fmaf(t3, ex, v1x); v1y = fmaf(t3, ey, v1y); v1z = fmaf(t3, ez, v1z);
    }
  }

  const float SCL = 0.0078125f;
  const float C4  = 0.125f / (16.0f * 1.7320508075688772f);
  float* ar = agg + (size_t)n * 512;
  ar[l]       = s0 * SCL;
  ar[64 + l]  = s1 * C4;
  ar[128 + 3 * l]     = v0x * SCL;
  ar[128 + 3 * l + 1] = v0y * SCL;
  ar[128 + 3 * l + 2] = v0z * SCL;
  ar[320 + 3 * l]     = v1x * SCL;
  ar[320 + 3 * l + 1] = v1y * SCL;
  ar[320 + 3 * l + 2] = v1z * SCL;
}

// ---------------- tier-3: atomic edge kernel ----------------
__global__ __launch_bounds__(256) void edge_kernel(
    const float* __restrict__ y, const float* __restrict__ edge_sh,
    const int* __restrict__ senders, const int* __restrict__ receivers,
    const float* __restrict__ emb, const float* __restrict__ Wm1,
    const float* __restrict__ Wm2, const float* __restrict__ Wm3,
    float* __restrict__ agg)
{
  __shared__ float h2s[64 * 256];
  const int tid = threadIdx.x;
  const int e = blockIdx.x * 256 + tid;
  const int s = senders[e];
  const int r = receivers[e];
  const float4 shv = *(const float4*)(edge_sh + (size_t)e * 4);
  float e8[8];
  ld8(e8, emb + (size_t)e * 8);

  float h2a[64];
  #pragma unroll
  for (int v = 0; v < 64; ++v) h2a[v] = 0.f;
  #pragma unroll 2
  for (int k = 0; k < 64; ++k) {
    float a = 0.f;
    #pragma unroll
    for (int j = 0; j < 8; ++j) a = fmaf(e8[j], Wm1[j * 64 + k], a);
    float h1k = swishf(a * 0.35355339059327373f);
    const float* wrow = Wm2 + k * 64;
    #pragma unroll
    for (int v = 0; v < 64; ++v) h2a[v] = fmaf(h1k, wrow[v], h2a[v]);
  }
  #pragma unroll
  for (int v = 0; v < 64; ++v)
    h2s[v * 256 + tid] = swishf(h2a[v] * 0.125f);

  const float* yrow = y + (size_t)s * 256;
  float* aggr = agg + (size_t)r * 512;
  const float SCL = 0.0078125f;
  const float c0  = shv.x * SCL;
  const float c1x = shv.y * SCL, c1y = shv.z * SCL, c1z = shv.w * SCL;
  const float c4  = 0.125f / (16.0f * 1.7320508075688772f);

  float wa[64];

  wgemv(wa, Wm3, h2s + tid, 0);
  #pragma unroll
  for (int uc = 0; uc < 8; ++uc) {
    float ev[8];
    ld8(ev, yrow + uc * 8);
    #pragma unroll
    for (int j = 0; j < 8; ++j) {
      int u = uc * 8 + j;
      atomicAdd(&aggr[u], wa[u] * ev[j] * c0);
    }
  }
  wgemv(wa, Wm3, h2s + tid, 1);
  #pragma unroll
  for (int uc = 0; uc < 8; ++uc) {
    float ev[8];
    ld8(ev, yrow + uc * 8);
    #pragma unroll
    for (int j = 0; j < 8; ++j) {
      int u = uc * 8 + j;
      float tt = wa[u] * ev[j];
      atomicAdd(&aggr[128 + 3 * u    ], tt * c1x);
      atomicAdd(&aggr[128 + 3 * u + 1], tt * c1y);
      atomicAdd(&aggr[128 + 3 * u + 2], tt * c1z);
    }
  }
  wgemv(wa, Wm3, h2s + tid, 2);
  #pragma unroll
  for (int uc = 0; uc < 8; ++uc) {
    float ev[24];
    ld8(ev,      yrow + 64 + uc * 24);
    ld8(ev + 8,  yrow + 64 + uc * 24 + 8);
    ld8(ev + 16, yrow + 64 + uc * 24 + 16);
    #pragma unroll
    for (int j = 0; j < 8; ++j) {
      int u = uc * 8 + j;
      float tt = wa[u] * c0;
      atomicAdd(&aggr[320 + 3 * u    ], tt * ev[3 * j    ]);
      atomicAdd(&aggr[320 + 3 * u + 1], tt * ev[3 * j + 1]);
      atomicAdd(&aggr[320 + 3 * u + 2], tt * ev[3 * j + 2]);
    }
  }
  wgemv(wa, Wm3, h2s + tid, 3);
  #pragma unroll
  for (int uc = 0; uc < 8; ++uc) {
    float ev[24];
    ld8(ev,      yrow + 64 + uc * 24);
    ld8(ev + 8,  yrow + 64 + uc * 24 + 8);
    ld8(ev + 16, yrow + 64 + uc * 24 + 16);
    #pragma unroll
    for (int j = 0; j < 8; ++j) {
      int u = uc * 8 + j;
      float d = ev[3*j]*shv.y + ev[3*j+1]*shv.z + ev[3*j+2]*shv.w;
      atomicAdd(&aggr[64 + u], wa[u] * d * c4);
    }
  }
}

// ---------------- VALU node_post (tier-2/3 fallback, old agg layout) --------
__global__ __launch_bounds__(256) void node_post(
    const float* __restrict__ feats, const float* __restrict__ attrs,
    const float* __restrict__ agg, const float* __restrict__ W2s,
    const float* __restrict__ W2v, const float* __restrict__ Wr_s,
    const float* __restrict__ Wr_v, float* __restrict__ out)
{
  __shared__ __align__(16) float sA[320 * 8];
  __shared__ __align__(16) float sX0[64 * 8];
  __shared__ __align__(16) float sX1[192 * 8];
  __shared__ __align__(16) float sAt[5 * 8];
  __shared__ __align__(16) float sAggS[128 * 8];
  __shared__ __align__(16) float sAggV[384 * 8];
  __shared__ __align__(16) float sZs[8 * 128];
  __shared__ __align__(16) float sZv[8 * 192];

  const int t = threadIdx.x;
  const int n0 = blockIdx.x * 8;
  const float nr = 0.05590169943749474f;
  const float n2 = 0.08838834764831845f;

  #pragma unroll
  for (int nb = 0; nb < 8; ++nb) {
    float v = feats[(size_t)(n0 + nb) * 256 + t];
    if (t < 64) sX0[t * 8 + nb] = v;
    else        sX1[(t - 64) * 8 + nb] = v;
  }
  if (t < 40) {
    int nb = t & 7, s = t >> 3;
    sAt[s * 8 + nb] = attrs[(size_t)(n0 + nb) * 5 + s] * nr;
  }
  #pragma unroll
  for (int i = 0; i < 16; ++i) {
    int idx = i * 256 + t;
    int nb = idx >> 9;
    int c = idx & 511;
    float v = agg[(size_t)(n0 + nb) * 512 + c] * n2;
    if (c < 128) sAggS[c * 8 + nb] = v;
    else         sAggV[(c - 128) * 8 + nb] = v;
  }
  __syncthreads();

  #pragma unroll
  for (int i = 0; i < 10; ++i) {
    int idx = i * 256 + t;
    int nb = idx & 7;
    int us = idx >> 3;
    int u = us / 5;
    int s = us - u * 5;
    sA[us * 8 + nb] = sX0[u * 8 + nb] * sAt[s * 8 + nb];
  }
  __syncthreads();

  float av[8][3];

  if (t < 128) {
    const int v = t;
    float acc[8];
    #pragma unroll
    for (int nb = 0; nb < 8; ++nb) acc[nb] = 0.f;
    for (int us = 0; us < 320; ++us)
      fma8v(acc, &sA[us * 8], Wr_s[us * 128 + v]);
    for (int c = 0; c < 128; ++c)
      fma8v(acc, &sAggS[c * 8], W2s[c * 128 + v]);
    #pragma unroll
    for (int nb = 0; nb < 8; ++nb) sZs[nb * 128 + v] = acc[nb];
  } else {
    const int tv = t - 128;
    const int v = tv & 63;
    const int half = tv >> 6;
    #pragma unroll
    for (int nb = 0; nb < 8; ++nb)
      #pragma unroll
      for (int m = 0; m < 3; ++m) av[nb][m] = 0.f;

    const int u0 = half * 32;
    for (int u = u0; u < u0 + 32; ++u) {
      float xr0[8], xr1[8], xr2[8];
      ld8(xr0, &sX1[(u * 3 + 0) * 8]);
      ld8(xr1, &sX1[(u * 3 + 1) * 8]);
      ld8(xr2, &sX1[(u * 3 + 2) * 8]);
      #pragma unroll
      for (int s = 0; s < 5; ++s) {
        float w = Wr_v[(u * 5 + s) * 64 + v];
        float at[8];
        ld8(at, &sAt[s * 8]);
        #pragma unroll
        for (int nb = 0; nb < 8; ++nb) {
          float tt = at[nb] * w;
          av[nb][0] = fmaf(xr0[nb], tt, av[nb][0]);
          av[nb][1] = fmaf(xr1[nb], tt, av[nb][1]);
          av[nb][2] = fmaf(xr2[nb], tt, av[nb][2]);
        }
      }
    }
    const int c0 = half * 64;
    for (int c = c0; c < c0 + 64; ++c) {
      float w = W2v[c * 64 + v];
      float g0[8], g1[8], g2[8];
      ld8(g0, &sAggV[(c * 3 + 0) * 8]);
      ld8(g1, &sAggV[(c * 3 + 1) * 8]);
      ld8(g2, &sAggV[(c * 3 + 2) * 8]);
      #pragma unroll
      for (int nb = 0; nb < 8; ++nb) {
        av[nb][0] = fmaf(g0[nb], w, av[nb][0]);
        av[nb][1] = fmaf(g1[nb], w, av[nb][1]);
        av[nb][2] = fmaf(g2[nb], w, av[nb][2]);
      }
    }
    if (half == 0) {
      #pragma unroll
      for (int nb = 0; nb < 8; ++nb)
        #pragma unroll
        for (int m = 0; m < 3; ++m)
          sZv[nb * 192 + v * 3 + m] = av[nb][m];
    }
  }
  __syncthreads();
  if (t >= 192) {
    const int v = (t - 128) & 63;
    #pragma unroll
    for (int nb = 0; nb < 8; ++nb)
      #pragma unroll
      for (int m = 0; m < 3; ++m)
        sZv[nb * 192 + v * 3 + m] += av[nb][m];
  }
  __syncthreads();

  const int i = t - 64;
  const int ug = (t >= 64) ? (i / 3) : 0;
  #pragma unroll
  for (int nb = 0; nb < 8; ++nb) {
    float val;
    if (t < 64) {
      val = swishf(sZs[nb * 128 + t]);
    } else {
      float gate = swishf(sZs[nb * 128 + 64 + ug]);
      val = gate * sZv[nb * 192 + i];
    }
    out[(size_t)(n0 + nb) * 256 + t] = val;
  }
}

extern "C" void kernel_launch(void* const* d_in, const int* in_sizes, int n_in,
                              void* d_out, int out_size, void* d_ws, size_t ws_size,
                              hipStream_t stream)
{
  const float* feats = (const float*)d_in[0];
  const float* attrs = (const float*)d_in[1];
  const float* esh   = (const float*)d_in[2];
  const int*   snd   = (const int*)d_in[3];
  const int*   rcv   = (const int*)d_in[4];
  const float* emb   = (const float*)d_in[5];
  const float* Wl0   = (const float*)d_in[6];
  const float* Wl1   = (const float*)d_in[7];
  const float* Wm1   = (const float*)d_in[8];
  const float* Wm2   = (const float*)d_in[9];
  const float* Wm3   = (const float*)d_in[10];
  const float* W2s   = (const float*)d_in[11];
  const float* W2v   = (const float*)d_in[12];
  const float* Wr_s  = (const float*)d_in[13];
  const float* Wr_v  = (const float*)d_in[14];
  float* out = (float*)d_out;

  float* y   = (float*)d_ws;                     // NN*256 f32
  float* agg = y + (size_t)NN * 256;             // NN*512 f32
  int* counts = (int*)agg;                       // aliased transients
  int* cursor = counts + NN;
  int* csr_edge = (int*)(agg + (size_t)NN * 512);   // NE ints
  int* offsets  = csr_edge + NE;                    // NN+1 ints
  int* snd_sorted = offsets + NN + 1;               // NE ints
  float* sh_sorted = (float*)(snd_sorted + NE);     // NE*4 f32
  __half* w_sorted = (__half*)(sh_sorted + (size_t)NE * 4);  // NE*256 f16
  unsigned* Wm2P = (unsigned*)(w_sorted + (size_t)NE * 256); // 2048 u32
  unsigned* Wm3P = Wm2P + 2048;                              // 8192 u32
  unsigned* Wm3T = Wm3P + 8192;                              // 8192 u32
  unsigned* BsT  = Wm3T + 8192;                              // 28672 u32
  unsigned* BvT  = BsT + 28672;                              // 14336 u32
  unsigned* Wm2T = BvT + 14336;                              // 2048 u32
  size_t need1 = (size_t)((char*)(Wm2T + 2048) - (char*)d_ws);
  size_t need2 = (size_t)((char*)(offsets + NN + 1) - (char*)d_ws);

  if (ws_size >= need1) {
    hipMemsetAsync(counts, 0, (size_t)NN * sizeof(int), stream);
    hist_kernel<<<NE / 256, 256, 0, stream>>>(rcv, counts);
    scan_kernel<<<1, 1024, 0, stream>>>(counts, offsets, cursor);
    scatter_full<<<NE / 256, 256, 0, stream>>>(rcv, snd, esh, cursor,
                                               csr_edge, snd_sorted, sh_sorted);
    pack_weights<<<80, 256, 0, stream>>>(Wm2, Wm3, Wm2P, Wm3P, Wm3T, Wm2T);
    pack_node_B<<<168, 256, 0, stream>>>(Wr_s, W2s, Wr_v, W2v, BsT, BvT);
    node_prep<<<NN / 4, 256, 0, stream>>>(feats, Wl0, Wl1, y);
    w_kernel<<<NE / 256, 256, 0, stream>>>(csr_edge, emb, Wm1, Wm2T, Wm3T, w_sorted);
    gather_tp<<<NN / 4, 256, 0, stream>>>(y, w_sorted, sh_sorted, snd_sorted,
                                          offsets, agg);
    node_gemm<<<NN / 16, 256, 0, stream>>>(feats, attrs, agg, BsT, BvT, out);
  } else if (ws_size >= need2) {
    hipMemsetAsync(counts, 0, (size_t)NN * sizeof(int), stream);
    hist_kernel<<<NE / 256, 256, 0, stream>>>(rcv, counts);
    scan_kernel<<<1, 1024, 0, stream>>>(counts, offsets, cursor);
    scatter_kernel<<<NE / 256, 256, 0, stream>>>(rcv, cursor, csr_edge);
    node_prep<<<NN / 4, 256, 0, stream>>>(feats, Wl0, Wl1, y);
    gather_fused<<<NN / 8, 512, 0, stream>>>(y, csr_edge, snd, esh, emb,
                                             Wm1, Wm2, Wm3, offsets, agg);
    node_post<<<NN / 8, 256, 0, stream>>>(feats, attrs, agg, W2s, W2v, Wr_s, Wr_v, out);
  } else {
    hipMemsetAsync(agg, 0, (size_t)NN * 512 * sizeof(float), stream);
    node_prep<<<NN / 4, 256, 0, stream>>>(feats, Wl0, Wl1, y);
    edge_kernel<<<NE / 256, 256, 0, stream>>>(y, esh, snd, rcv, emb, Wm1, Wm2, Wm3, agg);
    node_post<<<NN / 8, 256, 0, stream>>>(feats, attrs, agg, W2s, W2v, Wr_s, Wr_v, out);
  }
}